// Round 6
// baseline (765.031 us; speedup 1.0000x reference)
//
#include <hip/hip_runtime.h>
#include <hip/hip_bf16.h>
#include <math.h>

#define EMBED 1024
#define NHEADS 16
#define HDIM 64
#define BATCH 4
#define SQL 1024
#define SKL 2048

typedef unsigned short u16;
typedef __attribute__((ext_vector_type(4))) float f32x4;
typedef __attribute__((ext_vector_type(8))) __bf16 bf16x8;
typedef __attribute__((ext_vector_type(8))) short s16x8;
typedef __attribute__((ext_vector_type(4))) short s16x4;
typedef __attribute__((ext_vector_type(8))) u16 u16x8;

__device__ __forceinline__ u16 f2bf(float x) {
    __hip_bfloat16 h = __float2bfloat16(x);
    return *reinterpret_cast<u16*>(&h);
}
__device__ __forceinline__ float bf2f(u16 u) {
    __hip_bfloat16 h;
    *reinterpret_cast<u16*>(&h) = u;
    return __bfloat162float(h);
}
__device__ __forceinline__ f32x4 mfma16(s16x8 a, s16x8 b, f32x4 c) {
    return __builtin_amdgcn_mfma_f32_16x16x32_bf16(
        __builtin_bit_cast(bf16x8, a), __builtin_bit_cast(bf16x8, b), c, 0, 0, 0);
}
__device__ __forceinline__ f32x4 mfma16k16(s16x4 a, s16x4 b, f32x4 c) {
    return __builtin_amdgcn_mfma_f32_16x16x16bf16_1k(a, b, c, 0, 0, 0);
}

// ---------------------------------------------------------------------------
// GEMM NT (unchanged, proven ~770 TF-eff): Y = A * W^T + bias. K=1024.
// ---------------------------------------------------------------------------
template<int SPLIT, int A_BF16, int OUT_MODE>
__global__ __launch_bounds__(256)
void gemm_mfma(const void* __restrict__ Ap, const float* __restrict__ Wp,
               const float* __restrict__ bias,
               void* __restrict__ Y0p, void* __restrict__ Y1p,
               int M, int N) {
    const int K = 1024;
    __shared__ u16 sA[2][128 * 40];
    __shared__ u16 sB[2][128 * 40];

    const int t = threadIdx.x;
    const int lane = t & 63;
    const int w = t >> 6;
    const int wm = w >> 1, wn = w & 1;
    const int rowBase = blockIdx.y * 128;
    const int colBase = blockIdx.x * 128;
    const int srow = t >> 1;
    const int sc = (t & 1) * 16;

    const float* Af = (const float*)Ap;
    const u16* Au = (const u16*)Ap;

    f32x4 acc[4][4];
#pragma unroll
    for (int i = 0; i < 4; ++i)
#pragma unroll
        for (int j = 0; j < 4; ++j) acc[i][j] = (f32x4){0.f, 0.f, 0.f, 0.f};

    float ax[16], bx[16];
    u16x8 au0, au1;

    {
        const int k0 = 0;
        if constexpr (A_BF16) {
            au0 = *(const u16x8*)&Au[(size_t)(rowBase + srow) * K + k0 + sc];
            au1 = *(const u16x8*)&Au[(size_t)(rowBase + srow) * K + k0 + sc + 8];
        } else {
#pragma unroll
            for (int j = 0; j < 4; ++j)
                *(float4*)&ax[j * 4] = *(const float4*)&Af[(size_t)(rowBase + srow) * K + k0 + sc + j * 4];
        }
#pragma unroll
        for (int j = 0; j < 4; ++j)
            *(float4*)&bx[j * 4] = *(const float4*)&Wp[(size_t)(colBase + srow) * K + k0 + sc + j * 4];
    }

    for (int k0 = 0; k0 < K; k0 += 32) {
        __syncthreads();
        {
            u16x8 h0, h1, l0, l1;
            if constexpr (A_BF16) {
                h0 = au0; h1 = au1;
            } else {
#pragma unroll
                for (int j = 0; j < 8; ++j) {
                    h0[j] = f2bf(ax[j]); h1[j] = f2bf(ax[j + 8]);
                    if constexpr (SPLIT) {
                        l0[j] = f2bf(ax[j] - bf2f(h0[j]));
                        l1[j] = f2bf(ax[j + 8] - bf2f(h1[j]));
                    }
                }
            }
            *(u16x8*)&sA[0][srow * 40 + sc] = h0;
            *(u16x8*)&sA[0][srow * 40 + sc + 8] = h1;
            if constexpr (SPLIT) {
                *(u16x8*)&sA[1][srow * 40 + sc] = l0;
                *(u16x8*)&sA[1][srow * 40 + sc + 8] = l1;
            }
            u16x8 bh0, bh1, bl0, bl1;
#pragma unroll
            for (int j = 0; j < 8; ++j) {
                bh0[j] = f2bf(bx[j]); bh1[j] = f2bf(bx[j + 8]);
                if constexpr (SPLIT) {
                    bl0[j] = f2bf(bx[j] - bf2f(bh0[j]));
                    bl1[j] = f2bf(bx[j + 8] - bf2f(bh1[j]));
                }
            }
            *(u16x8*)&sB[0][srow * 40 + sc] = bh0;
            *(u16x8*)&sB[0][srow * 40 + sc + 8] = bh1;
            if constexpr (SPLIT) {
                *(u16x8*)&sB[1][srow * 40 + sc] = bl0;
                *(u16x8*)&sB[1][srow * 40 + sc + 8] = bl1;
            }
        }
        __syncthreads();
        if (k0 + 32 < K) {
            const int kn = k0 + 32;
            if constexpr (A_BF16) {
                au0 = *(const u16x8*)&Au[(size_t)(rowBase + srow) * K + kn + sc];
                au1 = *(const u16x8*)&Au[(size_t)(rowBase + srow) * K + kn + sc + 8];
            } else {
#pragma unroll
                for (int j = 0; j < 4; ++j)
                    *(float4*)&ax[j * 4] = *(const float4*)&Af[(size_t)(rowBase + srow) * K + kn + sc + j * 4];
            }
#pragma unroll
            for (int j = 0; j < 4; ++j)
                *(float4*)&bx[j * 4] = *(const float4*)&Wp[(size_t)(colBase + srow) * K + kn + sc + j * 4];
        }
        {
            s16x8 afh[4], afl[4], bfh[4], bfl[4];
#pragma unroll
            for (int mi = 0; mi < 4; ++mi) {
                int ar = wm * 64 + mi * 16 + (lane & 15);
                int ai = ar * 40 + (lane >> 4) * 8;
                afh[mi] = *(const s16x8*)&sA[0][ai];
                if constexpr (SPLIT) afl[mi] = *(const s16x8*)&sA[1][ai];
            }
#pragma unroll
            for (int ni = 0; ni < 4; ++ni) {
                int br = wn * 64 + ni * 16 + (lane & 15);
                int bi = br * 40 + (lane >> 4) * 8;
                bfh[ni] = *(const s16x8*)&sB[0][bi];
                if constexpr (SPLIT) bfl[ni] = *(const s16x8*)&sB[1][bi];
            }
#pragma unroll
            for (int mi = 0; mi < 4; ++mi)
#pragma unroll
                for (int ni = 0; ni < 4; ++ni) {
                    acc[mi][ni] = mfma16(afh[mi], bfh[ni], acc[mi][ni]);
                    if constexpr (SPLIT) {
                        acc[mi][ni] = mfma16(afh[mi], bfl[ni], acc[mi][ni]);
                        acc[mi][ni] = mfma16(afl[mi], bfh[ni], acc[mi][ni]);
                    }
                }
        }
    }

#pragma unroll
    for (int mi = 0; mi < 4; ++mi)
#pragma unroll
        for (int ni = 0; ni < 4; ++ni)
#pragma unroll
            for (int rr = 0; rr < 4; ++rr) {
                int mg = rowBase + wm * 64 + mi * 16 + (lane >> 4) * 4 + rr;
                int ng = colBase + wn * 64 + ni * 16 + (lane & 15);
                float y = acc[mi][ni][rr];
                if constexpr (OUT_MODE == 0) {
                    ((float*)Y0p)[(size_t)mg * N + ng] = y + bias[ng];
                } else if constexpr (OUT_MODE == 1) {
                    y += bias[ng];
                    u16 h = f2bf(y);
                    ((u16*)Y0p)[(size_t)mg * N + ng] = h;
                    ((u16*)Y1p)[(size_t)mg * N + ng] = f2bf(y - bf2f(h));
                } else {
                    y += bias[mg];
                    ((u16*)Y0p)[(size_t)mg * N + ng] = f2bf(y);
                }
            }
}

// ---------------------------------------------------------------------------
// Kernel A: softmax denominators. Block = (b, h, qtile of 64), 256 thr (4
// waves). Wave wv owns k-slab [wv*512, +512); 4 q-tiles in registers reuse
// every K fragment 4x. Swapped QK^T (D[k][q], lane = one q). No barriers
// until the tiny final reduce. Writes llog = log2(l).
// ---------------------------------------------------------------------------
#define ALOADK(S, sub) { \
    size_t _kr = (size_t)(b * SKL + kslab + (sub) * 16 + c16) * EMBED + h * HDIM + g * 8; \
    kh0##S = *(const s16x8*)&Khi[_kr]; kh1##S = *(const s16x8*)&Khi[_kr + 32]; \
    kl0##S = *(const s16x8*)&Klo[_kr]; kl1##S = *(const s16x8*)&Klo[_kr + 32]; }

#define ACOMP(S) { \
    _Pragma("unroll") \
    for (int qi = 0; qi < 4; ++qi) { \
        f32x4 s = {0.f, 0.f, 0.f, 0.f}; \
        s = mfma16(kh0##S, qh0v[qi], s); s = mfma16(kh1##S, qh1v[qi], s); \
        s = mfma16(kh0##S, ql0v[qi], s); s = mfma16(kh1##S, ql1v[qi], s); \
        s = mfma16(kl0##S, qh0v[qi], s); s = mfma16(kl1##S, qh1v[qi], s); \
        lsum[qi] += (__expf(s[0] * 0.125f) + __expf(s[1] * 0.125f)) + \
                    (__expf(s[2] * 0.125f) + __expf(s[3] * 0.125f)); } }

__global__ __launch_bounds__(256)
void attn_lsum(const u16* __restrict__ Qhi, const u16* __restrict__ Qlo,
               const u16* __restrict__ Khi, const u16* __restrict__ Klo,
               float* __restrict__ llog) {
    __shared__ float sLA[4][4][16];
    const int t = threadIdx.x;
    const int wv = t >> 6;
    const int lane = t & 63;
    const int g = lane >> 4, c16 = lane & 15;
    const int qt = blockIdx.x & 15;
    const int bh = blockIdx.x >> 4;       // b*16 + h
    const int h = bh & 15, b = bh >> 4;
    const int qbase = qt * 64;
    const int kslab = wv * 512;

    s16x8 qh0v[4], qh1v[4], ql0v[4], ql1v[4];
#pragma unroll
    for (int qi = 0; qi < 4; ++qi) {
        size_t qo = (size_t)(b * SQL + qbase + qi * 16 + c16) * EMBED + h * HDIM + g * 8;
        qh0v[qi] = *(const s16x8*)&Qhi[qo];
        qh1v[qi] = *(const s16x8*)&Qhi[qo + 32];
        ql0v[qi] = *(const s16x8*)&Qlo[qo];
        ql1v[qi] = *(const s16x8*)&Qlo[qo + 32];
    }
    float lsum[4] = {0.f, 0.f, 0.f, 0.f};
    s16x8 kh0a, kh1a, kl0a, kl1a, kh0b, kh1b, kl0b, kl1b;

    ALOADK(a, 0)
    for (int sub = 0; sub < 32; sub += 2) {
        ALOADK(b, sub + 1)
        ACOMP(a)
        if (sub + 2 < 32) ALOADK(a, sub + 2)
        ACOMP(b)
    }

#pragma unroll
    for (int qi = 0; qi < 4; ++qi) {
        float v = lsum[qi];
        v += __shfl_xor(v, 16, 64);
        v += __shfl_xor(v, 32, 64);
        if (lane < 16) sLA[wv][qi][c16] = v;
    }
    __syncthreads();
    if (t < 64) {
        int qi = t >> 4, qc = t & 15;
        float l = sLA[0][qi][qc] + sLA[1][qi][qc] + sLA[2][qi][qc] + sLA[3][qi][qc];
        llog[(size_t)bh * SQL + qbase + qi * 16 + qc] = log2f(l);
    }
}

// ---------------------------------------------------------------------------
// Kernel B: main attention with precomputed denominators.
// Block = (b, qtile16, kslab of 512): grid 1024, 512 thr (8 waves), 2
// blocks/CU (launch_bounds(512,4) -> <=128 VGPR). Wave w owns k in
// [ks*512 + w*64, +64): 4 subchunks of 16 k, double-buffered reg prefetch.
// p = exp2(s*scale*log2e - log2(l)) is FINAL -> mean accumulates in 16 regs;
// PV via swapped-operand 16x16x16 (p regs ARE the B-frag; no P LDS, no
// barrier in the k/h inner loop). Per head: pad-17 LDS reduce of 8 waves'
// O^T then one bf16 O-partial write per kslab. blockIdx low bits = (b,ks)
// so each of the 16 K/V streams pins to one XCD's L2.
// ---------------------------------------------------------------------------
#define BLOADKV(S, sub) { \
    size_t _kr = (size_t)(b * SKL + kbase + (sub) * 16 + c16) * EMBED + h * HDIM + g * 8; \
    kh0##S = *(const s16x8*)&Khi[_kr]; kh1##S = *(const s16x8*)&Khi[_kr + 32]; \
    kl0##S = *(const s16x8*)&Klo[_kr]; kl1##S = *(const s16x8*)&Klo[_kr + 32]; \
    size_t _vc = (size_t)b * SKL + kbase + (sub) * 16 + g * 4; \
    vv0##S = *(const s16x4*)&VT[(size_t)(h * HDIM +  0 + c16) * (BATCH * SKL) + _vc]; \
    vv1##S = *(const s16x4*)&VT[(size_t)(h * HDIM + 16 + c16) * (BATCH * SKL) + _vc]; \
    vv2##S = *(const s16x4*)&VT[(size_t)(h * HDIM + 32 + c16) * (BATCH * SKL) + _vc]; \
    vv3##S = *(const s16x4*)&VT[(size_t)(h * HDIM + 48 + c16) * (BATCH * SKL) + _vc]; }

#define BCOMP(S, sub) { \
    f32x4 s = {0.f, 0.f, 0.f, 0.f}; \
    s = mfma16(kh0##S, qh0, s); s = mfma16(kh1##S, qh1, s); \
    s = mfma16(kh0##S, ql0, s); s = mfma16(kh1##S, ql1, s); \
    s = mfma16(kl0##S, qh0, s); s = mfma16(kl1##S, qh1, s); \
    float p0 = exp2f(s[0] * 0.18033688f - lb); \
    float p1 = exp2f(s[1] * 0.18033688f - lb); \
    float p2 = exp2f(s[2] * 0.18033688f - lb); \
    float p3 = exp2f(s[3] * 0.18033688f - lb); \
    meanacc[sub][0] += p0; meanacc[sub][1] += p1; \
    meanacc[sub][2] += p2; meanacc[sub][3] += p3; \
    s16x4 pb; \
    pb[0] = (short)f2bf(p0); pb[1] = (short)f2bf(p1); \
    pb[2] = (short)f2bf(p2); pb[3] = (short)f2bf(p3); \
    oacc[0] = mfma16k16(vv0##S, pb, oacc[0]); \
    oacc[1] = mfma16k16(vv1##S, pb, oacc[1]); \
    oacc[2] = mfma16k16(vv2##S, pb, oacc[2]); \
    oacc[3] = mfma16k16(vv3##S, pb, oacc[3]); }

__global__ __launch_bounds__(512, 4)
void attn_main(const u16* __restrict__ Qhi, const u16* __restrict__ Qlo,
               const u16* __restrict__ Khi, const u16* __restrict__ Klo,
               const u16* __restrict__ VT, const float* __restrict__ llog,
               u16* __restrict__ Op01, u16* __restrict__ Op23,
               float* __restrict__ meanOut) {
    __shared__ float sO[8 * 1088];   // [w][d*17 + q], 34.8 KB

    const int t = threadIdx.x;
    const int w = t >> 6;
    const int lane = t & 63;
    const int g = lane >> 4, c16 = lane & 15;
    const int gg = blockIdx.x & 15;   // (b, ks) -> XCD group
    const int qt = blockIdx.x >> 4;
    const int b = gg >> 2, ks = gg & 3;
    const int qbase = qt * 16;
    const int kbase = ks * 512 + w * 64;

    u16* Opart = (ks & 2) ? Op23 : Op01;
    const size_t opslab = (size_t)(ks & 1) * (4096UL * 1024);

    float meanacc[4][4];
#pragma unroll
    for (int i = 0; i < 4; ++i)
#pragma unroll
        for (int j = 0; j < 4; ++j) meanacc[i][j] = 0.f;

    for (int h = 0; h < NHEADS; ++h) {
        size_t qo = (size_t)(b * SQL + qbase + c16) * EMBED + h * HDIM + g * 8;
        s16x8 qh0 = *(const s16x8*)&Qhi[qo];
        s16x8 qh1 = *(const s16x8*)&Qhi[qo + 32];
        s16x8 ql0 = *(const s16x8*)&Qlo[qo];
        s16x8 ql1 = *(const s16x8*)&Qlo[qo + 32];
        float lb = llog[(size_t)(b * 16 + h) * SQL + qbase + c16];

        f32x4 oacc[4];
#pragma unroll
        for (int mi = 0; mi < 4; ++mi) oacc[mi] = (f32x4){0.f, 0.f, 0.f, 0.f};

        s16x8 kh0a, kh1a, kl0a, kl1a, kh0b, kh1b, kl0b, kl1b;
        s16x4 vv0a, vv1a, vv2a, vv3a, vv0b, vv1b, vv2b, vv3b;

        BLOADKV(a, 0)
        BLOADKV(b, 1)
        BCOMP(a, 0)
        BLOADKV(a, 2)
        BCOMP(b, 1)
        BLOADKV(b, 3)
        BCOMP(a, 2)
        BCOMP(b, 3)

        // ---- per-head: cross-wave O^T reduce -> bf16 O-partial
#pragma unroll
        for (int mi = 0; mi < 4; ++mi)
#pragma unroll
            for (int r = 0; r < 4; ++r)
                sO[w * 1088 + (mi * 16 + g * 4 + r) * 17 + c16] = oacc[mi][r];
        __syncthreads();
#pragma unroll
        for (int rep = 0; rep < 2; ++rep) {
            int idx = rep * 512 + t;
            int qq = idx >> 6, d = idx & 63;
            float o = 0.f;
#pragma unroll
            for (int ww = 0; ww < 8; ++ww) o += sO[ww * 1088 + d * 17 + qq];
            Opart[opslab + (size_t)(b * SQL + qbase + qq) * EMBED + h * HDIM + d] = f2bf(o);
        }
        __syncthreads();
    }

    // ---- mean write: q = c16, k = kbase + sub*16 + g*4 + r (exclusive owner)
    const float s16c = 1.f / 16.f;
#pragma unroll
    for (int sub = 0; sub < 4; ++sub) {
        f32x4 m;
#pragma unroll
        for (int r = 0; r < 4; ++r) m[r] = meanacc[sub][r] * s16c;
        *(f32x4*)&meanOut[(size_t)(b * SQL + qbase + c16) * SKL + kbase + sub * 16 + g * 4] = m;
    }
}

// ---------------------------------------------------------------------------
// Sum the 4 bf16 O-partial slabs -> Att bf16 (feeds the out-projection).
// ---------------------------------------------------------------------------
__global__ __launch_bounds__(256)
void osum(const u16* __restrict__ Op01, const u16* __restrict__ Op23,
          u16* __restrict__ Att) {
    const size_t SLAB = 4096UL * 1024;
    size_t i = ((size_t)blockIdx.x * 256 + threadIdx.x) * 8;
    u16x8 a = *(const u16x8*)&Op01[i];
    u16x8 b = *(const u16x8*)&Op01[SLAB + i];
    u16x8 c = *(const u16x8*)&Op23[i];
    u16x8 d = *(const u16x8*)&Op23[SLAB + i];
    u16x8 o;
#pragma unroll
    for (int j = 0; j < 8; ++j)
        o[j] = f2bf((bf2f(a[j]) + bf2f(b[j])) + (bf2f(c[j]) + bf2f(d[j])));
    *(u16x8*)&Att[i] = o;
}

// ---------------------------------------------------------------------------
extern "C" void kernel_launch(void* const* d_in, const int* in_sizes, int n_in,
                              void* d_out, int out_size, void* d_ws, size_t ws_size,
                              hipStream_t stream) {
    const float* query = (const float*)d_in[0];
    const float* key   = (const float*)d_in[1];
    const float* value = (const float*)d_in[2];
    const float* Wq = (const float*)d_in[3];
    const float* bq = (const float*)d_in[4];
    const float* Wk = (const float*)d_in[5];
    const float* bk = (const float*)d_in[6];
    const float* Wv = (const float*)d_in[7];
    const float* bv = (const float*)d_in[8];
    const float* Wo = (const float*)d_in[9];
    const float* bo = (const float*)d_in[10];

    float* out = (float*)d_out;                         // [4,1024,1024] f32
    float* meanOut = out + (size_t)BATCH * SQL * EMBED; // [4,1024,2048] f32

    u16* Qhi = (u16*)d_ws;                              // 8.39MB (later aliased by Att)
    u16* Qlo = Qhi + (size_t)4096 * 1024;               // 8.39MB
    u16* Khi = Qlo + (size_t)4096 * 1024;               // 16.78MB
    u16* Klo = Khi + (size_t)8192 * 1024;               // 16.78MB
    u16* VTw = Klo + (size_t)8192 * 1024;               // 16.78MB (V^T)
    float* llog = (float*)(VTw + (size_t)1024 * 8192);  // 256KB: log2(l)[b][h][q]
    u16* Op23 = (u16*)(llog + 64 * 1024);               // slabs 2,3: 16.78MB
    u16* Op01 = (u16*)d_out;                            // slabs 0,1 park in out0 region
    u16* Att = Qhi;                                     // alias: Q dead after attn_main

    // projections
    gemm_mfma<1, 0, 1><<<dim3(8, 32), 256, 0, stream>>>(query, Wq, bq, Qhi, Qlo, 4096, 1024);
    gemm_mfma<1, 0, 1><<<dim3(8, 64), 256, 0, stream>>>(key, Wk, bk, Khi, Klo, 8192, 1024);
    gemm_mfma<0, 0, 2><<<dim3(64, 8), 256, 0, stream>>>(Wv, value, bv, VTw, nullptr, 1024, 8192);
    // attention: denominators, then main
    attn_lsum<<<dim3(1024), dim3(256), 0, stream>>>(Qhi, Qlo, Khi, Klo, llog);
    attn_main<<<dim3(1024), dim3(512), 0, stream>>>(Qhi, Qlo, Khi, Klo, VTw, llog,
                                                    Op01, Op23, meanOut);
    // fold O-partials and project out
    osum<<<dim3(2048), dim3(256), 0, stream>>>(Op01, Op23, Att);
    gemm_mfma<0, 1, 0><<<dim3(8, 32), 256, 0, stream>>>(Att, Wo, bo, out, nullptr, 4096, 1024);
}

// Round 7
// 375.670 us; speedup vs baseline: 2.0364x; 2.0364x over previous
//
#include <hip/hip_runtime.h>
#include <hip/hip_bf16.h>
#include <math.h>

#define EMBED 1024
#define NHEADS 16
#define HDIM 64
#define BATCH 4
#define SQL 1024
#define SKL 2048
#define PSC 0.18033688f   // 0.125 * log2(e)

typedef unsigned short u16;
typedef __attribute__((ext_vector_type(4))) float f32x4;
typedef __attribute__((ext_vector_type(8))) __bf16 bf16x8;
typedef __attribute__((ext_vector_type(8))) short s16x8;
typedef __attribute__((ext_vector_type(4))) short s16x4;
typedef __attribute__((ext_vector_type(8))) u16 u16x8;

__device__ __forceinline__ u16 f2bf(float x) {
    __hip_bfloat16 h = __float2bfloat16(x);
    return *reinterpret_cast<u16*>(&h);
}
__device__ __forceinline__ float bf2f(u16 u) {
    __hip_bfloat16 h;
    *reinterpret_cast<u16*>(&h) = u;
    return __bfloat162float(h);
}
__device__ __forceinline__ f32x4 mfma16(s16x8 a, s16x8 b, f32x4 c) {
    return __builtin_amdgcn_mfma_f32_16x16x32_bf16(
        __builtin_bit_cast(bf16x8, a), __builtin_bit_cast(bf16x8, b), c, 0, 0, 0);
}
__device__ __forceinline__ f32x4 mfma16k16(s16x4 a, s16x4 b, f32x4 c) {
    return __builtin_amdgcn_mfma_f32_16x16x16bf16_1k(a, b, c, 0, 0, 0);
}
__device__ __forceinline__ void gload16(const void* g, void* l) {
    __builtin_amdgcn_global_load_lds(
        (const __attribute__((address_space(1))) void*)g,
        (__attribute__((address_space(3))) void*)l, 16, 0, 0);
}
// Stage one 8KB plane (64 rows x 128B) with XOR-preswizzled source.
// LDS chunk (r, c) receives global chunk (r, c ^ (r&7)).  Dest is wave-uniform.
__device__ __forceinline__ void stage8k(const char* g, size_t rstrideB,
                                        char* ldsPlane, int w, int lane) {
    int r = w * 8 + (lane >> 3);
    int cs = (lane & 7) ^ (r & 7);
    gload16(g + (size_t)r * rstrideB + cs * 16, ldsPlane + (size_t)w * 1024);
}
#define WAIT_STAGE() { asm volatile("s_waitcnt vmcnt(0)" ::: "memory"); \
    __builtin_amdgcn_sched_barrier(0); __builtin_amdgcn_s_barrier(); \
    __builtin_amdgcn_sched_barrier(0); }

#define QK6(s, kh0, kh1, kl0, kl1, q0, q1, q2, q3) \
    s = mfma16(kh0, q0, s); s = mfma16(kh1, q1, s); \
    s = mfma16(kh0, q2, s); s = mfma16(kh1, q3, s); \
    s = mfma16(kl0, q0, s); s = mfma16(kl1, q1, s);

// ---------------------------------------------------------------------------
// GEMM NT: Y = A * W^T + bias. K=1024. 128x128 tile, proven structure.
// OUT_MODE 0: f32 + bias[col].  1: bf16 hi/lo + bias[col] (flat).
// 3: bf16 hi/lo head-major [b][h][s][64] (+bias[col]); sl = 1<<bshift.
// 4: bf16 V^T head-major [b][h][d][2048] (+bias[row]).
// ---------------------------------------------------------------------------
template<int SPLIT, int A_BF16, int OUT_MODE>
__global__ __launch_bounds__(256)
void gemm_mfma(const void* __restrict__ Ap, const float* __restrict__ Wp,
               const float* __restrict__ bias,
               void* __restrict__ Y0p, void* __restrict__ Y1p,
               int M, int N, int bshift) {
    const int K = 1024;
    __shared__ u16 sA[2][128 * 40];
    __shared__ u16 sB[2][128 * 40];

    const int t = threadIdx.x;
    const int lane = t & 63;
    const int w = t >> 6;
    const int wm = w >> 1, wn = w & 1;
    const int rowBase = blockIdx.y * 128;
    const int colBase = blockIdx.x * 128;
    const int srow = t >> 1;
    const int sc = (t & 1) * 16;

    const float* Af = (const float*)Ap;
    const u16* Au = (const u16*)Ap;

    f32x4 acc[4][4];
#pragma unroll
    for (int i = 0; i < 4; ++i)
#pragma unroll
        for (int j = 0; j < 4; ++j) acc[i][j] = (f32x4){0.f, 0.f, 0.f, 0.f};

    float ax[16], bx[16];
    u16x8 au0, au1;
    {
        if constexpr (A_BF16) {
            au0 = *(const u16x8*)&Au[(size_t)(rowBase + srow) * K + sc];
            au1 = *(const u16x8*)&Au[(size_t)(rowBase + srow) * K + sc + 8];
        } else {
#pragma unroll
            for (int j = 0; j < 4; ++j)
                *(float4*)&ax[j * 4] = *(const float4*)&Af[(size_t)(rowBase + srow) * K + sc + j * 4];
        }
#pragma unroll
        for (int j = 0; j < 4; ++j)
            *(float4*)&bx[j * 4] = *(const float4*)&Wp[(size_t)(colBase + srow) * K + sc + j * 4];
    }

    for (int k0 = 0; k0 < K; k0 += 32) {
        __syncthreads();
        {
            u16x8 h0, h1, l0, l1;
            if constexpr (A_BF16) {
                h0 = au0; h1 = au1;
            } else {
#pragma unroll
                for (int j = 0; j < 8; ++j) {
                    h0[j] = f2bf(ax[j]); h1[j] = f2bf(ax[j + 8]);
                    if constexpr (SPLIT) {
                        l0[j] = f2bf(ax[j] - bf2f(h0[j]));
                        l1[j] = f2bf(ax[j + 8] - bf2f(h1[j]));
                    }
                }
            }
            *(u16x8*)&sA[0][srow * 40 + sc] = h0;
            *(u16x8*)&sA[0][srow * 40 + sc + 8] = h1;
            if constexpr (SPLIT) {
                *(u16x8*)&sA[1][srow * 40 + sc] = l0;
                *(u16x8*)&sA[1][srow * 40 + sc + 8] = l1;
            }
            u16x8 bh0, bh1, bl0, bl1;
#pragma unroll
            for (int j = 0; j < 8; ++j) {
                bh0[j] = f2bf(bx[j]); bh1[j] = f2bf(bx[j + 8]);
                if constexpr (SPLIT) {
                    bl0[j] = f2bf(bx[j] - bf2f(bh0[j]));
                    bl1[j] = f2bf(bx[j + 8] - bf2f(bh1[j]));
                }
            }
            *(u16x8*)&sB[0][srow * 40 + sc] = bh0;
            *(u16x8*)&sB[0][srow * 40 + sc + 8] = bh1;
            if constexpr (SPLIT) {
                *(u16x8*)&sB[1][srow * 40 + sc] = bl0;
                *(u16x8*)&sB[1][srow * 40 + sc + 8] = bl1;
            }
        }
        __syncthreads();
        if (k0 + 32 < K) {
            const int kn = k0 + 32;
            if constexpr (A_BF16) {
                au0 = *(const u16x8*)&Au[(size_t)(rowBase + srow) * K + kn + sc];
                au1 = *(const u16x8*)&Au[(size_t)(rowBase + srow) * K + kn + sc + 8];
            } else {
#pragma unroll
                for (int j = 0; j < 4; ++j)
                    *(float4*)&ax[j * 4] = *(const float4*)&Af[(size_t)(rowBase + srow) * K + kn + sc + j * 4];
            }
#pragma unroll
            for (int j = 0; j < 4; ++j)
                *(float4*)&bx[j * 4] = *(const float4*)&Wp[(size_t)(colBase + srow) * K + kn + sc + j * 4];
        }
        {
            s16x8 afh[4], afl[4], bfh[4], bfl[4];
#pragma unroll
            for (int mi = 0; mi < 4; ++mi) {
                int ai = (wm * 64 + mi * 16 + (lane & 15)) * 40 + (lane >> 4) * 8;
                afh[mi] = *(const s16x8*)&sA[0][ai];
                if constexpr (SPLIT) afl[mi] = *(const s16x8*)&sA[1][ai];
            }
#pragma unroll
            for (int ni = 0; ni < 4; ++ni) {
                int bi = (wn * 64 + ni * 16 + (lane & 15)) * 40 + (lane >> 4) * 8;
                bfh[ni] = *(const s16x8*)&sB[0][bi];
                if constexpr (SPLIT) bfl[ni] = *(const s16x8*)&sB[1][bi];
            }
#pragma unroll
            for (int mi = 0; mi < 4; ++mi)
#pragma unroll
                for (int ni = 0; ni < 4; ++ni) {
                    acc[mi][ni] = mfma16(afh[mi], bfh[ni], acc[mi][ni]);
                    if constexpr (SPLIT) {
                        acc[mi][ni] = mfma16(afh[mi], bfl[ni], acc[mi][ni]);
                        acc[mi][ni] = mfma16(afl[mi], bfh[ni], acc[mi][ni]);
                    }
                }
        }
    }

#pragma unroll
    for (int mi = 0; mi < 4; ++mi)
#pragma unroll
        for (int ni = 0; ni < 4; ++ni)
#pragma unroll
            for (int rr = 0; rr < 4; ++rr) {
                int mg = rowBase + wm * 64 + mi * 16 + (lane >> 4) * 4 + rr;
                int ng = colBase + wn * 64 + ni * 16 + (lane & 15);
                float y = acc[mi][ni][rr];
                if constexpr (OUT_MODE == 0) {
                    ((float*)Y0p)[(size_t)mg * N + ng] = y + bias[ng];
                } else if constexpr (OUT_MODE == 1) {
                    y += bias[ng];
                    u16 hh = f2bf(y);
                    ((u16*)Y0p)[(size_t)mg * N + ng] = hh;
                    ((u16*)Y1p)[(size_t)mg * N + ng] = f2bf(y - bf2f(hh));
                } else if constexpr (OUT_MODE == 3) {
                    y += bias[ng];
                    int bb = mg >> bshift, s = mg & ((1 << bshift) - 1);
                    size_t idx = ((((size_t)(bb * 16 + (ng >> 6))) << bshift) + s) * 64 + (ng & 63);
                    u16 hh = f2bf(y);
                    ((u16*)Y0p)[idx] = hh;
                    ((u16*)Y1p)[idx] = f2bf(y - bf2f(hh));
                } else if constexpr (OUT_MODE == 4) {
                    y += bias[mg];
                    size_t idx = ((size_t)((ng >> 11) * 16 + (mg >> 6)) * 64 + (mg & 63)) * 2048 + (ng & 2047);
                    ((u16*)Y0p)[idx] = f2bf(y);
                }
            }
}

// ---------------------------------------------------------------------------
// Pass 1: softmax denominators. Block=(b,h,qtile128), 512 thr (8 waves =
// 4wq x 2wk). Q staged once (hi/lo 32KB LDS), K chunks of 64k dbuf (2x16KB).
// One barrier + vmcnt(0) per chunk; staging issued after the wait so loads
// fly under compute. Swapped QK^T: D[k][q], lane = (q=c16, k=g*4+r).
// ---------------------------------------------------------------------------
__global__ __launch_bounds__(512, 4)
void attn_lsum(const u16* __restrict__ Qhi, const u16* __restrict__ Qlo,
               const u16* __restrict__ Khi, const u16* __restrict__ Klo,
               float* __restrict__ llog) {
    __shared__ char lds[65536];      // Qh 16K | Ql 16K | K dbuf 2x(hi8K+lo8K)
    __shared__ float sLA[2][4][2][16];
    char* sQh = lds;
    char* sQl = lds + 16384;

    const int t = threadIdx.x;
    const int w = t >> 6, lane = t & 63;
    const int g = lane >> 4, c16 = lane & 15;
    const int qt = blockIdx.x >> 6;
    const int b = (blockIdx.x >> 4) & 3;
    const int h = blockIdx.x & 15;
    const int qbase = qt * 128;
    const int wq = w >> 1, wk = w & 1;
    const int kswz = (g ^ (c16 & 7)) << 4;

    const char* Qh_g = (const char*)(Qhi + ((size_t)(b * 16 + h) * SQL + qbase) * 64);
    const char* Ql_g = (const char*)(Qlo + ((size_t)(b * 16 + h) * SQL + qbase) * 64);
    const char* Kh_g = (const char*)(Khi + (size_t)(b * 16 + h) * SKL * 64);
    const char* Kl_g = (const char*)(Klo + (size_t)(b * 16 + h) * SKL * 64);

    stage8k(Qh_g, 128, sQh, w, lane);
    stage8k(Qh_g + 8192, 128, sQh + 8192, w, lane);
    stage8k(Ql_g, 128, sQl, w, lane);
    stage8k(Ql_g + 8192, 128, sQl + 8192, w, lane);
    stage8k(Kh_g, 128, lds + 32768, w, lane);
    stage8k(Kl_g, 128, lds + 32768 + 8192, w, lane);

    s16x8 qh[2][2], ql[2][2];
    float ls0 = 0.f, ls1 = 0.f;

    for (int c = 0; c < 32; ++c) {
        WAIT_STAGE();
        if (c == 0) {
#pragma unroll
            for (int qf = 0; qf < 2; ++qf) {
                int qb = (wq * 32 + qf * 16 + c16) * 128 + kswz;
                qh[qf][0] = *(const s16x8*)(sQh + qb);
                qh[qf][1] = *(const s16x8*)(sQh + (qb ^ 64));
                ql[qf][0] = *(const s16x8*)(sQl + qb);
                ql[qf][1] = *(const s16x8*)(sQl + (qb ^ 64));
            }
        }
        if (c < 31) {
            char* nb = lds + 32768 + ((c + 1) & 1) * 16384;
            stage8k(Kh_g + (size_t)(c + 1) * 8192, 128, nb, w, lane);
            stage8k(Kl_g + (size_t)(c + 1) * 8192, 128, nb + 8192, w, lane);
        }
        char* curK = lds + 32768 + (c & 1) * 16384;
#pragma unroll
        for (int kf = 0; kf < 2; ++kf) {
            int kb = (wk * 32 + kf * 16 + c16) * 128 + kswz;
            s16x8 kh0 = *(const s16x8*)(curK + kb);
            s16x8 kh1 = *(const s16x8*)(curK + (kb ^ 64));
            s16x8 kl0 = *(const s16x8*)(curK + 8192 + kb);
            s16x8 kl1 = *(const s16x8*)(curK + 8192 + (kb ^ 64));
            f32x4 s0 = {0.f, 0.f, 0.f, 0.f}, s1 = {0.f, 0.f, 0.f, 0.f};
            QK6(s0, kh0, kh1, kl0, kl1, qh[0][0], qh[0][1], ql[0][0], ql[0][1])
            QK6(s1, kh0, kh1, kl0, kl1, qh[1][0], qh[1][1], ql[1][0], ql[1][1])
            ls0 += (__expf(s0[0] * 0.125f) + __expf(s0[1] * 0.125f)) +
                   (__expf(s0[2] * 0.125f) + __expf(s0[3] * 0.125f));
            ls1 += (__expf(s1[0] * 0.125f) + __expf(s1[1] * 0.125f)) +
                   (__expf(s1[2] * 0.125f) + __expf(s1[3] * 0.125f));
        }
    }

    ls0 += __shfl_xor(ls0, 16, 64); ls0 += __shfl_xor(ls0, 32, 64);
    ls1 += __shfl_xor(ls1, 16, 64); ls1 += __shfl_xor(ls1, 32, 64);
    if (g == 0) { sLA[wk][wq][0][c16] = ls0; sLA[wk][wq][1][c16] = ls1; }
    __syncthreads();
    if (t < 128) {
        float l = sLA[0][t >> 5][(t >> 4) & 1][t & 15] +
                  sLA[1][t >> 5][(t >> 4) & 1][t & 15];
        llog[(size_t)(b * 16 + h) * SQL + qbase + t] = log2f(l);
    }
}

// ---------------------------------------------------------------------------
// Pass 2: mean_attn. Block=(b,qtile64,kslab256), loops 16 heads; p final via
// llog; mean lives in 8 f32x4 regs (exclusive (q,k) cells). K-only staging
// (Q 16KB + K dbuf 2x16KB). meanOut written once at the end.
// ---------------------------------------------------------------------------
__global__ __launch_bounds__(512, 4)
void attn_mean(const u16* __restrict__ Qhi, const u16* __restrict__ Qlo,
               const u16* __restrict__ Khi, const u16* __restrict__ Klo,
               const float* __restrict__ llog, float* __restrict__ meanOut) {
    __shared__ char lds[49152];      // Qh 8K | Ql 8K | K dbuf 2x(hi8K+lo8K)
    char* sQh = lds;
    char* sQl = lds + 8192;

    const int t = threadIdx.x;
    const int w = t >> 6, lane = t & 63;
    const int g = lane >> 4, c16 = lane & 15;
    const int qt = blockIdx.x >> 5;
    const int b = (blockIdx.x >> 3) & 3;
    const int ks = blockIdx.x & 7;
    const int qbase = qt * 64;
    const int kbase = ks * 256;
    const int wq = w >> 1, wk = w & 1;
    const int kswz = (g ^ (c16 & 7)) << 4;

    f32x4 ma[8];
#pragma unroll
    for (int i = 0; i < 8; ++i) ma[i] = (f32x4){0.f, 0.f, 0.f, 0.f};

    for (int h = 0; h < NHEADS; ++h) {
        const char* Qh_g = (const char*)(Qhi + ((size_t)(b * 16 + h) * SQL + qbase) * 64);
        const char* Ql_g = (const char*)(Qlo + ((size_t)(b * 16 + h) * SQL + qbase) * 64);
        const char* Kh_g = (const char*)(Khi + ((size_t)(b * 16 + h) * SKL + kbase) * 64);
        const char* Kl_g = (const char*)(Klo + ((size_t)(b * 16 + h) * SKL + kbase) * 64);
        float lb = llog[(size_t)(b * 16 + h) * SQL + qbase + wq * 16 + c16];

        stage8k(Qh_g, 128, sQh, w, lane);
        stage8k(Ql_g, 128, sQl, w, lane);
        stage8k(Kh_g, 128, lds + 16384, w, lane);
        stage8k(Kl_g, 128, lds + 16384 + 8192, w, lane);

        s16x8 qh0, qh1, ql0, ql1;
#pragma unroll
        for (int c = 0; c < 4; ++c) {
            WAIT_STAGE();
            if (c == 0) {
                int qb = (wq * 16 + c16) * 128 + kswz;
                qh0 = *(const s16x8*)(sQh + qb);
                qh1 = *(const s16x8*)(sQh + (qb ^ 64));
                ql0 = *(const s16x8*)(sQl + qb);
                ql1 = *(const s16x8*)(sQl + (qb ^ 64));
            }
            if (c < 3) {
                char* nb = lds + 16384 + ((c + 1) & 1) * 16384;
                stage8k(Kh_g + (size_t)(c + 1) * 8192, 128, nb, w, lane);
                stage8k(Kl_g + (size_t)(c + 1) * 8192, 128, nb + 8192, w, lane);
            }
            char* curK = lds + 16384 + (c & 1) * 16384;
#pragma unroll
            for (int kf = 0; kf < 2; ++kf) {
                int kb = (wk * 32 + kf * 16 + c16) * 128 + kswz;
                s16x8 kh0 = *(const s16x8*)(curK + kb);
                s16x8 kh1 = *(const s16x8*)(curK + (kb ^ 64));
                s16x8 kl0 = *(const s16x8*)(curK + 8192 + kb);
                s16x8 kl1 = *(const s16x8*)(curK + 8192 + (kb ^ 64));
                f32x4 s = {0.f, 0.f, 0.f, 0.f};
                QK6(s, kh0, kh1, kl0, kl1, qh0, qh1, ql0, ql1)
                ma[c * 2 + kf][0] += exp2f(s[0] * PSC - lb);
                ma[c * 2 + kf][1] += exp2f(s[1] * PSC - lb);
                ma[c * 2 + kf][2] += exp2f(s[2] * PSC - lb);
                ma[c * 2 + kf][3] += exp2f(s[3] * PSC - lb);
            }
        }
    }

    const float s16c = 1.f / 16.f;
#pragma unroll
    for (int c = 0; c < 4; ++c)
#pragma unroll
        for (int kf = 0; kf < 2; ++kf) {
            f32x4 m = ma[c * 2 + kf];
            m[0] *= s16c; m[1] *= s16c; m[2] *= s16c; m[3] *= s16c;
            *(f32x4*)&meanOut[(size_t)(b * SQL + qbase + wq * 16 + c16) * SKL +
                              kbase + c * 64 + wk * 32 + kf * 16 + g * 4] = m;
        }
}

// ---------------------------------------------------------------------------
// Pass 3: attended output (flash, p final via llog). Block=(b,h,qtile64),
// 512 thr (4wq x 2wk), 32 chunks of 64k, K+V dbuf. oacc f32 in regs across
// all chunks; single cross-wk LDS reduce at the end -> bf16 Att (no partials).
// ---------------------------------------------------------------------------
__global__ __launch_bounds__(512, 4)
void attn_O(const u16* __restrict__ Qhi, const u16* __restrict__ Qlo,
            const u16* __restrict__ Khi, const u16* __restrict__ Klo,
            const u16* __restrict__ VT, const float* __restrict__ llog,
            u16* __restrict__ Att) {
    __shared__ char lds[65536];  // Qh8K|Ql8K| K dbuf 2x16K @16384 | V dbuf 2x8K @49152
    char* sQh = lds;
    char* sQl = lds + 8192;
    float* sOf = (float*)(lds + 16384);   // reduce scratch [2][64][68], aliases K

    const int t = threadIdx.x;
    const int w = t >> 6, lane = t & 63;
    const int g = lane >> 4, c16 = lane & 15;
    const int qt = blockIdx.x >> 6;
    const int b = (blockIdx.x >> 4) & 3;
    const int h = blockIdx.x & 15;
    const int qbase = qt * 64;
    const int wq = w >> 1, wk = w & 1;
    const int kswz = (g ^ (c16 & 7)) << 4;
    const int vsw0 = (((wk * 4 + 0 + (g >> 1)) ^ (c16 & 7)) << 4) | ((g & 1) << 3);
    const int vsw1 = (((wk * 4 + 2 + (g >> 1)) ^ (c16 & 7)) << 4) | ((g & 1) << 3);

    const char* Qh_g = (const char*)(Qhi + ((size_t)(b * 16 + h) * SQL + qbase) * 64);
    const char* Ql_g = (const char*)(Qlo + ((size_t)(b * 16 + h) * SQL + qbase) * 64);
    const char* Kh_g = (const char*)(Khi + (size_t)(b * 16 + h) * SKL * 64);
    const char* Kl_g = (const char*)(Klo + (size_t)(b * 16 + h) * SKL * 64);
    const char* V_g  = (const char*)(VT + (size_t)(b * 16 + h) * 64 * SKL);

    float lb = llog[(size_t)(b * 16 + h) * SQL + qbase + wq * 16 + c16];

    stage8k(Qh_g, 128, sQh, w, lane);
    stage8k(Ql_g, 128, sQl, w, lane);
    stage8k(Kh_g, 128, lds + 16384, w, lane);
    stage8k(Kl_g, 128, lds + 16384 + 8192, w, lane);
    stage8k(V_g, 4096, lds + 49152, w, lane);

    s16x8 qh0, qh1, ql0, ql1;
    f32x4 oacc[4];
#pragma unroll
    for (int i = 0; i < 4; ++i) oacc[i] = (f32x4){0.f, 0.f, 0.f, 0.f};

    for (int c = 0; c < 32; ++c) {
        WAIT_STAGE();
        if (c == 0) {
            int qb = (wq * 16 + c16) * 128 + kswz;
            qh0 = *(const s16x8*)(sQh + qb);
            qh1 = *(const s16x8*)(sQh + (qb ^ 64));
            ql0 = *(const s16x8*)(sQl + qb);
            ql1 = *(const s16x8*)(sQl + (qb ^ 64));
        }
        if (c < 31) {
            char* nbK = lds + 16384 + ((c + 1) & 1) * 16384;
            char* nbV = lds + 49152 + ((c + 1) & 1) * 8192;
            stage8k(Kh_g + (size_t)(c + 1) * 8192, 128, nbK, w, lane);
            stage8k(Kl_g + (size_t)(c + 1) * 8192, 128, nbK + 8192, w, lane);
            stage8k(V_g + (size_t)(c + 1) * 128, 4096, nbV, w, lane);
        }
        char* curK = lds + 16384 + (c & 1) * 16384;
        char* curV = lds + 49152 + (c & 1) * 8192;
#pragma unroll
        for (int kf = 0; kf < 2; ++kf) {
            int kb = (wk * 32 + kf * 16 + c16) * 128 + kswz;
            s16x8 kh0 = *(const s16x8*)(curK + kb);
            s16x8 kh1 = *(const s16x8*)(curK + (kb ^ 64));
            s16x8 kl0 = *(const s16x8*)(curK + 8192 + kb);
            s16x8 kl1 = *(const s16x8*)(curK + 8192 + (kb ^ 64));
            f32x4 s = {0.f, 0.f, 0.f, 0.f};
            QK6(s, kh0, kh1, kl0, kl1, qh0, qh1, ql0, ql1)
            s16x4 pb;
            pb[0] = (short)f2bf(exp2f(s[0] * PSC - lb));
            pb[1] = (short)f2bf(exp2f(s[1] * PSC - lb));
            pb[2] = (short)f2bf(exp2f(s[2] * PSC - lb));
            pb[3] = (short)f2bf(exp2f(s[3] * PSC - lb));
            int vs = kf ? vsw1 : vsw0;
#pragma unroll
            for (int df = 0; df < 4; ++df) {
                s16x4 vf = *(const s16x4*)(curV + (df * 16 + c16) * 128 + vs);
                oacc[df] = mfma16k16(vf, pb, oacc[df]);
            }
        }
    }

    __syncthreads();   // all compute done; K region becomes sOf
#pragma unroll
    for (int df = 0; df < 4; ++df)
#pragma unroll
        for (int r = 0; r < 4; ++r)
            sOf[wk * 4352 + (df * 16 + g * 4 + r) * 68 + wq * 16 + c16] = oacc[df][r];
    __syncthreads();
    {
        int q = t >> 3, dg = t & 7;
        u16x8 ov;
#pragma unroll
        for (int i = 0; i < 8; ++i) {
            int d = dg * 8 + i;
            ov[i] = f2bf(sOf[d * 68 + q] + sOf[4352 + d * 68 + q]);
        }
        *(u16x8*)&Att[(size_t)(b * SQL + qbase + q) * EMBED + h * 64 + dg * 8] = ov;
    }
}

// ---------------------------------------------------------------------------
extern "C" void kernel_launch(void* const* d_in, const int* in_sizes, int n_in,
                              void* d_out, int out_size, void* d_ws, size_t ws_size,
                              hipStream_t stream) {
    const float* query = (const float*)d_in[0];
    const float* key   = (const float*)d_in[1];
    const float* value = (const float*)d_in[2];
    const float* Wq = (const float*)d_in[3];
    const float* bq = (const float*)d_in[4];
    const float* Wk = (const float*)d_in[5];
    const float* bk = (const float*)d_in[6];
    const float* Wv = (const float*)d_in[7];
    const float* bv = (const float*)d_in[8];
    const float* Wo = (const float*)d_in[9];
    const float* bo = (const float*)d_in[10];

    float* out = (float*)d_out;                         // [4,1024,1024] f32
    float* meanOut = out + (size_t)BATCH * SQL * EMBED; // [4,1024,2048] f32

    u16* Qhi = (u16*)d_ws;                              // head-major [b][h][q][64]
    u16* Qlo = Qhi + (size_t)4096 * 1024;
    u16* Khi = Qlo + (size_t)4096 * 1024;               // [b][h][k][64]
    u16* Klo = Khi + (size_t)8192 * 1024;
    u16* VTh = Klo + (size_t)8192 * 1024;               // [b][h][d][2048]
    u16* Att = VTh + (size_t)8192 * 1024;               // [4096][1024] bf16
    float* llog = (float*)(Att + (size_t)4096 * 1024);  // [b*16+h][q]

    gemm_mfma<1, 0, 3><<<dim3(8, 32), 256, 0, stream>>>(query, Wq, bq, Qhi, Qlo, 4096, 1024, 10);
    gemm_mfma<1, 0, 3><<<dim3(8, 64), 256, 0, stream>>>(key, Wk, bk, Khi, Klo, 8192, 1024, 11);
    gemm_mfma<0, 0, 4><<<dim3(64, 8), 256, 0, stream>>>(Wv, value, bv, VTh, nullptr, 1024, 8192, 0);

    attn_lsum<<<dim3(512), dim3(512), 0, stream>>>(Qhi, Qlo, Khi, Klo, llog);
    attn_mean<<<dim3(512), dim3(512), 0, stream>>>(Qhi, Qlo, Khi, Klo, llog, meanOut);
    attn_O<<<dim3(1024), dim3(512), 0, stream>>>(Qhi, Qlo, Khi, Klo, VTh, llog, Att);

    gemm_mfma<0, 1, 0><<<dim3(8, 32), 256, 0, stream>>>(Att, Wo, bo, out, nullptr, 4096, 1024, 0);
}

// Round 8
// 337.634 us; speedup vs baseline: 2.2659x; 1.1127x over previous
//
#include <hip/hip_runtime.h>
#include <hip/hip_bf16.h>
#include <math.h>

#define EMBED 1024
#define NHEADS 16
#define HDIM 64
#define BATCH 4
#define SQL 1024
#define SKL 2048
#define PSC 0.18033688f   // 0.125 * log2(e)

typedef unsigned short u16;
typedef __attribute__((ext_vector_type(4))) float f32x4;
typedef __attribute__((ext_vector_type(8))) __bf16 bf16x8;
typedef __attribute__((ext_vector_type(8))) short s16x8;
typedef __attribute__((ext_vector_type(4))) short s16x4;
typedef __attribute__((ext_vector_type(8))) u16 u16x8;

__device__ __forceinline__ u16 f2bf(float x) {
    __hip_bfloat16 h = __float2bfloat16(x);
    return *reinterpret_cast<u16*>(&h);
}
__device__ __forceinline__ float bf2f(u16 u) {
    __hip_bfloat16 h;
    *reinterpret_cast<u16*>(&h) = u;
    return __bfloat162float(h);
}
__device__ __forceinline__ f32x4 mfma16(s16x8 a, s16x8 b, f32x4 c) {
    return __builtin_amdgcn_mfma_f32_16x16x32_bf16(
        __builtin_bit_cast(bf16x8, a), __builtin_bit_cast(bf16x8, b), c, 0, 0, 0);
}
__device__ __forceinline__ f32x4 mfma16k16(s16x4 a, s16x4 b, f32x4 c) {
    return __builtin_amdgcn_mfma_f32_16x16x16bf16_1k(a, b, c, 0, 0, 0);
}
__device__ __forceinline__ void gload16(const void* g, void* l) {
    __builtin_amdgcn_global_load_lds(
        (const __attribute__((address_space(1))) void*)g,
        (__attribute__((address_space(3))) void*)l, 16, 0, 0);
}
// Stage one 8KB plane (64 rows x 128B) with XOR-preswizzled source.
// LDS chunk (r, c) receives global chunk (r, c ^ (r&7)).  Dest is wave-uniform.
__device__ __forceinline__ void stage8k(const char* g, size_t rstrideB,
                                        char* ldsPlane, int w, int lane) {
    int r = w * 8 + (lane >> 3);
    int cs = (lane & 7) ^ (r & 7);
    gload16(g + (size_t)r * rstrideB + cs * 16, ldsPlane + (size_t)w * 1024);
}
#define WAIT_STAGE() { asm volatile("s_waitcnt vmcnt(0)" ::: "memory"); \
    __builtin_amdgcn_sched_barrier(0); __builtin_amdgcn_s_barrier(); \
    __builtin_amdgcn_sched_barrier(0); }

#define QK6(s, kh0, kh1, kl0, kl1, q0, q1, q2, q3) \
    s = mfma16(kh0, q0, s); s = mfma16(kh1, q1, s); \
    s = mfma16(kh0, q2, s); s = mfma16(kh1, q3, s); \
    s = mfma16(kl0, q0, s); s = mfma16(kl1, q1, s);

// ---------------------------------------------------------------------------
// GEMM NT: Y = A * W^T + bias. K=1024. 128x128 tile, proven structure.
// OUT_MODE 0: f32 + bias[col].  1: bf16 hi/lo + bias[col] (flat).
// 3: bf16 hi/lo head-major [b][h][s][64] (+bias[col]); sl = 1<<bshift.
// 4: bf16 V^T head-major [b][h][d][2048] (+bias[row]).
// ---------------------------------------------------------------------------
template<int SPLIT, int A_BF16, int OUT_MODE>
__global__ __launch_bounds__(256)
void gemm_mfma(const void* __restrict__ Ap, const float* __restrict__ Wp,
               const float* __restrict__ bias,
               void* __restrict__ Y0p, void* __restrict__ Y1p,
               int M, int N, int bshift) {
    const int K = 1024;
    __shared__ u16 sA[2][128 * 40];
    __shared__ u16 sB[2][128 * 40];

    const int t = threadIdx.x;
    const int lane = t & 63;
    const int w = t >> 6;
    const int wm = w >> 1, wn = w & 1;
    const int rowBase = blockIdx.y * 128;
    const int colBase = blockIdx.x * 128;
    const int srow = t >> 1;
    const int sc = (t & 1) * 16;

    const float* Af = (const float*)Ap;
    const u16* Au = (const u16*)Ap;

    f32x4 acc[4][4];
#pragma unroll
    for (int i = 0; i < 4; ++i)
#pragma unroll
        for (int j = 0; j < 4; ++j) acc[i][j] = (f32x4){0.f, 0.f, 0.f, 0.f};

    float ax[16], bx[16];
    u16x8 au0, au1;
    {
        if constexpr (A_BF16) {
            au0 = *(const u16x8*)&Au[(size_t)(rowBase + srow) * K + sc];
            au1 = *(const u16x8*)&Au[(size_t)(rowBase + srow) * K + sc + 8];
        } else {
#pragma unroll
            for (int j = 0; j < 4; ++j)
                *(float4*)&ax[j * 4] = *(const float4*)&Af[(size_t)(rowBase + srow) * K + sc + j * 4];
        }
#pragma unroll
        for (int j = 0; j < 4; ++j)
            *(float4*)&bx[j * 4] = *(const float4*)&Wp[(size_t)(colBase + srow) * K + sc + j * 4];
    }

    for (int k0 = 0; k0 < K; k0 += 32) {
        __syncthreads();
        {
            u16x8 h0, h1, l0, l1;
            if constexpr (A_BF16) {
                h0 = au0; h1 = au1;
            } else {
#pragma unroll
                for (int j = 0; j < 8; ++j) {
                    h0[j] = f2bf(ax[j]); h1[j] = f2bf(ax[j + 8]);
                    if constexpr (SPLIT) {
                        l0[j] = f2bf(ax[j] - bf2f(h0[j]));
                        l1[j] = f2bf(ax[j + 8] - bf2f(h1[j]));
                    }
                }
            }
            *(u16x8*)&sA[0][srow * 40 + sc] = h0;
            *(u16x8*)&sA[0][srow * 40 + sc + 8] = h1;
            if constexpr (SPLIT) {
                *(u16x8*)&sA[1][srow * 40 + sc] = l0;
                *(u16x8*)&sA[1][srow * 40 + sc + 8] = l1;
            }
            u16x8 bh0, bh1, bl0, bl1;
#pragma unroll
            for (int j = 0; j < 8; ++j) {
                bh0[j] = f2bf(bx[j]); bh1[j] = f2bf(bx[j + 8]);
                if constexpr (SPLIT) {
                    bl0[j] = f2bf(bx[j] - bf2f(bh0[j]));
                    bl1[j] = f2bf(bx[j + 8] - bf2f(bh1[j]));
                }
            }
            *(u16x8*)&sB[0][srow * 40 + sc] = bh0;
            *(u16x8*)&sB[0][srow * 40 + sc + 8] = bh1;
            if constexpr (SPLIT) {
                *(u16x8*)&sB[1][srow * 40 + sc] = bl0;
                *(u16x8*)&sB[1][srow * 40 + sc + 8] = bl1;
            }
        }
        __syncthreads();
        if (k0 + 32 < K) {
            const int kn = k0 + 32;
            if constexpr (A_BF16) {
                au0 = *(const u16x8*)&Au[(size_t)(rowBase + srow) * K + kn + sc];
                au1 = *(const u16x8*)&Au[(size_t)(rowBase + srow) * K + kn + sc + 8];
            } else {
#pragma unroll
                for (int j = 0; j < 4; ++j)
                    *(float4*)&ax[j * 4] = *(const float4*)&Af[(size_t)(rowBase + srow) * K + kn + sc + j * 4];
            }
#pragma unroll
            for (int j = 0; j < 4; ++j)
                *(float4*)&bx[j * 4] = *(const float4*)&Wp[(size_t)(colBase + srow) * K + kn + sc + j * 4];
        }
        {
            s16x8 afh[4], afl[4], bfh[4], bfl[4];
#pragma unroll
            for (int mi = 0; mi < 4; ++mi) {
                int ai = (wm * 64 + mi * 16 + (lane & 15)) * 40 + (lane >> 4) * 8;
                afh[mi] = *(const s16x8*)&sA[0][ai];
                if constexpr (SPLIT) afl[mi] = *(const s16x8*)&sA[1][ai];
            }
#pragma unroll
            for (int ni = 0; ni < 4; ++ni) {
                int bi = (wn * 64 + ni * 16 + (lane & 15)) * 40 + (lane >> 4) * 8;
                bfh[ni] = *(const s16x8*)&sB[0][bi];
                if constexpr (SPLIT) bfl[ni] = *(const s16x8*)&sB[1][bi];
            }
#pragma unroll
            for (int mi = 0; mi < 4; ++mi)
#pragma unroll
                for (int ni = 0; ni < 4; ++ni) {
                    acc[mi][ni] = mfma16(afh[mi], bfh[ni], acc[mi][ni]);
                    if constexpr (SPLIT) {
                        acc[mi][ni] = mfma16(afh[mi], bfl[ni], acc[mi][ni]);
                        acc[mi][ni] = mfma16(afl[mi], bfh[ni], acc[mi][ni]);
                    }
                }
        }
    }

#pragma unroll
    for (int mi = 0; mi < 4; ++mi)
#pragma unroll
        for (int ni = 0; ni < 4; ++ni)
#pragma unroll
            for (int rr = 0; rr < 4; ++rr) {
                int mg = rowBase + wm * 64 + mi * 16 + (lane >> 4) * 4 + rr;
                int ng = colBase + wn * 64 + ni * 16 + (lane & 15);
                float y = acc[mi][ni][rr];
                if constexpr (OUT_MODE == 0) {
                    ((float*)Y0p)[(size_t)mg * N + ng] = y + bias[ng];
                } else if constexpr (OUT_MODE == 1) {
                    y += bias[ng];
                    u16 hh = f2bf(y);
                    ((u16*)Y0p)[(size_t)mg * N + ng] = hh;
                    ((u16*)Y1p)[(size_t)mg * N + ng] = f2bf(y - bf2f(hh));
                } else if constexpr (OUT_MODE == 3) {
                    y += bias[ng];
                    int bb = mg >> bshift, s = mg & ((1 << bshift) - 1);
                    size_t idx = ((((size_t)(bb * 16 + (ng >> 6))) << bshift) + s) * 64 + (ng & 63);
                    u16 hh = f2bf(y);
                    ((u16*)Y0p)[idx] = hh;
                    ((u16*)Y1p)[idx] = f2bf(y - bf2f(hh));
                } else if constexpr (OUT_MODE == 4) {
                    y += bias[mg];
                    size_t idx = ((size_t)((ng >> 11) * 16 + (mg >> 6)) * 64 + (mg & 63)) * 2048 + (ng & 2047);
                    ((u16*)Y0p)[idx] = f2bf(y);
                }
            }
}

// ---------------------------------------------------------------------------
// Pass 1: attended output + denominators (online l, flash-style; scores are
// bounded so no max subtraction). Block=(b,h,qtile64), 512 thr (4wq x 2wk),
// 32 chunks of 64k, K+V dbuf. PV accumulates UNNORMALIZED bf16 e; per-lane
// f32 lsum tracks l. Epilogue: cross-wave reduce of O and l, write Att =
// O/l and llog = log2(l) (consumed by attn_mean).
// ---------------------------------------------------------------------------
__global__ __launch_bounds__(512, 4)
void attn_O(const u16* __restrict__ Qhi, const u16* __restrict__ Qlo,
            const u16* __restrict__ Khi, const u16* __restrict__ Klo,
            const u16* __restrict__ VT, u16* __restrict__ Att,
            float* __restrict__ llog) {
    __shared__ char lds[65536];  // Qh8K|Ql8K| K dbuf 2x16K @16384 | V dbuf 2x8K @49152
    __shared__ float sL2[2][64];
    char* sQh = lds;
    char* sQl = lds + 8192;
    float* sOf = (float*)(lds + 16384);   // reduce scratch [2][64][68], aliases K

    const int t = threadIdx.x;
    const int w = t >> 6, lane = t & 63;
    const int g = lane >> 4, c16 = lane & 15;
    const int qt = blockIdx.x >> 6;
    const int b = (blockIdx.x >> 4) & 3;
    const int h = blockIdx.x & 15;
    const int qbase = qt * 64;
    const int wq = w >> 1, wk = w & 1;
    const int kswz = (g ^ (c16 & 7)) << 4;
    const int vsw0 = (((wk * 4 + 0 + (g >> 1)) ^ (c16 & 7)) << 4) | ((g & 1) << 3);
    const int vsw1 = (((wk * 4 + 2 + (g >> 1)) ^ (c16 & 7)) << 4) | ((g & 1) << 3);

    const char* Qh_g = (const char*)(Qhi + ((size_t)(b * 16 + h) * SQL + qbase) * 64);
    const char* Ql_g = (const char*)(Qlo + ((size_t)(b * 16 + h) * SQL + qbase) * 64);
    const char* Kh_g = (const char*)(Khi + (size_t)(b * 16 + h) * SKL * 64);
    const char* Kl_g = (const char*)(Klo + (size_t)(b * 16 + h) * SKL * 64);
    const char* V_g  = (const char*)(VT + (size_t)(b * 16 + h) * 64 * SKL);

    stage8k(Qh_g, 128, sQh, w, lane);
    stage8k(Ql_g, 128, sQl, w, lane);
    stage8k(Kh_g, 128, lds + 16384, w, lane);
    stage8k(Kl_g, 128, lds + 16384 + 8192, w, lane);
    stage8k(V_g, 4096, lds + 49152, w, lane);

    s16x8 qh0, qh1, ql0, ql1;
    f32x4 oacc[4];
#pragma unroll
    for (int i = 0; i < 4; ++i) oacc[i] = (f32x4){0.f, 0.f, 0.f, 0.f};
    float lsum = 0.f;

    for (int c = 0; c < 32; ++c) {
        WAIT_STAGE();
        if (c == 0) {
            int qb = (wq * 16 + c16) * 128 + kswz;
            qh0 = *(const s16x8*)(sQh + qb);
            qh1 = *(const s16x8*)(sQh + (qb ^ 64));
            ql0 = *(const s16x8*)(sQl + qb);
            ql1 = *(const s16x8*)(sQl + (qb ^ 64));
        }
        if (c < 31) {
            char* nbK = lds + 16384 + ((c + 1) & 1) * 16384;
            char* nbV = lds + 49152 + ((c + 1) & 1) * 8192;
            stage8k(Kh_g + (size_t)(c + 1) * 8192, 128, nbK, w, lane);
            stage8k(Kl_g + (size_t)(c + 1) * 8192, 128, nbK + 8192, w, lane);
            stage8k(V_g + (size_t)(c + 1) * 128, 4096, nbV, w, lane);
        }
        char* curK = lds + 16384 + (c & 1) * 16384;
        char* curV = lds + 49152 + (c & 1) * 8192;
#pragma unroll
        for (int kf = 0; kf < 2; ++kf) {
            int kb = (wk * 32 + kf * 16 + c16) * 128 + kswz;
            s16x8 kh0 = *(const s16x8*)(curK + kb);
            s16x8 kh1 = *(const s16x8*)(curK + (kb ^ 64));
            s16x8 kl0 = *(const s16x8*)(curK + 8192 + kb);
            s16x8 kl1 = *(const s16x8*)(curK + 8192 + (kb ^ 64));
            f32x4 s = {0.f, 0.f, 0.f, 0.f};
            QK6(s, kh0, kh1, kl0, kl1, qh0, qh1, ql0, ql1)
            float e0 = exp2f(s[0] * PSC);
            float e1 = exp2f(s[1] * PSC);
            float e2 = exp2f(s[2] * PSC);
            float e3 = exp2f(s[3] * PSC);
            lsum += (e0 + e1) + (e2 + e3);
            s16x4 pb;
            pb[0] = (short)f2bf(e0); pb[1] = (short)f2bf(e1);
            pb[2] = (short)f2bf(e2); pb[3] = (short)f2bf(e3);
            int vs = kf ? vsw1 : vsw0;
#pragma unroll
            for (int df = 0; df < 4; ++df) {
                s16x4 vf = *(const s16x4*)(curV + (df * 16 + c16) * 128 + vs);
                oacc[df] = mfma16k16(vf, pb, oacc[df]);
            }
        }
    }

    // ---- reduce l across the 4 k-groups of this wave (16 lanes each hold a q)
    lsum += __shfl_xor(lsum, 16, 64);
    lsum += __shfl_xor(lsum, 32, 64);

    __syncthreads();   // all compute done; K region becomes sOf
#pragma unroll
    for (int df = 0; df < 4; ++df)
#pragma unroll
        for (int r = 0; r < 4; ++r)
            sOf[wk * 4352 + (df * 16 + g * 4 + r) * 68 + wq * 16 + c16] = oacc[df][r];
    if (g == 0) sL2[wk][wq * 16 + c16] = lsum;
    __syncthreads();
    {
        int q = t >> 3, dg = t & 7;
        float l = sL2[0][q] + sL2[1][q];
        float linv = 1.f / l;
        u16x8 ov;
#pragma unroll
        for (int i = 0; i < 8; ++i) {
            int d = dg * 8 + i;
            ov[i] = f2bf((sOf[d * 68 + q] + sOf[4352 + d * 68 + q]) * linv);
        }
        *(u16x8*)&Att[(size_t)(b * SQL + qbase + q) * EMBED + h * 64 + dg * 8] = ov;
        if (dg == 0)
            llog[(size_t)(b * 16 + h) * SQL + qbase + q] = log2f(l);
    }
}

// ---------------------------------------------------------------------------
// Pass 2: mean_attn. Block=(b,qtile64,kslab256); flattened 64-iteration
// (head, chunk) pipeline: Q dbuf (by head parity) + K dbuf (by iter parity),
// per-head lb prefetched one head ahead. p = exp2(s*PSC - lb) is final;
// mean lives in 8 f32x4 regs (exclusive (q,k) cells), written once.
// ---------------------------------------------------------------------------
__global__ __launch_bounds__(512, 4)
void attn_mean(const u16* __restrict__ Qhi, const u16* __restrict__ Qlo,
               const u16* __restrict__ Khi, const u16* __restrict__ Klo,
               const float* __restrict__ llog, float* __restrict__ meanOut) {
    __shared__ char lds[65536];      // Q dbuf 2x16K @0 | K dbuf 2x16K @32768

    const int t = threadIdx.x;
    const int w = t >> 6, lane = t & 63;
    const int g = lane >> 4, c16 = lane & 15;
    const int qt = blockIdx.x >> 5;
    const int b = (blockIdx.x >> 3) & 3;
    const int ks = blockIdx.x & 7;
    const int qbase = qt * 64;
    const int kbase = ks * 256;
    const int wq = w >> 1, wk = w & 1;
    const int kswz = (g ^ (c16 & 7)) << 4;

    const size_t QH_STRIDE = (size_t)SQL * 128;   // bytes per head
    const size_t KH_STRIDE = (size_t)SKL * 128;
    const char* Qh_b = (const char*)(Qhi + ((size_t)(b * 16) * SQL + qbase) * 64);
    const char* Ql_b = (const char*)(Qlo + ((size_t)(b * 16) * SQL + qbase) * 64);
    const char* Kh_b = (const char*)(Khi + ((size_t)(b * 16) * SKL + kbase) * 64);
    const char* Kl_b = (const char*)(Klo + ((size_t)(b * 16) * SKL + kbase) * 64);
    const int lql = wq * 16 + c16;   // this lane's q row (local)

    f32x4 ma[8];
#pragma unroll
    for (int i = 0; i < 8; ++i) ma[i] = (f32x4){0.f, 0.f, 0.f, 0.f};

    // prologue: stage head-0 Q and K chunk 0; prefetch lb for head 0
    stage8k(Qh_b, 128, lds, w, lane);
    stage8k(Ql_b, 128, lds + 8192, w, lane);
    stage8k(Kh_b, 128, lds + 32768, w, lane);
    stage8k(Kl_b, 128, lds + 32768 + 8192, w, lane);
    float lbn = llog[(size_t)(b * 16 + 0) * SQL + qbase + lql];

    s16x8 qh0, qh1, ql0, ql1;
    float lb = 0.f;

    for (int it = 0; it < 64; ++it) {
        const int h = it >> 2, c = it & 3;
        WAIT_STAGE();
        if (c == 0) {
            const char* sQ = lds + (h & 1) * 16384;
            int qb = lql * 128 + kswz;
            qh0 = *(const s16x8*)(sQ + qb);
            qh1 = *(const s16x8*)(sQ + (qb ^ 64));
            ql0 = *(const s16x8*)(sQ + 8192 + qb);
            ql1 = *(const s16x8*)(sQ + 8192 + (qb ^ 64));
            lb = lbn;
        }
        if (it + 1 < 64) {
            const int h2 = (it + 1) >> 2, c2 = (it + 1) & 3;
            char* nbK = lds + 32768 + ((it + 1) & 1) * 16384;
            stage8k(Kh_b + h2 * KH_STRIDE + (size_t)c2 * 8192, 128, nbK, w, lane);
            stage8k(Kl_b + h2 * KH_STRIDE + (size_t)c2 * 8192, 128, nbK + 8192, w, lane);
            if (c2 == 0) {
                char* nbQ = lds + (h2 & 1) * 16384;
                stage8k(Qh_b + h2 * QH_STRIDE, 128, nbQ, w, lane);
                stage8k(Ql_b + h2 * QH_STRIDE, 128, nbQ + 8192, w, lane);
                lbn = llog[(size_t)(b * 16 + h2) * SQL + qbase + lql];
            }
        }
        char* curK = lds + 32768 + (it & 1) * 16384;
#pragma unroll
        for (int kf = 0; kf < 2; ++kf) {
            int kb = (wk * 32 + kf * 16 + c16) * 128 + kswz;
            s16x8 kh0 = *(const s16x8*)(curK + kb);
            s16x8 kh1 = *(const s16x8*)(curK + (kb ^ 64));
            s16x8 kl0 = *(const s16x8*)(curK + 8192 + kb);
            s16x8 kl1 = *(const s16x8*)(curK + 8192 + (kb ^ 64));
            f32x4 s = {0.f, 0.f, 0.f, 0.f};
            QK6(s, kh0, kh1, kl0, kl1, qh0, qh1, ql0, ql1)
            ma[c * 2 + kf][0] += exp2f(s[0] * PSC - lb);
            ma[c * 2 + kf][1] += exp2f(s[1] * PSC - lb);
            ma[c * 2 + kf][2] += exp2f(s[2] * PSC - lb);
            ma[c * 2 + kf][3] += exp2f(s[3] * PSC - lb);
        }
    }

    const float s16c = 1.f / 16.f;
#pragma unroll
    for (int c = 0; c < 4; ++c)
#pragma unroll
        for (int kf = 0; kf < 2; ++kf) {
            f32x4 m = ma[c * 2 + kf];
            m[0] *= s16c; m[1] *= s16c; m[2] *= s16c; m[3] *= s16c;
            *(f32x4*)&meanOut[(size_t)(b * SQL + qbase + lql) * SKL +
                              kbase + c * 64 + wk * 32 + kf * 16 + g * 4] = m;
        }
}

// ---------------------------------------------------------------------------
extern "C" void kernel_launch(void* const* d_in, const int* in_sizes, int n_in,
                              void* d_out, int out_size, void* d_ws, size_t ws_size,
                              hipStream_t stream) {
    const float* query = (const float*)d_in[0];
    const float* key   = (const float*)d_in[1];
    const float* value = (const float*)d_in[2];
    const float* Wq = (const float*)d_in[3];
    const float* bq = (const float*)d_in[4];
    const float* Wk = (const float*)d_in[5];
    const float* bk = (const float*)d_in[6];
    const float* Wv = (const float*)d_in[7];
    const float* bv = (const float*)d_in[8];
    const float* Wo = (const float*)d_in[9];
    const float* bo = (const float*)d_in[10];

    float* out = (float*)d_out;                         // [4,1024,1024] f32
    float* meanOut = out + (size_t)BATCH * SQL * EMBED; // [4,1024,2048] f32

    u16* Qhi = (u16*)d_ws;                              // head-major [b][h][q][64]
    u16* Qlo = Qhi + (size_t)4096 * 1024;
    u16* Khi = Qlo + (size_t)4096 * 1024;               // [b][h][k][64]
    u16* Klo = Khi + (size_t)8192 * 1024;
    u16* VTh = Klo + (size_t)8192 * 1024;               // [b][h][d][2048]
    u16* Att = VTh + (size_t)8192 * 1024;               // [4096][1024] bf16
    float* llog = (float*)(Att + (size_t)4096 * 1024);  // [b*16+h][q]

    gemm_mfma<1, 0, 3><<<dim3(8, 32), 256, 0, stream>>>(query, Wq, bq, Qhi, Qlo, 4096, 1024, 10);
    gemm_mfma<1, 0, 3><<<dim3(8, 64), 256, 0, stream>>>(key, Wk, bk, Khi, Klo, 8192, 1024, 11);
    gemm_mfma<0, 0, 4><<<dim3(64, 8), 256, 0, stream>>>(Wv, value, bv, VTh, nullptr, 1024, 8192, 0);

    attn_O<<<dim3(1024), dim3(512), 0, stream>>>(Qhi, Qlo, Khi, Klo, VTh, Att, llog);
    attn_mean<<<dim3(512), dim3(512), 0, stream>>>(Qhi, Qlo, Khi, Klo, llog, meanOut);

    gemm_mfma<0, 1, 0><<<dim3(8, 32), 256, 0, stream>>>(Att, Wo, bo, out, nullptr, 4096, 1024, 0);
}

// Round 9
// 310.987 us; speedup vs baseline: 2.4600x; 1.0857x over previous
//
#include <hip/hip_runtime.h>
#include <hip/hip_bf16.h>
#include <math.h>

#define EMBED 1024
#define NHEADS 16
#define HDIM 64
#define BATCH 4
#define SQL 1024
#define SKL 2048
#define PSC 0.18033688f   // 0.125 * log2(e)

typedef unsigned short u16;
typedef __attribute__((ext_vector_type(4))) float f32x4;
typedef __attribute__((ext_vector_type(8))) __bf16 bf16x8;
typedef __attribute__((ext_vector_type(8))) short s16x8;
typedef __attribute__((ext_vector_type(4))) short s16x4;
typedef __attribute__((ext_vector_type(8))) u16 u16x8;

__device__ __forceinline__ u16 f2bf(float x) {
    __hip_bfloat16 h = __float2bfloat16(x);
    return *reinterpret_cast<u16*>(&h);
}
__device__ __forceinline__ float bf2f(u16 u) {
    __hip_bfloat16 h;
    *reinterpret_cast<u16*>(&h) = u;
    return __bfloat162float(h);
}
__device__ __forceinline__ f32x4 mfma16(s16x8 a, s16x8 b, f32x4 c) {
    return __builtin_amdgcn_mfma_f32_16x16x32_bf16(
        __builtin_bit_cast(bf16x8, a), __builtin_bit_cast(bf16x8, b), c, 0, 0, 0);
}
__device__ __forceinline__ f32x4 mfma16k16(s16x4 a, s16x4 b, f32x4 c) {
    return __builtin_amdgcn_mfma_f32_16x16x16bf16_1k(a, b, c, 0, 0, 0);
}
__device__ __forceinline__ void gload16(const void* g, void* l) {
    __builtin_amdgcn_global_load_lds(
        (const __attribute__((address_space(1))) void*)g,
        (__attribute__((address_space(3))) void*)l, 16, 0, 0);
}
// Stage one 8KB plane (64 rows x 128B) with XOR-preswizzled source.
// LDS chunk (r, c) receives global chunk (r, c ^ (r&7)).  Dest is wave-uniform.
__device__ __forceinline__ void stage8k(const char* g, size_t rstrideB,
                                        char* ldsPlane, int w, int lane) {
    int r = w * 8 + (lane >> 3);
    int cs = (lane & 7) ^ (r & 7);
    gload16(g + (size_t)r * rstrideB + cs * 16, ldsPlane + (size_t)w * 1024);
}
#define WAIT_STAGE() { asm volatile("s_waitcnt vmcnt(0)" ::: "memory"); \
    __builtin_amdgcn_sched_barrier(0); __builtin_amdgcn_s_barrier(); \
    __builtin_amdgcn_sched_barrier(0); }

#define QK6(s, kh0, kh1, kl0, kl1, q0, q1, q2, q3) \
    s = mfma16(kh0, q0, s); s = mfma16(kh1, q1, s); \
    s = mfma16(kh0, q2, s); s = mfma16(kh1, q3, s); \
    s = mfma16(kl0, q0, s); s = mfma16(kl1, q1, s);

// ---------------------------------------------------------------------------
// GEMM NT: Y = A * W^T + bias. K=1024. 128x128 tile (unchanged, proven).
// ---------------------------------------------------------------------------
template<int SPLIT, int A_BF16, int OUT_MODE>
__global__ __launch_bounds__(256)
void gemm_mfma(const void* __restrict__ Ap, const float* __restrict__ Wp,
               const float* __restrict__ bias,
               void* __restrict__ Y0p, void* __restrict__ Y1p,
               int M, int N, int bshift) {
    const int K = 1024;
    __shared__ u16 sA[2][128 * 40];
    __shared__ u16 sB[2][128 * 40];

    const int t = threadIdx.x;
    const int lane = t & 63;
    const int w = t >> 6;
    const int wm = w >> 1, wn = w & 1;
    const int rowBase = blockIdx.y * 128;
    const int colBase = blockIdx.x * 128;
    const int srow = t >> 1;
    const int sc = (t & 1) * 16;

    const float* Af = (const float*)Ap;
    const u16* Au = (const u16*)Ap;

    f32x4 acc[4][4];
#pragma unroll
    for (int i = 0; i < 4; ++i)
#pragma unroll
        for (int j = 0; j < 4; ++j) acc[i][j] = (f32x4){0.f, 0.f, 0.f, 0.f};

    float ax[16], bx[16];
    u16x8 au0, au1;
    {
        if constexpr (A_BF16) {
            au0 = *(const u16x8*)&Au[(size_t)(rowBase + srow) * K + sc];
            au1 = *(const u16x8*)&Au[(size_t)(rowBase + srow) * K + sc + 8];
        } else {
#pragma unroll
            for (int j = 0; j < 4; ++j)
                *(float4*)&ax[j * 4] = *(const float4*)&Af[(size_t)(rowBase + srow) * K + sc + j * 4];
        }
#pragma unroll
        for (int j = 0; j < 4; ++j)
            *(float4*)&bx[j * 4] = *(const float4*)&Wp[(size_t)(colBase + srow) * K + sc + j * 4];
    }

    for (int k0 = 0; k0 < K; k0 += 32) {
        __syncthreads();
        {
            u16x8 h0, h1, l0, l1;
            if constexpr (A_BF16) {
                h0 = au0; h1 = au1;
            } else {
#pragma unroll
                for (int j = 0; j < 8; ++j) {
                    h0[j] = f2bf(ax[j]); h1[j] = f2bf(ax[j + 8]);
                    if constexpr (SPLIT) {
                        l0[j] = f2bf(ax[j] - bf2f(h0[j]));
                        l1[j] = f2bf(ax[j + 8] - bf2f(h1[j]));
                    }
                }
            }
            *(u16x8*)&sA[0][srow * 40 + sc] = h0;
            *(u16x8*)&sA[0][srow * 40 + sc + 8] = h1;
            if constexpr (SPLIT) {
                *(u16x8*)&sA[1][srow * 40 + sc] = l0;
                *(u16x8*)&sA[1][srow * 40 + sc + 8] = l1;
            }
            u16x8 bh0, bh1, bl0, bl1;
#pragma unroll
            for (int j = 0; j < 8; ++j) {
                bh0[j] = f2bf(bx[j]); bh1[j] = f2bf(bx[j + 8]);
                if constexpr (SPLIT) {
                    bl0[j] = f2bf(bx[j] - bf2f(bh0[j]));
                    bl1[j] = f2bf(bx[j + 8] - bf2f(bh1[j]));
                }
            }
            *(u16x8*)&sB[0][srow * 40 + sc] = bh0;
            *(u16x8*)&sB[0][srow * 40 + sc + 8] = bh1;
            if constexpr (SPLIT) {
                *(u16x8*)&sB[1][srow * 40 + sc] = bl0;
                *(u16x8*)&sB[1][srow * 40 + sc + 8] = bl1;
            }
        }
        __syncthreads();
        if (k0 + 32 < K) {
            const int kn = k0 + 32;
            if constexpr (A_BF16) {
                au0 = *(const u16x8*)&Au[(size_t)(rowBase + srow) * K + kn + sc];
                au1 = *(const u16x8*)&Au[(size_t)(rowBase + srow) * K + kn + sc + 8];
            } else {
#pragma unroll
                for (int j = 0; j < 4; ++j)
                    *(float4*)&ax[j * 4] = *(const float4*)&Af[(size_t)(rowBase + srow) * K + kn + sc + j * 4];
            }
#pragma unroll
            for (int j = 0; j < 4; ++j)
                *(float4*)&bx[j * 4] = *(const float4*)&Wp[(size_t)(colBase + srow) * K + kn + sc + j * 4];
        }
        {
            s16x8 afh[4], afl[4], bfh[4], bfl[4];
#pragma unroll
            for (int mi = 0; mi < 4; ++mi) {
                int ai = (wm * 64 + mi * 16 + (lane & 15)) * 40 + (lane >> 4) * 8;
                afh[mi] = *(const s16x8*)&sA[0][ai];
                if constexpr (SPLIT) afl[mi] = *(const s16x8*)&sA[1][ai];
            }
#pragma unroll
            for (int ni = 0; ni < 4; ++ni) {
                int bi = (wn * 64 + ni * 16 + (lane & 15)) * 40 + (lane >> 4) * 8;
                bfh[ni] = *(const s16x8*)&sB[0][bi];
                if constexpr (SPLIT) bfl[ni] = *(const s16x8*)&sB[1][bi];
            }
#pragma unroll
            for (int mi = 0; mi < 4; ++mi)
#pragma unroll
                for (int ni = 0; ni < 4; ++ni) {
                    acc[mi][ni] = mfma16(afh[mi], bfh[ni], acc[mi][ni]);
                    if constexpr (SPLIT) {
                        acc[mi][ni] = mfma16(afh[mi], bfl[ni], acc[mi][ni]);
                        acc[mi][ni] = mfma16(afl[mi], bfh[ni], acc[mi][ni]);
                    }
                }
        }
    }

#pragma unroll
    for (int mi = 0; mi < 4; ++mi)
#pragma unroll
        for (int ni = 0; ni < 4; ++ni)
#pragma unroll
            for (int rr = 0; rr < 4; ++rr) {
                int mg = rowBase + wm * 64 + mi * 16 + (lane >> 4) * 4 + rr;
                int ng = colBase + wn * 64 + ni * 16 + (lane & 15);
                float y = acc[mi][ni][rr];
                if constexpr (OUT_MODE == 0) {
                    ((float*)Y0p)[(size_t)mg * N + ng] = y + bias[ng];
                } else if constexpr (OUT_MODE == 1) {
                    y += bias[ng];
                    u16 hh = f2bf(y);
                    ((u16*)Y0p)[(size_t)mg * N + ng] = hh;
                    ((u16*)Y1p)[(size_t)mg * N + ng] = f2bf(y - bf2f(hh));
                } else if constexpr (OUT_MODE == 3) {
                    y += bias[ng];
                    int bb = mg >> bshift, s = mg & ((1 << bshift) - 1);
                    size_t idx = ((((size_t)(bb * 16 + (ng >> 6))) << bshift) + s) * 64 + (ng & 63);
                    u16 hh = f2bf(y);
                    ((u16*)Y0p)[idx] = hh;
                    ((u16*)Y1p)[idx] = f2bf(y - bf2f(hh));
                } else if constexpr (OUT_MODE == 4) {
                    y += bias[mg];
                    size_t idx = ((size_t)((ng >> 11) * 16 + (mg >> 6)) * 64 + (mg & 63)) * 2048 + (ng & 2047);
                    ((u16*)Y0p)[idx] = f2bf(y);
                }
            }
}

// ---------------------------------------------------------------------------
// Pass 1: attended output + denominators, qtile128. Block=(b,h,qtile128),
// grid 512 (blockIdx = qt*64 + b*16 + h: all 8 qt-blocks of a (b,h) share one
// XCD). 512 thr = 4wq x 2wk; each wave owns 32 q rows (2 frags) in REGISTERS.
// 32 chunks of 64k, K/V dbuf in 48KB LDS. PV accumulates unnormalized bf16 e,
// per-lane f32 lsum per q-frag. Epilogue per q-half: cross-wk reduce, write
// Att = O/l and llog = log2(l).
// ---------------------------------------------------------------------------
__global__ __launch_bounds__(512, 4)
void attn_O(const u16* __restrict__ Qhi, const u16* __restrict__ Qlo,
            const u16* __restrict__ Khi, const u16* __restrict__ Klo,
            const u16* __restrict__ VT, u16* __restrict__ Att,
            float* __restrict__ llog) {
    __shared__ char lds[49152];
    // K dbuf: [0,16K),[16K,32K) (each hi8K+lo8K). V dbuf: [32K,40K),[40K,48K).
    // Epilogue: sOf f32[2][64][68] at 0 (34816 B); sL2 f32[2][128] at 35840.
    float* sOf = (float*)lds;
    float* sL2 = (float*)(lds + 35840);

    const int t = threadIdx.x;
    const int w = t >> 6, lane = t & 63;
    const int g = lane >> 4, c16 = lane & 15;
    const int qt = blockIdx.x >> 6;
    const int g6 = blockIdx.x & 63;
    const int b = g6 >> 4, h = g6 & 15;
    const int qbase = qt * 128;
    const int wq = w >> 1, wk = w & 1;
    const int kswz = (g ^ (c16 & 7)) << 4;
    const int vsw0 = (((wk * 4 + 0 + (g >> 1)) ^ (c16 & 7)) << 4) | ((g & 1) << 3);
    const int vsw1 = (((wk * 4 + 2 + (g >> 1)) ^ (c16 & 7)) << 4) | ((g & 1) << 3);

    const char* Kh_g = (const char*)(Khi + (size_t)(b * 16 + h) * SKL * 64);
    const char* Kl_g = (const char*)(Klo + (size_t)(b * 16 + h) * SKL * 64);
    const char* V_g  = (const char*)(VT + (size_t)(b * 16 + h) * 64 * SKL);

    // Q fragments direct from global (plain layout), once per block
    s16x8 qh[2][2], ql[2][2];
    const size_t qrowbase = (size_t)(b * 16 + h) * SQL + qbase;
#pragma unroll
    for (int qf = 0; qf < 2; ++qf) {
        size_t qo = (qrowbase + wq * 32 + qf * 16 + c16) * 64 + g * 8;
        qh[qf][0] = *(const s16x8*)&Qhi[qo];
        qh[qf][1] = *(const s16x8*)&Qhi[qo + 32];
        ql[qf][0] = *(const s16x8*)&Qlo[qo];
        ql[qf][1] = *(const s16x8*)&Qlo[qo + 32];
    }

    stage8k(Kh_g, 128, lds, w, lane);
    stage8k(Kl_g, 128, lds + 8192, w, lane);
    stage8k(V_g, 4096, lds + 32768, w, lane);

    f32x4 oacc[2][4];
#pragma unroll
    for (int qf = 0; qf < 2; ++qf)
#pragma unroll
        for (int i = 0; i < 4; ++i) oacc[qf][i] = (f32x4){0.f, 0.f, 0.f, 0.f};
    float lsum[2] = {0.f, 0.f};

    for (int c = 0; c < 32; ++c) {
        WAIT_STAGE();
        if (c < 31) {
            char* nbK = lds + ((c + 1) & 1) * 16384;
            char* nbV = lds + 32768 + ((c + 1) & 1) * 8192;
            stage8k(Kh_g + (size_t)(c + 1) * 8192, 128, nbK, w, lane);
            stage8k(Kl_g + (size_t)(c + 1) * 8192, 128, nbK + 8192, w, lane);
            stage8k(V_g + (size_t)(c + 1) * 128, 4096, nbV, w, lane);
        }
        char* curK = lds + (c & 1) * 16384;
        char* curV = lds + 32768 + (c & 1) * 8192;
#pragma unroll
        for (int kf = 0; kf < 2; ++kf) {
            int kb = (wk * 32 + kf * 16 + c16) * 128 + kswz;
            s16x8 kh0 = *(const s16x8*)(curK + kb);
            s16x8 kh1 = *(const s16x8*)(curK + (kb ^ 64));
            s16x8 kl0 = *(const s16x8*)(curK + 8192 + kb);
            s16x8 kl1 = *(const s16x8*)(curK + 8192 + (kb ^ 64));
            s16x4 pb[2];
#pragma unroll
            for (int qf = 0; qf < 2; ++qf) {
                f32x4 s = {0.f, 0.f, 0.f, 0.f};
                QK6(s, kh0, kh1, kl0, kl1, qh[qf][0], qh[qf][1], ql[qf][0], ql[qf][1])
                float e0 = exp2f(s[0] * PSC);
                float e1 = exp2f(s[1] * PSC);
                float e2 = exp2f(s[2] * PSC);
                float e3 = exp2f(s[3] * PSC);
                lsum[qf] += (e0 + e1) + (e2 + e3);
                pb[qf][0] = (short)f2bf(e0); pb[qf][1] = (short)f2bf(e1);
                pb[qf][2] = (short)f2bf(e2); pb[qf][3] = (short)f2bf(e3);
            }
            int vs = kf ? vsw1 : vsw0;
#pragma unroll
            for (int df = 0; df < 4; ++df) {
                s16x4 vf = *(const s16x4*)(curV + (df * 16 + c16) * 128 + vs);
                oacc[0][df] = mfma16k16(vf, pb[0], oacc[0][df]);
                oacc[1][df] = mfma16k16(vf, pb[1], oacc[1][df]);
            }
        }
    }

    // reduce l across the 4 k-groups (16 lanes each hold one q)
#pragma unroll
    for (int qf = 0; qf < 2; ++qf) {
        lsum[qf] += __shfl_xor(lsum[qf], 16, 64);
        lsum[qf] += __shfl_xor(lsum[qf], 32, 64);
        if (g == 0) sL2[wk * 128 + wq * 32 + qf * 16 + c16] = lsum[qf];
    }

    // epilogue per q-half: waves wq in {2*half, 2*half+1} dump partials
#pragma unroll
    for (int half = 0; half < 2; ++half) {
        __syncthreads();
        if ((wq >> 1) == half) {
            int qlocal = (wq & 1) * 32 + c16;
#pragma unroll
            for (int qf = 0; qf < 2; ++qf)
#pragma unroll
                for (int df = 0; df < 4; ++df)
#pragma unroll
                    for (int r = 0; r < 4; ++r)
                        sOf[wk * 4352 + (df * 16 + g * 4 + r) * 68 + qlocal + qf * 16] =
                            oacc[qf][df][r];
        }
        __syncthreads();
        {
            int q = t >> 3, dg = t & 7;
            float l = sL2[half * 64 + q] + sL2[128 + half * 64 + q];
            float linv = 1.f / l;
            u16x8 ov;
#pragma unroll
            for (int i = 0; i < 8; ++i) {
                int d = dg * 8 + i;
                ov[i] = f2bf((sOf[d * 68 + q] + sOf[4352 + d * 68 + q]) * linv);
            }
            *(u16x8*)&Att[(size_t)(b * SQL + qbase + half * 64 + q) * EMBED + h * 64 + dg * 8] = ov;
            if (dg == 0)
                llog[(size_t)(b * 16 + h) * SQL + qbase + half * 64 + q] = log2f(l);
        }
    }
}

// ---------------------------------------------------------------------------
// Pass 2: mean_attn, qtile128 x kslab128. Block=(b,qt,ks), grid 512
// (blockIdx = qt*64 + b*16 + ks: qt-blocks sharing (b,ks) K data share an
// XCD). 32 iterations (16 heads x 2 chunks of 64k) -- half the barrier/drain
// count of r8. Q (128 rows hi+lo, 32KB) single-buffered per head; K dbuf
// 2x16KB. p = exp2(s*PSC - lb) is final; mean in 32 VGPRs, written once.
// ---------------------------------------------------------------------------
__global__ __launch_bounds__(512, 4)
void attn_mean(const u16* __restrict__ Qhi, const u16* __restrict__ Qlo,
               const u16* __restrict__ Khi, const u16* __restrict__ Klo,
               const float* __restrict__ llog, float* __restrict__ meanOut) {
    __shared__ char lds[65536];   // Q: hi [0,16K) lo [16K,32K); K dbuf [32K,48K),[48K,64K)
    char* sQh = lds;
    char* sQl = lds + 16384;

    const int t = threadIdx.x;
    const int w = t >> 6, lane = t & 63;
    const int g = lane >> 4, c16 = lane & 15;
    const int qt = blockIdx.x >> 6;
    const int low = blockIdx.x & 63;
    const int b = low >> 4, ks = low & 15;
    const int qbase = qt * 128;
    const int kbase = ks * 128;
    const int wq = w >> 1, wk = w & 1;
    const int kswz = (g ^ (c16 & 7)) << 4;

    const size_t QH_STRIDE = (size_t)SQL * 128;   // bytes per head
    const size_t KH_STRIDE = (size_t)SKL * 128;
    const char* Qh_b = (const char*)(Qhi + ((size_t)(b * 16) * SQL + qbase) * 64);
    const char* Ql_b = (const char*)(Qlo + ((size_t)(b * 16) * SQL + qbase) * 64);
    const char* Kh_b = (const char*)(Khi + ((size_t)(b * 16) * SKL + kbase) * 64);
    const char* Kl_b = (const char*)(Klo + ((size_t)(b * 16) * SKL + kbase) * 64);

    f32x4 ma[2][4];
#pragma unroll
    for (int qf = 0; qf < 2; ++qf)
#pragma unroll
        for (int i = 0; i < 4; ++i) ma[qf][i] = (f32x4){0.f, 0.f, 0.f, 0.f};

    // prologue: stage head-0 Q (4 planes) + K chunk 0; prefetch lb
    stage8k(Qh_b, 128, sQh, w, lane);
    stage8k(Qh_b + 8192, 128, sQh + 8192, w, lane);
    stage8k(Ql_b, 128, sQl, w, lane);
    stage8k(Ql_b + 8192, 128, sQl + 8192, w, lane);
    stage8k(Kh_b, 128, lds + 32768, w, lane);
    stage8k(Kl_b, 128, lds + 32768 + 8192, w, lane);
    float lbn0 = llog[(size_t)(b * 16) * SQL + qbase + wq * 32 + c16];
    float lbn1 = llog[(size_t)(b * 16) * SQL + qbase + wq * 32 + 16 + c16];

    s16x8 qh[2][2], ql[2][2];
    float lb0 = 0.f, lb1 = 0.f;

    for (int it = 0; it < 32; ++it) {
        const int c = it & 1;
        WAIT_STAGE();
        if (c == 0) {
#pragma unroll
            for (int qf = 0; qf < 2; ++qf) {
                int qb = (wq * 32 + qf * 16 + c16) * 128 + kswz;
                qh[qf][0] = *(const s16x8*)(sQh + qb);
                qh[qf][1] = *(const s16x8*)(sQh + (qb ^ 64));
                ql[qf][0] = *(const s16x8*)(sQl + qb);
                ql[qf][1] = *(const s16x8*)(sQl + (qb ^ 64));
            }
            lb0 = lbn0; lb1 = lbn1;
        }
        if (it + 1 < 32) {
            const int h2 = (it + 1) >> 1, c2 = (it + 1) & 1;
            char* nbK = lds + 32768 + ((it + 1) & 1) * 16384;
            stage8k(Kh_b + h2 * KH_STRIDE + (size_t)c2 * 8192, 128, nbK, w, lane);
            stage8k(Kl_b + h2 * KH_STRIDE + (size_t)c2 * 8192, 128, nbK + 8192, w, lane);
            if (c2 == 0) {
                stage8k(Qh_b + h2 * QH_STRIDE, 128, sQh, w, lane);
                stage8k(Qh_b + h2 * QH_STRIDE + 8192, 128, sQh + 8192, w, lane);
                stage8k(Ql_b + h2 * QH_STRIDE, 128, sQl, w, lane);
                stage8k(Ql_b + h2 * QH_STRIDE + 8192, 128, sQl + 8192, w, lane);
                lbn0 = llog[(size_t)(b * 16 + h2) * SQL + qbase + wq * 32 + c16];
                lbn1 = llog[(size_t)(b * 16 + h2) * SQL + qbase + wq * 32 + 16 + c16];
            }
        }
        char* curK = lds + 32768 + (it & 1) * 16384;
#pragma unroll
        for (int kf = 0; kf < 2; ++kf) {
            int kb = (wk * 32 + kf * 16 + c16) * 128 + kswz;
            s16x8 kh0 = *(const s16x8*)(curK + kb);
            s16x8 kh1 = *(const s16x8*)(curK + (kb ^ 64));
            s16x8 kl0 = *(const s16x8*)(curK + 8192 + kb);
            s16x8 kl1 = *(const s16x8*)(curK + 8192 + (kb ^ 64));
            {
                f32x4 s = {0.f, 0.f, 0.f, 0.f};
                QK6(s, kh0, kh1, kl0, kl1, qh[0][0], qh[0][1], ql[0][0], ql[0][1])
                ma[0][c * 2 + kf][0] += exp2f(s[0] * PSC - lb0);
                ma[0][c * 2 + kf][1] += exp2f(s[1] * PSC - lb0);
                ma[0][c * 2 + kf][2] += exp2f(s[2] * PSC - lb0);
                ma[0][c * 2 + kf][3] += exp2f(s[3] * PSC - lb0);
            }
            {
                f32x4 s = {0.f, 0.f, 0.f, 0.f};
                QK6(s, kh0, kh1, kl0, kl1, qh[1][0], qh[1][1], ql[1][0], ql[1][1])
                ma[1][c * 2 + kf][0] += exp2f(s[0] * PSC - lb1);
                ma[1][c * 2 + kf][1] += exp2f(s[1] * PSC - lb1);
                ma[1][c * 2 + kf][2] += exp2f(s[2] * PSC - lb1);
                ma[1][c * 2 + kf][3] += exp2f(s[3] * PSC - lb1);
            }
        }
    }

    const float s16c = 1.f / 16.f;
#pragma unroll
    for (int qf = 0; qf < 2; ++qf)
#pragma unroll
        for (int c = 0; c < 2; ++c)
#pragma unroll
            for (int kf = 0; kf < 2; ++kf) {
                f32x4 m = ma[qf][c * 2 + kf];
                m[0] *= s16c; m[1] *= s16c; m[2] *= s16c; m[3] *= s16c;
                *(f32x4*)&meanOut[(size_t)(b * SQL + qbase + wq * 32 + qf * 16 + c16) * SKL +
                                  kbase + c * 64 + wk * 32 + kf * 16 + g * 4] = m;
            }
}

// ---------------------------------------------------------------------------
extern "C" void kernel_launch(void* const* d_in, const int* in_sizes, int n_in,
                              void* d_out, int out_size, void* d_ws, size_t ws_size,
                              hipStream_t stream) {
    const float* query = (const float*)d_in[0];
    const float* key   = (const float*)d_in[1];
    const float* value = (const float*)d_in[2];
    const float* Wq = (const float*)d_in[3];
    const float* bq = (const float*)d_in[4];
    const float* Wk = (const float*)d_in[5];
    const float* bk = (const float*)d_in[6];
    const float* Wv = (const float*)d_in[7];
    const float* bv = (const float*)d_in[8];
    const float* Wo = (const float*)d_in[9];
    const float* bo = (const float*)d_in[10];

    float* out = (float*)d_out;                         // [4,1024,1024] f32
    float* meanOut = out + (size_t)BATCH * SQL * EMBED; // [4,1024,2048] f32

    u16* Qhi = (u16*)d_ws;                              // head-major [b][h][q][64]
    u16* Qlo = Qhi + (size_t)4096 * 1024;
    u16* Khi = Qlo + (size_t)4096 * 1024;               // [b][h][k][64]
    u16* Klo = Khi + (size_t)8192 * 1024;
    u16* VTh = Klo + (size_t)8192 * 1024;               // [b][h][d][2048]
    u16* Att = VTh + (size_t)8192 * 1024;               // [4096][1024] bf16
    float* llog = (float*)(Att + (size_t)4096 * 1024);  // [b*16+h][q]

    gemm_mfma<1, 0, 3><<<dim3(8, 32), 256, 0, stream>>>(query, Wq, bq, Qhi, Qlo, 4096, 1024, 10);
    gemm_mfma<1, 0, 3><<<dim3(8, 64), 256, 0, stream>>>(key, Wk, bk, Khi, Klo, 8192, 1024, 11);
    gemm_mfma<0, 0, 4><<<dim3(64, 8), 256, 0, stream>>>(Wv, value, bv, VTh, nullptr, 1024, 8192, 0);

    attn_O<<<dim3(512), dim3(512), 0, stream>>>(Qhi, Qlo, Khi, Klo, VTh, Att, llog);
    attn_mean<<<dim3(512), dim3(512), 0, stream>>>(Qhi, Qlo, Khi, Klo, llog, meanOut);

    gemm_mfma<0, 1, 0><<<dim3(8, 32), 256, 0, stream>>>(Att, Wo, bo, out, nullptr, 4096, 1024, 0);
}

// Round 10
// 292.917 us; speedup vs baseline: 2.6118x; 1.0617x over previous
//
#include <hip/hip_runtime.h>
#include <hip/hip_bf16.h>
#include <math.h>

#define EMBED 1024
#define NHEADS 16
#define HDIM 64
#define BATCH 4
#define SQL 1024
#define SKL 2048
#define PSC 0.18033688f   // 0.125 * log2(e)

typedef unsigned short u16;
typedef __attribute__((ext_vector_type(4))) float f32x4;
typedef __attribute__((ext_vector_type(8))) __bf16 bf16x8;
typedef __attribute__((ext_vector_type(8))) short s16x8;
typedef __attribute__((ext_vector_type(4))) short s16x4;
typedef __attribute__((ext_vector_type(8))) u16 u16x8;

__device__ __forceinline__ u16 f2bf(float x) {
    __hip_bfloat16 h = __float2bfloat16(x);
    return *reinterpret_cast<u16*>(&h);
}
__device__ __forceinline__ float bf2f(u16 u) {
    __hip_bfloat16 h;
    *reinterpret_cast<u16*>(&h) = u;
    return __bfloat162float(h);
}
__device__ __forceinline__ f32x4 mfma16(s16x8 a, s16x8 b, f32x4 c) {
    return __builtin_amdgcn_mfma_f32_16x16x32_bf16(
        __builtin_bit_cast(bf16x8, a), __builtin_bit_cast(bf16x8, b), c, 0, 0, 0);
}
__device__ __forceinline__ f32x4 mfma16k16(s16x4 a, s16x4 b, f32x4 c) {
    return __builtin_amdgcn_mfma_f32_16x16x16bf16_1k(a, b, c, 0, 0, 0);
}
__device__ __forceinline__ void gload16(const void* g, void* l) {
    __builtin_amdgcn_global_load_lds(
        (const __attribute__((address_space(1))) void*)g,
        (__attribute__((address_space(3))) void*)l, 16, 0, 0);
}
// Stage one 8KB plane (64 rows x 128B) with XOR-preswizzled source.
// LDS chunk (r, c) receives global chunk (r, c ^ (r&7)).  Dest is wave-uniform.
__device__ __forceinline__ void stage8k(const char* g, size_t rstrideB,
                                        char* ldsPlane, int w, int lane) {
    int r = w * 8 + (lane >> 3);
    int cs = (lane & 7) ^ (r & 7);
    gload16(g + (size_t)r * rstrideB + cs * 16, ldsPlane + (size_t)w * 1024);
}
#define WAIT_STAGE() { asm volatile("s_waitcnt vmcnt(0)" ::: "memory"); \
    __builtin_amdgcn_sched_barrier(0); __builtin_amdgcn_s_barrier(); \
    __builtin_amdgcn_sched_barrier(0); }

#define QK6(s, kh0, kh1, kl0, kl1, q0, q1, q2, q3) \
    s = mfma16(kh0, q0, s); s = mfma16(kh1, q1, s); \
    s = mfma16(kh0, q2, s); s = mfma16(kh1, q3, s); \
    s = mfma16(kl0, q0, s); s = mfma16(kl1, q1, s);

// ---------------------------------------------------------------------------
// GEMM NT: Y = A * W^T + bias. K=1024. 128x128 tile (unchanged, proven).
// ---------------------------------------------------------------------------
template<int SPLIT, int A_BF16, int OUT_MODE>
__global__ __launch_bounds__(256)
void gemm_mfma(const void* __restrict__ Ap, const float* __restrict__ Wp,
               const float* __restrict__ bias,
               void* __restrict__ Y0p, void* __restrict__ Y1p,
               int M, int N, int bshift) {
    const int K = 1024;
    __shared__ u16 sA[2][128 * 40];
    __shared__ u16 sB[2][128 * 40];

    const int t = threadIdx.x;
    const int lane = t & 63;
    const int w = t >> 6;
    const int wm = w >> 1, wn = w & 1;
    const int rowBase = blockIdx.y * 128;
    const int colBase = blockIdx.x * 128;
    const int srow = t >> 1;
    const int sc = (t & 1) * 16;

    const float* Af = (const float*)Ap;
    const u16* Au = (const u16*)Ap;

    f32x4 acc[4][4];
#pragma unroll
    for (int i = 0; i < 4; ++i)
#pragma unroll
        for (int j = 0; j < 4; ++j) acc[i][j] = (f32x4){0.f, 0.f, 0.f, 0.f};

    float ax[16], bx[16];
    u16x8 au0, au1;
    {
        if constexpr (A_BF16) {
            au0 = *(const u16x8*)&Au[(size_t)(rowBase + srow) * K + sc];
            au1 = *(const u16x8*)&Au[(size_t)(rowBase + srow) * K + sc + 8];
        } else {
#pragma unroll
            for (int j = 0; j < 4; ++j)
                *(float4*)&ax[j * 4] = *(const float4*)&Af[(size_t)(rowBase + srow) * K + sc + j * 4];
        }
#pragma unroll
        for (int j = 0; j < 4; ++j)
            *(float4*)&bx[j * 4] = *(const float4*)&Wp[(size_t)(colBase + srow) * K + sc + j * 4];
    }

    for (int k0 = 0; k0 < K; k0 += 32) {
        __syncthreads();
        {
            u16x8 h0, h1, l0, l1;
            if constexpr (A_BF16) {
                h0 = au0; h1 = au1;
            } else {
#pragma unroll
                for (int j = 0; j < 8; ++j) {
                    h0[j] = f2bf(ax[j]); h1[j] = f2bf(ax[j + 8]);
                    if constexpr (SPLIT) {
                        l0[j] = f2bf(ax[j] - bf2f(h0[j]));
                        l1[j] = f2bf(ax[j + 8] - bf2f(h1[j]));
                    }
                }
            }
            *(u16x8*)&sA[0][srow * 40 + sc] = h0;
            *(u16x8*)&sA[0][srow * 40 + sc + 8] = h1;
            if constexpr (SPLIT) {
                *(u16x8*)&sA[1][srow * 40 + sc] = l0;
                *(u16x8*)&sA[1][srow * 40 + sc + 8] = l1;
            }
            u16x8 bh0, bh1, bl0, bl1;
#pragma unroll
            for (int j = 0; j < 8; ++j) {
                bh0[j] = f2bf(bx[j]); bh1[j] = f2bf(bx[j + 8]);
                if constexpr (SPLIT) {
                    bl0[j] = f2bf(bx[j] - bf2f(bh0[j]));
                    bl1[j] = f2bf(bx[j + 8] - bf2f(bh1[j]));
                }
            }
            *(u16x8*)&sB[0][srow * 40 + sc] = bh0;
            *(u16x8*)&sB[0][srow * 40 + sc + 8] = bh1;
            if constexpr (SPLIT) {
                *(u16x8*)&sB[1][srow * 40 + sc] = bl0;
                *(u16x8*)&sB[1][srow * 40 + sc + 8] = bl1;
            }
        }
        __syncthreads();
        if (k0 + 32 < K) {
            const int kn = k0 + 32;
            if constexpr (A_BF16) {
                au0 = *(const u16x8*)&Au[(size_t)(rowBase + srow) * K + kn + sc];
                au1 = *(const u16x8*)&Au[(size_t)(rowBase + srow) * K + kn + sc + 8];
            } else {
#pragma unroll
                for (int j = 0; j < 4; ++j)
                    *(float4*)&ax[j * 4] = *(const float4*)&Af[(size_t)(rowBase + srow) * K + kn + sc + j * 4];
            }
#pragma unroll
            for (int j = 0; j < 4; ++j)
                *(float4*)&bx[j * 4] = *(const float4*)&Wp[(size_t)(colBase + srow) * K + kn + sc + j * 4];
        }
        {
            s16x8 afh[4], afl[4], bfh[4], bfl[4];
#pragma unroll
            for (int mi = 0; mi < 4; ++mi) {
                int ai = (wm * 64 + mi * 16 + (lane & 15)) * 40 + (lane >> 4) * 8;
                afh[mi] = *(const s16x8*)&sA[0][ai];
                if constexpr (SPLIT) afl[mi] = *(const s16x8*)&sA[1][ai];
            }
#pragma unroll
            for (int ni = 0; ni < 4; ++ni) {
                int bi = (wn * 64 + ni * 16 + (lane & 15)) * 40 + (lane >> 4) * 8;
                bfh[ni] = *(const s16x8*)&sB[0][bi];
                if constexpr (SPLIT) bfl[ni] = *(const s16x8*)&sB[1][bi];
            }
#pragma unroll
            for (int mi = 0; mi < 4; ++mi)
#pragma unroll
                for (int ni = 0; ni < 4; ++ni) {
                    acc[mi][ni] = mfma16(afh[mi], bfh[ni], acc[mi][ni]);
                    if constexpr (SPLIT) {
                        acc[mi][ni] = mfma16(afh[mi], bfl[ni], acc[mi][ni]);
                        acc[mi][ni] = mfma16(afl[mi], bfh[ni], acc[mi][ni]);
                    }
                }
        }
    }

#pragma unroll
    for (int mi = 0; mi < 4; ++mi)
#pragma unroll
        for (int ni = 0; ni < 4; ++ni)
#pragma unroll
            for (int rr = 0; rr < 4; ++rr) {
                int mg = rowBase + wm * 64 + mi * 16 + (lane >> 4) * 4 + rr;
                int ng = colBase + wn * 64 + ni * 16 + (lane & 15);
                float y = acc[mi][ni][rr];
                if constexpr (OUT_MODE == 0) {
                    ((float*)Y0p)[(size_t)mg * N + ng] = y + bias[ng];
                } else if constexpr (OUT_MODE == 1) {
                    y += bias[ng];
                    u16 hh = f2bf(y);
                    ((u16*)Y0p)[(size_t)mg * N + ng] = hh;
                    ((u16*)Y1p)[(size_t)mg * N + ng] = f2bf(y - bf2f(hh));
                } else if constexpr (OUT_MODE == 3) {
                    y += bias[ng];
                    int bb = mg >> bshift, s = mg & ((1 << bshift) - 1);
                    size_t idx = ((((size_t)(bb * 16 + (ng >> 6))) << bshift) + s) * 64 + (ng & 63);
                    u16 hh = f2bf(y);
                    ((u16*)Y0p)[idx] = hh;
                    ((u16*)Y1p)[idx] = f2bf(y - bf2f(hh));
                } else if constexpr (OUT_MODE == 4) {
                    y += bias[mg];
                    size_t idx = ((size_t)((ng >> 11) * 16 + (mg >> 6)) * 64 + (mg & 63)) * 2048 + (ng & 2047);
                    ((u16*)Y0p)[idx] = f2bf(y);
                }
            }
}

// ---------------------------------------------------------------------------
// Pass 1: attended output + denominators, qtile128, PLAIN-bf16 QK^T.
// (Split not needed here: l averages per-score noise over 2048 k; numerator
// errors average under the p-weighted sum. attn_mean keeps full precision.)
// Block=(b,h,qtile128), grid 512. 512 thr = 4wq x 2wk; 32 q rows/wave in
// registers. 32 chunks of 64k; K(hi only)+V dbuf in 32KB LDS. PV accumulates
// unnormalized bf16 e; f32 lsum per q-frag. Epilogue per q-half: cross-wk
// reduce, write Att = O/l and llog = log2(l).
// ---------------------------------------------------------------------------
__global__ __launch_bounds__(512, 4)
void attn_O(const u16* __restrict__ Qhi, const u16* __restrict__ Khi,
            const u16* __restrict__ VT, u16* __restrict__ Att,
            float* __restrict__ llog) {
    __shared__ char lds[36864];
    // staging: K dbuf [0,8K),[8K,16K); V dbuf [16K,24K),[24K,32K)
    // epilogue (after final barrier): sOf f32[2][64][68] @0 (34816B), sL2 @34816
    float* sOf = (float*)lds;
    float* sL2 = (float*)(lds + 34816);

    const int t = threadIdx.x;
    const int w = t >> 6, lane = t & 63;
    const int g = lane >> 4, c16 = lane & 15;
    const int qt = blockIdx.x >> 6;
    const int g6 = blockIdx.x & 63;
    const int b = g6 >> 4, h = g6 & 15;
    const int qbase = qt * 128;
    const int wq = w >> 1, wk = w & 1;
    const int kswz = (g ^ (c16 & 7)) << 4;
    const int vsw0 = (((wk * 4 + 0 + (g >> 1)) ^ (c16 & 7)) << 4) | ((g & 1) << 3);
    const int vsw1 = (((wk * 4 + 2 + (g >> 1)) ^ (c16 & 7)) << 4) | ((g & 1) << 3);

    const char* Kh_g = (const char*)(Khi + (size_t)(b * 16 + h) * SKL * 64);
    const char* V_g  = (const char*)(VT + (size_t)(b * 16 + h) * 64 * SKL);

    // Q fragments direct from global, once per block
    s16x8 qh[2][2];
    const size_t qrowbase = (size_t)(b * 16 + h) * SQL + qbase;
#pragma unroll
    for (int qf = 0; qf < 2; ++qf) {
        size_t qo = (qrowbase + wq * 32 + qf * 16 + c16) * 64 + g * 8;
        qh[qf][0] = *(const s16x8*)&Qhi[qo];
        qh[qf][1] = *(const s16x8*)&Qhi[qo + 32];
    }

    stage8k(Kh_g, 128, lds, w, lane);
    stage8k(V_g, 4096, lds + 16384, w, lane);

    f32x4 oacc[2][4];
#pragma unroll
    for (int qf = 0; qf < 2; ++qf)
#pragma unroll
        for (int i = 0; i < 4; ++i) oacc[qf][i] = (f32x4){0.f, 0.f, 0.f, 0.f};
    float lsum[2] = {0.f, 0.f};

    for (int c = 0; c < 32; ++c) {
        WAIT_STAGE();
        if (c < 31) {
            stage8k(Kh_g + (size_t)(c + 1) * 8192, 128, lds + ((c + 1) & 1) * 8192, w, lane);
            stage8k(V_g + (size_t)(c + 1) * 128, 4096, lds + 16384 + ((c + 1) & 1) * 8192, w, lane);
        }
        char* curK = lds + (c & 1) * 8192;
        char* curV = lds + 16384 + (c & 1) * 8192;
#pragma unroll
        for (int kf = 0; kf < 2; ++kf) {
            int kb = (wk * 32 + kf * 16 + c16) * 128 + kswz;
            s16x8 kh0 = *(const s16x8*)(curK + kb);
            s16x8 kh1 = *(const s16x8*)(curK + (kb ^ 64));
            s16x4 pb[2];
#pragma unroll
            for (int qf = 0; qf < 2; ++qf) {
                f32x4 s = {0.f, 0.f, 0.f, 0.f};
                s = mfma16(kh0, qh[qf][0], s);
                s = mfma16(kh1, qh[qf][1], s);
                float e0 = exp2f(s[0] * PSC);
                float e1 = exp2f(s[1] * PSC);
                float e2 = exp2f(s[2] * PSC);
                float e3 = exp2f(s[3] * PSC);
                lsum[qf] += (e0 + e1) + (e2 + e3);
                pb[qf][0] = (short)f2bf(e0); pb[qf][1] = (short)f2bf(e1);
                pb[qf][2] = (short)f2bf(e2); pb[qf][3] = (short)f2bf(e3);
            }
            int vs = kf ? vsw1 : vsw0;
#pragma unroll
            for (int df = 0; df < 4; ++df) {
                s16x4 vf = *(const s16x4*)(curV + (df * 16 + c16) * 128 + vs);
                oacc[0][df] = mfma16k16(vf, pb[0], oacc[0][df]);
                oacc[1][df] = mfma16k16(vf, pb[1], oacc[1][df]);
            }
        }
    }

    // reduce l across the 4 k-groups (16 lanes each hold one q)
#pragma unroll
    for (int qf = 0; qf < 2; ++qf) {
        lsum[qf] += __shfl_xor(lsum[qf], 16, 64);
        lsum[qf] += __shfl_xor(lsum[qf], 32, 64);
    }
    __syncthreads();   // all compute done; staging region becomes sOf
#pragma unroll
    for (int qf = 0; qf < 2; ++qf)
        if (g == 0) sL2[wk * 128 + wq * 32 + qf * 16 + c16] = lsum[qf];

    // epilogue per q-half: waves wq in {2*half, 2*half+1} dump partials
#pragma unroll
    for (int half = 0; half < 2; ++half) {
        if (half) __syncthreads();
        if ((wq >> 1) == half) {
            int qlocal = (wq & 1) * 32 + c16;
#pragma unroll
            for (int qf = 0; qf < 2; ++qf)
#pragma unroll
                for (int df = 0; df < 4; ++df)
#pragma unroll
                    for (int r = 0; r < 4; ++r)
                        sOf[wk * 4352 + (df * 16 + g * 4 + r) * 68 + qlocal + qf * 16] =
                            oacc[qf][df][r];
        }
        __syncthreads();
        {
            int q = t >> 3, dg = t & 7;
            float l = sL2[half * 64 + q] + sL2[128 + half * 64 + q];
            float linv = 1.f / l;
            u16x8 ov;
#pragma unroll
            for (int i = 0; i < 8; ++i) {
                int d = dg * 8 + i;
                ov[i] = f2bf((sOf[d * 68 + q] + sOf[4352 + d * 68 + q]) * linv);
            }
            *(u16x8*)&Att[(size_t)(b * SQL + qbase + half * 64 + q) * EMBED + h * 64 + dg * 8] = ov;
            if (dg == 0)
                llog[(size_t)(b * 16 + h) * SQL + qbase + half * 64 + q] = log2f(l);
        }
    }
}

// ---------------------------------------------------------------------------
// Pass 2: mean_attn, qtile128 x kslab128 (unchanged from r9; keeps split-bf16
// QK^T for per-element p precision). 32 iterations; Q single-buffered per
// head, K dbuf; p = exp2(s*PSC - lb) final; mean in 32 VGPRs, written once.
// ---------------------------------------------------------------------------
__global__ __launch_bounds__(512, 4)
void attn_mean(const u16* __restrict__ Qhi, const u16* __restrict__ Qlo,
               const u16* __restrict__ Khi, const u16* __restrict__ Klo,
               const float* __restrict__ llog, float* __restrict__ meanOut) {
    __shared__ char lds[65536];   // Q: hi [0,16K) lo [16K,32K); K dbuf [32K,48K),[48K,64K)
    char* sQh = lds;
    char* sQl = lds + 16384;

    const int t = threadIdx.x;
    const int w = t >> 6, lane = t & 63;
    const int g = lane >> 4, c16 = lane & 15;
    const int qt = blockIdx.x >> 6;
    const int low = blockIdx.x & 63;
    const int b = low >> 4, ks = low & 15;
    const int qbase = qt * 128;
    const int kbase = ks * 128;
    const int wq = w >> 1, wk = w & 1;
    const int kswz = (g ^ (c16 & 7)) << 4;

    const size_t QH_STRIDE = (size_t)SQL * 128;   // bytes per head
    const size_t KH_STRIDE = (size_t)SKL * 128;
    const char* Qh_b = (const char*)(Qhi + ((size_t)(b * 16) * SQL + qbase) * 64);
    const char* Ql_b = (const char*)(Qlo + ((size_t)(b * 16) * SQL + qbase) * 64);
    const char* Kh_b = (const char*)(Khi + ((size_t)(b * 16) * SKL + kbase) * 64);
    const char* Kl_b = (const char*)(Klo + ((size_t)(b * 16) * SKL + kbase) * 64);

    f32x4 ma[2][4];
#pragma unroll
    for (int qf = 0; qf < 2; ++qf)
#pragma unroll
        for (int i = 0; i < 4; ++i) ma[qf][i] = (f32x4){0.f, 0.f, 0.f, 0.f};

    stage8k(Qh_b, 128, sQh, w, lane);
    stage8k(Qh_b + 8192, 128, sQh + 8192, w, lane);
    stage8k(Ql_b, 128, sQl, w, lane);
    stage8k(Ql_b + 8192, 128, sQl + 8192, w, lane);
    stage8k(Kh_b, 128, lds + 32768, w, lane);
    stage8k(Kl_b, 128, lds + 32768 + 8192, w, lane);
    float lbn0 = llog[(size_t)(b * 16) * SQL + qbase + wq * 32 + c16];
    float lbn1 = llog[(size_t)(b * 16) * SQL + qbase + wq * 32 + 16 + c16];

    s16x8 qh[2][2], ql[2][2];
    float lb0 = 0.f, lb1 = 0.f;

    for (int it = 0; it < 32; ++it) {
        const int c = it & 1;
        WAIT_STAGE();
        if (c == 0) {
#pragma unroll
            for (int qf = 0; qf < 2; ++qf) {
                int qb = (wq * 32 + qf * 16 + c16) * 128 + kswz;
                qh[qf][0] = *(const s16x8*)(sQh + qb);
                qh[qf][1] = *(const s16x8*)(sQh + (qb ^ 64));
                ql[qf][0] = *(const s16x8*)(sQl + qb);
                ql[qf][1] = *(const s16x8*)(sQl + (qb ^ 64));
            }
            lb0 = lbn0; lb1 = lbn1;
        }
        if (it + 1 < 32) {
            const int h2 = (it + 1) >> 1, c2 = (it + 1) & 1;
            char* nbK = lds + 32768 + ((it + 1) & 1) * 16384;
            stage8k(Kh_b + h2 * KH_STRIDE + (size_t)c2 * 8192, 128, nbK, w, lane);
            stage8k(Kl_b + h2 * KH_STRIDE + (size_t)c2 * 8192, 128, nbK + 8192, w, lane);
            if (c2 == 0) {
                stage8k(Qh_b + h2 * QH_STRIDE, 128, sQh, w, lane);
                stage8k(Qh_b + h2 * QH_STRIDE + 8192, 128, sQh + 8192, w, lane);
                stage8k(Ql_b + h2 * QH_STRIDE, 128, sQl, w, lane);
                stage8k(Ql_b + h2 * QH_STRIDE + 8192, 128, sQl + 8192, w, lane);
                lbn0 = llog[(size_t)(b * 16 + h2) * SQL + qbase + wq * 32 + c16];
                lbn1 = llog[(size_t)(b * 16 + h2) * SQL + qbase + wq * 32 + 16 + c16];
            }
        }
        char* curK = lds + 32768 + (it & 1) * 16384;
#pragma unroll
        for (int kf = 0; kf < 2; ++kf) {
            int kb = (wk * 32 + kf * 16 + c16) * 128 + kswz;
            s16x8 kh0 = *(const s16x8*)(curK + kb);
            s16x8 kh1 = *(const s16x8*)(curK + (kb ^ 64));
            s16x8 kl0 = *(const s16x8*)(curK + 8192 + kb);
            s16x8 kl1 = *(const s16x8*)(curK + 8192 + (kb ^ 64));
            {
                f32x4 s = {0.f, 0.f, 0.f, 0.f};
                QK6(s, kh0, kh1, kl0, kl1, qh[0][0], qh[0][1], ql[0][0], ql[0][1])
                ma[0][c * 2 + kf][0] += exp2f(s[0] * PSC - lb0);
                ma[0][c * 2 + kf][1] += exp2f(s[1] * PSC - lb0);
                ma[0][c * 2 + kf][2] += exp2f(s[2] * PSC - lb0);
                ma[0][c * 2 + kf][3] += exp2f(s[3] * PSC - lb0);
            }
            {
                f32x4 s = {0.f, 0.f, 0.f, 0.f};
                QK6(s, kh0, kh1, kl0, kl1, qh[1][0], qh[1][1], ql[1][0], ql[1][1])
                ma[1][c * 2 + kf][0] += exp2f(s[0] * PSC - lb1);
                ma[1][c * 2 + kf][1] += exp2f(s[1] * PSC - lb1);
                ma[1][c * 2 + kf][2] += exp2f(s[2] * PSC - lb1);
                ma[1][c * 2 + kf][3] += exp2f(s[3] * PSC - lb1);
            }
        }
    }

    const float s16c = 1.f / 16.f;
#pragma unroll
    for (int qf = 0; qf < 2; ++qf)
#pragma unroll
        for (int c = 0; c < 2; ++c)
#pragma unroll
            for (int kf = 0; kf < 2; ++kf) {
                f32x4 m = ma[qf][c * 2 + kf];
                m[0] *= s16c; m[1] *= s16c; m[2] *= s16c; m[3] *= s16c;
                *(f32x4*)&meanOut[(size_t)(b * SQL + qbase + wq * 32 + qf * 16 + c16) * SKL +
                                  kbase + c * 64 + wk * 32 + kf * 16 + g * 4] = m;
            }
}

// ---------------------------------------------------------------------------
extern "C" void kernel_launch(void* const* d_in, const int* in_sizes, int n_in,
                              void* d_out, int out_size, void* d_ws, size_t ws_size,
                              hipStream_t stream) {
    const float* query = (const float*)d_in[0];
    const float* key   = (const float*)d_in[1];
    const float* value = (const float*)d_in[2];
    const float* Wq = (const float*)d_in[3];
    const float* bq = (const float*)d_in[4];
    const float* Wk = (const float*)d_in[5];
    const float* bk = (const float*)d_in[6];
    const float* Wv = (const float*)d_in[7];
    const float* bv = (const float*)d_in[8];
    const float* Wo = (const float*)d_in[9];
    const float* bo = (const float*)d_in[10];

    float* out = (float*)d_out;                         // [4,1024,1024] f32
    float* meanOut = out + (size_t)BATCH * SQL * EMBED; // [4,1024,2048] f32

    u16* Qhi = (u16*)d_ws;                              // head-major [b][h][q][64]
    u16* Qlo = Qhi + (size_t)4096 * 1024;
    u16* Khi = Qlo + (size_t)4096 * 1024;               // [b][h][k][64]
    u16* Klo = Khi + (size_t)8192 * 1024;
    u16* VTh = Klo + (size_t)8192 * 1024;               // [b][h][d][2048]
    u16* Att = VTh + (size_t)8192 * 1024;               // [4096][1024] bf16
    float* llog = (float*)(Att + (size_t)4096 * 1024);  // [b*16+h][q]

    gemm_mfma<1, 0, 3><<<dim3(8, 32), 256, 0, stream>>>(query, Wq, bq, Qhi, Qlo, 4096, 1024, 10);
    gemm_mfma<1, 0, 3><<<dim3(8, 64), 256, 0, stream>>>(key, Wk, bk, Khi, Klo, 8192, 1024, 11);
    gemm_mfma<0, 0, 4><<<dim3(64, 8), 256, 0, stream>>>(Wv, value, bv, VTh, nullptr, 1024, 8192, 0);

    attn_O<<<dim3(512), dim3(512), 0, stream>>>(Qhi, Khi, VTh, Att, llog);
    attn_mean<<<dim3(512), dim3(512), 0, stream>>>(Qhi, Qlo, Khi, Klo, llog, meanOut);

    gemm_mfma<0, 1, 0><<<dim3(8, 32), 256, 0, stream>>>(Att, Wo, bo, out, nullptr, 4096, 1024, 0);
}

// Round 11
// 266.204 us; speedup vs baseline: 2.8739x; 1.1004x over previous
//
#include <hip/hip_runtime.h>
#include <hip/hip_bf16.h>
#include <math.h>

#define EMBED 1024
#define NHEADS 16
#define HDIM 64
#define BATCH 4
#define SQL 1024
#define SKL 2048
#define PSC 0.18033688f   // 0.125 * log2(e)

typedef unsigned short u16;
typedef __attribute__((ext_vector_type(4))) float f32x4;
typedef __attribute__((ext_vector_type(8))) __bf16 bf16x8;
typedef __attribute__((ext_vector_type(8))) short s16x8;
typedef __attribute__((ext_vector_type(4))) short s16x4;
typedef __attribute__((ext_vector_type(8))) u16 u16x8;

__device__ __forceinline__ u16 f2bf(float x) {
    __hip_bfloat16 h = __float2bfloat16(x);
    return *reinterpret_cast<u16*>(&h);
}
__device__ __forceinline__ float bf2f(u16 u) {
    __hip_bfloat16 h;
    *reinterpret_cast<u16*>(&h) = u;
    return __bfloat162float(h);
}
__device__ __forceinline__ f32x4 mfma16(s16x8 a, s16x8 b, f32x4 c) {
    return __builtin_amdgcn_mfma_f32_16x16x32_bf16(
        __builtin_bit_cast(bf16x8, a), __builtin_bit_cast(bf16x8, b), c, 0, 0, 0);
}
__device__ __forceinline__ f32x4 mfma16k16(s16x4 a, s16x4 b, f32x4 c) {
    return __builtin_amdgcn_mfma_f32_16x16x16bf16_1k(a, b, c, 0, 0, 0);
}
__device__ __forceinline__ void gload16(const void* g, void* l) {
    __builtin_amdgcn_global_load_lds(
        (const __attribute__((address_space(1))) void*)g,
        (__attribute__((address_space(3))) void*)l, 16, 0, 0);
}
// Stage one 8KB plane (64 rows x 128B) with XOR-preswizzled source.
__device__ __forceinline__ void stage8k(const char* g, size_t rstrideB,
                                        char* ldsPlane, int w, int lane) {
    int r = w * 8 + (lane >> 3);
    int cs = (lane & 7) ^ (r & 7);
    gload16(g + (size_t)r * rstrideB + cs * 16, ldsPlane + (size_t)w * 1024);
}
#define SBAR() { __builtin_amdgcn_sched_barrier(0); \
    __builtin_amdgcn_s_barrier(); __builtin_amdgcn_sched_barrier(0); }

// ---------------------------------------------------------------------------
// GEMM NT: Y = A * W^T + bias. K=1024. 128x128 tile (unchanged, proven).
// OUT_MODE 0: f32 + bias[col]. 1: bf16 hi/lo flat. 3: bf16 hi/lo head-major.
// 4: bf16 V^T head-major [b][h][d][2048] (+bias[row]).
// 5: bf16 hi-only head-major [b][h][s][64] (+bias[col]).
// ---------------------------------------------------------------------------
template<int SPLIT, int A_BF16, int OUT_MODE>
__global__ __launch_bounds__(256)
void gemm_mfma(const void* __restrict__ Ap, const float* __restrict__ Wp,
               const float* __restrict__ bias,
               void* __restrict__ Y0p, void* __restrict__ Y1p,
               int M, int N, int bshift) {
    const int K = 1024;
    __shared__ u16 sA[2][128 * 40];
    __shared__ u16 sB[2][128 * 40];

    const int t = threadIdx.x;
    const int lane = t & 63;
    const int w = t >> 6;
    const int wm = w >> 1, wn = w & 1;
    const int rowBase = blockIdx.y * 128;
    const int colBase = blockIdx.x * 128;
    const int srow = t >> 1;
    const int sc = (t & 1) * 16;

    const float* Af = (const float*)Ap;
    const u16* Au = (const u16*)Ap;

    f32x4 acc[4][4];
#pragma unroll
    for (int i = 0; i < 4; ++i)
#pragma unroll
        for (int j = 0; j < 4; ++j) acc[i][j] = (f32x4){0.f, 0.f, 0.f, 0.f};

    float ax[16], bx[16];
    u16x8 au0, au1;
    {
        if constexpr (A_BF16) {
            au0 = *(const u16x8*)&Au[(size_t)(rowBase + srow) * K + sc];
            au1 = *(const u16x8*)&Au[(size_t)(rowBase + srow) * K + sc + 8];
        } else {
#pragma unroll
            for (int j = 0; j < 4; ++j)
                *(float4*)&ax[j * 4] = *(const float4*)&Af[(size_t)(rowBase + srow) * K + sc + j * 4];
        }
#pragma unroll
        for (int j = 0; j < 4; ++j)
            *(float4*)&bx[j * 4] = *(const float4*)&Wp[(size_t)(colBase + srow) * K + sc + j * 4];
    }

    for (int k0 = 0; k0 < K; k0 += 32) {
        __syncthreads();
        {
            u16x8 h0, h1, l0, l1;
            if constexpr (A_BF16) {
                h0 = au0; h1 = au1;
            } else {
#pragma unroll
                for (int j = 0; j < 8; ++j) {
                    h0[j] = f2bf(ax[j]); h1[j] = f2bf(ax[j + 8]);
                    if constexpr (SPLIT) {
                        l0[j] = f2bf(ax[j] - bf2f(h0[j]));
                        l1[j] = f2bf(ax[j + 8] - bf2f(h1[j]));
                    }
                }
            }
            *(u16x8*)&sA[0][srow * 40 + sc] = h0;
            *(u16x8*)&sA[0][srow * 40 + sc + 8] = h1;
            if constexpr (SPLIT) {
                *(u16x8*)&sA[1][srow * 40 + sc] = l0;
                *(u16x8*)&sA[1][srow * 40 + sc + 8] = l1;
            }
            u16x8 bh0, bh1, bl0, bl1;
#pragma unroll
            for (int j = 0; j < 8; ++j) {
                bh0[j] = f2bf(bx[j]); bh1[j] = f2bf(bx[j + 8]);
                if constexpr (SPLIT) {
                    bl0[j] = f2bf(bx[j] - bf2f(bh0[j]));
                    bl1[j] = f2bf(bx[j + 8] - bf2f(bh1[j]));
                }
            }
            *(u16x8*)&sB[0][srow * 40 + sc] = bh0;
            *(u16x8*)&sB[0][srow * 40 + sc + 8] = bh1;
            if constexpr (SPLIT) {
                *(u16x8*)&sB[1][srow * 40 + sc] = bl0;
                *(u16x8*)&sB[1][srow * 40 + sc + 8] = bl1;
            }
        }
        __syncthreads();
        if (k0 + 32 < K) {
            const int kn = k0 + 32;
            if constexpr (A_BF16) {
                au0 = *(const u16x8*)&Au[(size_t)(rowBase + srow) * K + kn + sc];
                au1 = *(const u16x8*)&Au[(size_t)(rowBase + srow) * K + kn + sc + 8];
            } else {
#pragma unroll
                for (int j = 0; j < 4; ++j)
                    *(float4*)&ax[j * 4] = *(const float4*)&Af[(size_t)(rowBase + srow) * K + kn + sc + j * 4];
            }
#pragma unroll
            for (int j = 0; j < 4; ++j)
                *(float4*)&bx[j * 4] = *(const float4*)&Wp[(size_t)(colBase + srow) * K + kn + sc + j * 4];
        }
        {
            s16x8 afh[4], afl[4], bfh[4], bfl[4];
#pragma unroll
            for (int mi = 0; mi < 4; ++mi) {
                int ai = (wm * 64 + mi * 16 + (lane & 15)) * 40 + (lane >> 4) * 8;
                afh[mi] = *(const s16x8*)&sA[0][ai];
                if constexpr (SPLIT) afl[mi] = *(const s16x8*)&sA[1][ai];
            }
#pragma unroll
            for (int ni = 0; ni < 4; ++ni) {
                int bi = (wn * 64 + ni * 16 + (lane & 15)) * 40 + (lane >> 4) * 8;
                bfh[ni] = *(const s16x8*)&sB[0][bi];
                if constexpr (SPLIT) bfl[ni] = *(const s16x8*)&sB[1][bi];
            }
#pragma unroll
            for (int mi = 0; mi < 4; ++mi)
#pragma unroll
                for (int ni = 0; ni < 4; ++ni) {
                    acc[mi][ni] = mfma16(afh[mi], bfh[ni], acc[mi][ni]);
                    if constexpr (SPLIT) {
                        acc[mi][ni] = mfma16(afh[mi], bfl[ni], acc[mi][ni]);
                        acc[mi][ni] = mfma16(afl[mi], bfh[ni], acc[mi][ni]);
                    }
                }
        }
    }

#pragma unroll
    for (int mi = 0; mi < 4; ++mi)
#pragma unroll
        for (int ni = 0; ni < 4; ++ni)
#pragma unroll
            for (int rr = 0; rr < 4; ++rr) {
                int mg = rowBase + wm * 64 + mi * 16 + (lane >> 4) * 4 + rr;
                int ng = colBase + wn * 64 + ni * 16 + (lane & 15);
                float y = acc[mi][ni][rr];
                if constexpr (OUT_MODE == 0) {
                    ((float*)Y0p)[(size_t)mg * N + ng] = y + bias[ng];
                } else if constexpr (OUT_MODE == 1) {
                    y += bias[ng];
                    u16 hh = f2bf(y);
                    ((u16*)Y0p)[(size_t)mg * N + ng] = hh;
                    ((u16*)Y1p)[(size_t)mg * N + ng] = f2bf(y - bf2f(hh));
                } else if constexpr (OUT_MODE == 3) {
                    y += bias[ng];
                    int bb = mg >> bshift, s = mg & ((1 << bshift) - 1);
                    size_t idx = ((((size_t)(bb * 16 + (ng >> 6))) << bshift) + s) * 64 + (ng & 63);
                    u16 hh = f2bf(y);
                    ((u16*)Y0p)[idx] = hh;
                    ((u16*)Y1p)[idx] = f2bf(y - bf2f(hh));
                } else if constexpr (OUT_MODE == 4) {
                    y += bias[mg];
                    size_t idx = ((size_t)((ng >> 11) * 16 + (mg >> 6)) * 64 + (mg & 63)) * 2048 + (ng & 2047);
                    ((u16*)Y0p)[idx] = f2bf(y);
                } else if constexpr (OUT_MODE == 5) {
                    y += bias[ng];
                    int bb = mg >> bshift, s = mg & ((1 << bshift) - 1);
                    size_t idx = ((((size_t)(bb * 16 + (ng >> 6))) << bshift) + s) * 64 + (ng & 63);
                    ((u16*)Y0p)[idx] = f2bf(y);
                }
            }
}

// ---------------------------------------------------------------------------
// Pass 1: attended output + denominators, qtile128, plain-bf16 QK^T.
// K/V TRIPLE-buffered with counted vmcnt(2) (2-deep prefetch, never drains
// in the main loop). Single barrier per iter: buffer (c+2)%3 was consumed at
// iter c-1, and the pre-barrier per-wave vmcnt guarantees all waves' staging
// portions landed before any wave reads. Q in registers.
// ---------------------------------------------------------------------------
__global__ __launch_bounds__(512, 4)
void attn_O(const u16* __restrict__ Qhi, const u16* __restrict__ Khi,
            const u16* __restrict__ VT, u16* __restrict__ Att,
            float* __restrict__ llog) {
    __shared__ char lds[49152];
    // staging: K bufs 3x8K @0; V bufs 3x8K @24576.
    // epilogue (after final barrier): sOf f32[2][64][68] @0; sL2 @35840.
    float* sOf = (float*)lds;
    float* sL2 = (float*)(lds + 35840);

    const int t = threadIdx.x;
    const int w = t >> 6, lane = t & 63;
    const int g = lane >> 4, c16 = lane & 15;
    const int qt = blockIdx.x >> 6;
    const int g6 = blockIdx.x & 63;
    const int b = g6 >> 4, h = g6 & 15;
    const int qbase = qt * 128;
    const int wq = w >> 1, wk = w & 1;
    const int kswz = (g ^ (c16 & 7)) << 4;
    const int vsw0 = (((wk * 4 + 0 + (g >> 1)) ^ (c16 & 7)) << 4) | ((g & 1) << 3);
    const int vsw1 = (((wk * 4 + 2 + (g >> 1)) ^ (c16 & 7)) << 4) | ((g & 1) << 3);

    const char* Kh_g = (const char*)(Khi + (size_t)(b * 16 + h) * SKL * 64);
    const char* V_g  = (const char*)(VT + (size_t)(b * 16 + h) * 64 * SKL);

    // Q fragments direct from global, once per block
    s16x8 qh[2][2];
    const size_t qrowbase = (size_t)(b * 16 + h) * SQL + qbase;
#pragma unroll
    for (int qf = 0; qf < 2; ++qf) {
        size_t qo = (qrowbase + wq * 32 + qf * 16 + c16) * 64 + g * 8;
        qh[qf][0] = *(const s16x8*)&Qhi[qo];
        qh[qf][1] = *(const s16x8*)&Qhi[qo + 32];
    }

    // prologue: chunks 0 and 1
    stage8k(Kh_g, 128, lds, w, lane);
    stage8k(V_g, 4096, lds + 24576, w, lane);
    stage8k(Kh_g + 8192, 128, lds + 8192, w, lane);
    stage8k(V_g + 128, 4096, lds + 24576 + 8192, w, lane);

    f32x4 oacc[2][4];
#pragma unroll
    for (int qf = 0; qf < 2; ++qf)
#pragma unroll
        for (int i = 0; i < 4; ++i) oacc[qf][i] = (f32x4){0.f, 0.f, 0.f, 0.f};
    float lsum[2] = {0.f, 0.f};

    int cur = 0;   // c % 3
    for (int c = 0; c < 32; ++c) {
        if (c < 31) { asm volatile("s_waitcnt vmcnt(2)" ::: "memory"); }
        else        { asm volatile("s_waitcnt vmcnt(0)" ::: "memory"); }
        SBAR();
        if (c + 2 < 32) {
            int nb = cur + 2; if (nb >= 3) nb -= 3;
            stage8k(Kh_g + (size_t)(c + 2) * 8192, 128, lds + nb * 8192, w, lane);
            stage8k(V_g + (size_t)(c + 2) * 128, 4096, lds + 24576 + nb * 8192, w, lane);
        }
        char* curK = lds + cur * 8192;
        char* curV = lds + 24576 + cur * 8192;
#pragma unroll
        for (int kf = 0; kf < 2; ++kf) {
            int kb = (wk * 32 + kf * 16 + c16) * 128 + kswz;
            s16x8 kh0 = *(const s16x8*)(curK + kb);
            s16x8 kh1 = *(const s16x8*)(curK + (kb ^ 64));
            s16x4 pb[2];
#pragma unroll
            for (int qf = 0; qf < 2; ++qf) {
                f32x4 s = {0.f, 0.f, 0.f, 0.f};
                s = mfma16(kh0, qh[qf][0], s);
                s = mfma16(kh1, qh[qf][1], s);
                float e0 = exp2f(s[0] * PSC);
                float e1 = exp2f(s[1] * PSC);
                float e2 = exp2f(s[2] * PSC);
                float e3 = exp2f(s[3] * PSC);
                lsum[qf] += (e0 + e1) + (e2 + e3);
                pb[qf][0] = (short)f2bf(e0); pb[qf][1] = (short)f2bf(e1);
                pb[qf][2] = (short)f2bf(e2); pb[qf][3] = (short)f2bf(e3);
            }
            int vs = kf ? vsw1 : vsw0;
#pragma unroll
            for (int df = 0; df < 4; ++df) {
                s16x4 vf = *(const s16x4*)(curV + (df * 16 + c16) * 128 + vs);
                oacc[0][df] = mfma16k16(vf, pb[0], oacc[0][df]);
                oacc[1][df] = mfma16k16(vf, pb[1], oacc[1][df]);
            }
        }
        ++cur; if (cur == 3) cur = 0;
    }

    // reduce l across the 4 k-groups (16 lanes each hold one q)
#pragma unroll
    for (int qf = 0; qf < 2; ++qf) {
        lsum[qf] += __shfl_xor(lsum[qf], 16, 64);
        lsum[qf] += __shfl_xor(lsum[qf], 32, 64);
    }
    __syncthreads();   // all compute done; staging region becomes sOf
#pragma unroll
    for (int qf = 0; qf < 2; ++qf)
        if (g == 0) sL2[wk * 128 + wq * 32 + qf * 16 + c16] = lsum[qf];

    // epilogue per q-half
#pragma unroll
    for (int half = 0; half < 2; ++half) {
        if (half) __syncthreads();
        if ((wq >> 1) == half) {
            int qlocal = (wq & 1) * 32 + c16;
#pragma unroll
            for (int qf = 0; qf < 2; ++qf)
#pragma unroll
                for (int df = 0; df < 4; ++df)
#pragma unroll
                    for (int r = 0; r < 4; ++r)
                        sOf[wk * 4352 + (df * 16 + g * 4 + r) * 68 + qlocal + qf * 16] =
                            oacc[qf][df][r];
        }
        __syncthreads();
        {
            int q = t >> 3, dg = t & 7;
            float l = sL2[half * 64 + q] + sL2[128 + half * 64 + q];
            float linv = 1.f / l;
            u16x8 ov;
#pragma unroll
            for (int i = 0; i < 8; ++i) {
                int d = dg * 8 + i;
                ov[i] = f2bf((sOf[d * 68 + q] + sOf[4352 + d * 68 + q]) * linv);
            }
            *(u16x8*)&Att[(size_t)(b * SQL + qbase + half * 64 + q) * EMBED + h * 64 + dg * 8] = ov;
            if (dg == 0)
                llog[(size_t)(b * 16 + h) * SQL + qbase + half * 64 + q] = log2f(l);
        }
    }
}

// ---------------------------------------------------------------------------
// Pass 2: mean_attn, qtile128 x kslab128, plain-bf16 QK^T (projections are
// split-accurate; only bf16 rounding noise enters s: ~1.6e-3 relative on p,
// ~1.5e-6 absolute on the 16-head mean -- inside threshold margin).
// 16 iterations (1 head each, full 128k staged). Q dbuf 2x16K, K triple-buf
// 3x16K (80KB, 2 blocks/CU). Uniform counted vmcnt(4): every issue-group is
// >=4 loads (Q2+K2, llog loads float freely), so the 4 newest always belong
// to group h+1 -- group h is fully waited, never underwaits. Barrier #2
// protects Q buffer overwrite (issued into buf h&1 after all waves read it).
// ---------------------------------------------------------------------------
__global__ __launch_bounds__(512, 4)
void attn_mean(const u16* __restrict__ Qhi, const u16* __restrict__ Khi,
               const float* __restrict__ llog, float* __restrict__ meanOut) {
    __shared__ char lds[81920];   // Q dbuf 2x16K @0; K tbuf 3x16K @32768

    const int t = threadIdx.x;
    const int w = t >> 6, lane = t & 63;
    const int g = lane >> 4, c16 = lane & 15;
    const int qt = blockIdx.x >> 6;
    const int low = blockIdx.x & 63;
    const int b = low >> 4, ks = low & 15;
    const int qbase = qt * 128;
    const int kbase = ks * 128;
    const int wq = w >> 1, wk = w & 1;
    const int kswz = (g ^ (c16 & 7)) << 4;

    const size_t QH_STRIDE = (size_t)SQL * 128;   // bytes per head
    const size_t KH_STRIDE = (size_t)SKL * 128;
    const char* Qh_b = (const char*)(Qhi + ((size_t)(b * 16) * SQL + qbase) * 64);
    const char* Kh_b = (const char*)(Khi + ((size_t)(b * 16) * SKL + kbase) * 64);
    const float* ll_b = llog + (size_t)(b * 16) * SQL + qbase;

    f32x4 ma[2][4];
#pragma unroll
    for (int qf = 0; qf < 2; ++qf)
#pragma unroll
        for (int i = 0; i < 4; ++i) ma[qf][i] = (f32x4){0.f, 0.f, 0.f, 0.f};

    // prologue: groups for h=0 and h=1
    stage8k(Qh_b, 128, lds, w, lane);
    stage8k(Qh_b + 8192, 128, lds + 8192, w, lane);
    float lbA0 = ll_b[wq * 32 + c16];
    float lbA1 = ll_b[wq * 32 + 16 + c16];
    stage8k(Kh_b, 128, lds + 32768, w, lane);
    stage8k(Kh_b + 8192, 128, lds + 32768 + 8192, w, lane);
    stage8k(Qh_b + QH_STRIDE, 128, lds + 16384, w, lane);
    stage8k(Qh_b + QH_STRIDE + 8192, 128, lds + 16384 + 8192, w, lane);
    float lbB0 = ll_b[SQL + wq * 32 + c16];
    float lbB1 = ll_b[SQL + wq * 32 + 16 + c16];
    stage8k(Kh_b + KH_STRIDE, 128, lds + 32768 + 16384, w, lane);
    stage8k(Kh_b + KH_STRIDE + 8192, 128, lds + 32768 + 16384 + 8192, w, lane);

    int curK = 0;   // h % 3
    for (int h = 0; h < 16; ++h) {
        if (h < 15) { asm volatile("s_waitcnt vmcnt(4)" ::: "memory"); }
        else        { asm volatile("s_waitcnt vmcnt(0)" ::: "memory"); }
        SBAR();

        // Q frags from buf h&1 (read BEFORE barrier #2, then safe to overwrite)
        const char* sQ = lds + (h & 1) * 16384;
        s16x8 qa0, qa1, qc0, qc1;
        {
            int qb0 = (wq * 32 + c16) * 128 + kswz;
            qa0 = *(const s16x8*)(sQ + qb0);
            qa1 = *(const s16x8*)(sQ + (qb0 ^ 64));
            int qb1 = (wq * 32 + 16 + c16) * 128 + kswz;
            qc0 = *(const s16x8*)(sQ + qb1);
            qc1 = *(const s16x8*)(sQ + (qb1 ^ 64));
        }
        asm volatile("s_waitcnt lgkmcnt(0)" ::: "memory");
        SBAR();

        float lb0 = lbA0, lb1 = lbA1;
        lbA0 = lbB0; lbA1 = lbB1;

        if (h + 2 < 16) {
            const char* Qg = Qh_b + (size_t)(h + 2) * QH_STRIDE;
            char* qdst = lds + (h & 1) * 16384;     // (h+2)&1 == h&1
            stage8k(Qg, 128, qdst, w, lane);
            stage8k(Qg + 8192, 128, qdst + 8192, w, lane);
            lbB0 = ll_b[(size_t)(h + 2) * SQL + wq * 32 + c16];
            lbB1 = ll_b[(size_t)(h + 2) * SQL + wq * 32 + 16 + c16];
            const char* Kg = Kh_b + (size_t)(h + 2) * KH_STRIDE;
            int nb = curK + 2; if (nb >= 3) nb -= 3;
            char* kdst = lds + 32768 + nb * 16384;
            stage8k(Kg, 128, kdst, w, lane);
            stage8k(Kg + 8192, 128, kdst + 8192, w, lane);
        }

        const char* sK = lds + 32768 + curK * 16384;
#pragma unroll
        for (int kf = 0; kf < 4; ++kf) {
            int kb = (kf * 32 + wk * 16 + c16) * 128 + kswz;
            s16x8 kh0 = *(const s16x8*)(sK + kb);
            s16x8 kh1 = *(const s16x8*)(sK + (kb ^ 64));
            {
                f32x4 s = {0.f, 0.f, 0.f, 0.f};
                s = mfma16(kh0, qa0, s);
                s = mfma16(kh1, qa1, s);
                ma[0][kf][0] += exp2f(s[0] * PSC - lb0);
                ma[0][kf][1] += exp2f(s[1] * PSC - lb0);
                ma[0][kf][2] += exp2f(s[2] * PSC - lb0);
                ma[0][kf][3] += exp2f(s[3] * PSC - lb0);
            }
            {
                f32x4 s = {0.f, 0.f, 0.f, 0.f};
                s = mfma16(kh0, qc0, s);
                s = mfma16(kh1, qc1, s);
                ma[1][kf][0] += exp2f(s[0] * PSC - lb1);
                ma[1][kf][1] += exp2f(s[1] * PSC - lb1);
                ma[1][kf][2] += exp2f(s[2] * PSC - lb1);
                ma[1][kf][3] += exp2f(s[3] * PSC - lb1);
            }
        }
        ++curK; if (curK == 3) curK = 0;
    }

    const float s16c = 1.f / 16.f;
#pragma unroll
    for (int qf = 0; qf < 2; ++qf)
#pragma unroll
        for (int kf = 0; kf < 4; ++kf) {
            f32x4 m = ma[qf][kf];
            m[0] *= s16c; m[1] *= s16c; m[2] *= s16c; m[3] *= s16c;
            *(f32x4*)&meanOut[(size_t)(b * SQL + qbase + wq * 32 + qf * 16 + c16) * SKL +
                              kbase + kf * 32 + wk * 16 + g * 4] = m;
        }
}

// ---------------------------------------------------------------------------
extern "C" void kernel_launch(void* const* d_in, const int* in_sizes, int n_in,
                              void* d_out, int out_size, void* d_ws, size_t ws_size,
                              hipStream_t stream) {
    const float* query = (const float*)d_in[0];
    const float* key   = (const float*)d_in[1];
    const float* value = (const float*)d_in[2];
    const float* Wq = (const float*)d_in[3];
    const float* bq = (const float*)d_in[4];
    const float* Wk = (const float*)d_in[5];
    const float* bk = (const float*)d_in[6];
    const float* Wv = (const float*)d_in[7];
    const float* bv = (const float*)d_in[8];
    const float* Wo = (const float*)d_in[9];
    const float* bo = (const float*)d_in[10];

    float* out = (float*)d_out;                         // [4,1024,1024] f32
    float* meanOut = out + (size_t)BATCH * SQL * EMBED; // [4,1024,2048] f32

    u16* Qhi = (u16*)d_ws;                              // head-major [b][h][q][64]
    u16* Khi = Qhi + (size_t)4096 * 1024;               // [b][h][k][64]
    u16* VTh = Khi + (size_t)8192 * 1024;               // [b][h][d][2048]
    u16* Att = VTh + (size_t)8192 * 1024;               // [4096][1024] bf16
    float* llog = (float*)(Att + (size_t)4096 * 1024);  // [b*16+h][q]

    gemm_mfma<1, 0, 5><<<dim3(8, 32), 256, 0, stream>>>(query, Wq, bq, Qhi, nullptr, 4096, 1024, 10);
    gemm_mfma<1, 0, 5><<<dim3(8, 64), 256, 0, stream>>>(key, Wk, bk, Khi, nullptr, 8192, 1024, 11);
    gemm_mfma<0, 0, 4><<<dim3(64, 8), 256, 0, stream>>>(Wv, value, bv, VTh, nullptr, 1024, 8192, 0);

    attn_O<<<dim3(512), dim3(512), 0, stream>>>(Qhi, Khi, VTh, Att, llog);
    attn_mean<<<dim3(512), dim3(512), 0, stream>>>(Qhi, Khi, llog, meanOut);

    gemm_mfma<0, 1, 0><<<dim3(8, 32), 256, 0, stream>>>(Att, Wo, bo, out, nullptr, 4096, 1024, 0);
}

// Round 12
// 257.169 us; speedup vs baseline: 2.9748x; 1.0351x over previous
//
#include <hip/hip_runtime.h>
#include <hip/hip_bf16.h>
#include <math.h>

#define EMBED 1024
#define NHEADS 16
#define HDIM 64
#define BATCH 4
#define SQL 1024
#define SKL 2048
#define PSC 0.18033688f   // 0.125 * log2(e)

typedef unsigned short u16;
typedef __attribute__((ext_vector_type(4))) float f32x4;
typedef __attribute__((ext_vector_type(8))) __bf16 bf16x8;
typedef __attribute__((ext_vector_type(8))) short s16x8;
typedef __attribute__((ext_vector_type(4))) short s16x4;
typedef __attribute__((ext_vector_type(8))) u16 u16x8;

__device__ __forceinline__ u16 f2bf(float x) {
    __hip_bfloat16 h = __float2bfloat16(x);
    return *reinterpret_cast<u16*>(&h);
}
__device__ __forceinline__ float bf2f(u16 u) {
    __hip_bfloat16 h;
    *reinterpret_cast<u16*>(&h) = u;
    return __bfloat162float(h);
}
__device__ __forceinline__ f32x4 mfma16(s16x8 a, s16x8 b, f32x4 c) {
    return __builtin_amdgcn_mfma_f32_16x16x32_bf16(
        __builtin_bit_cast(bf16x8, a), __builtin_bit_cast(bf16x8, b), c, 0, 0, 0);
}
__device__ __forceinline__ f32x4 mfma16k16(s16x4 a, s16x4 b, f32x4 c) {
    return __builtin_amdgcn_mfma_f32_16x16x16bf16_1k(a, b, c, 0, 0, 0);
}
__device__ __forceinline__ void gload16(const void* g, void* l) {
    __builtin_amdgcn_global_load_lds(
        (const __attribute__((address_space(1))) void*)g,
        (__attribute__((address_space(3))) void*)l, 16, 0, 0);
}
// Stage one 8KB plane (64 rows x 128B) with XOR-preswizzled source.
__device__ __forceinline__ void stage8k(const char* g, size_t rstrideB,
                                        char* ldsPlane, int w, int lane) {
    int r = w * 8 + (lane >> 3);
    int cs = (lane & 7) ^ (r & 7);
    gload16(g + (size_t)r * rstrideB + cs * 16, ldsPlane + (size_t)w * 1024);
}
#define SBAR() { __builtin_amdgcn_sched_barrier(0); \
    __builtin_amdgcn_s_barrier(); __builtin_amdgcn_sched_barrier(0); }

// ---------------------------------------------------------------------------
// split_w: W f32 [1024][1024] -> bf16 hi/lo planes (Wq and Wk in one launch).
// ---------------------------------------------------------------------------
__global__ __launch_bounds__(256)
void split_w(const float* __restrict__ Wq, const float* __restrict__ Wk,
             u16* __restrict__ Wqh, u16* __restrict__ Wql,
             u16* __restrict__ Wkh, u16* __restrict__ Wkl) {
    int bid = blockIdx.x;
    const float* src; u16 *dh, *dl;
    if (bid < 512) { src = Wq; dh = Wqh; dl = Wql; }
    else { bid -= 512; src = Wk; dh = Wkh; dl = Wkl; }
    size_t i = ((size_t)bid * 256 + threadIdx.x) * 8;
    float4 a = *(const float4*)&src[i];
    float4 b = *(const float4*)&src[i + 4];
    float v[8] = {a.x, a.y, a.z, a.w, b.x, b.y, b.z, b.w};
    u16x8 hi, lo;
#pragma unroll
    for (int j = 0; j < 8; ++j) {
        hi[j] = f2bf(v[j]);
        lo[j] = f2bf(v[j] - bf2f(hi[j]));
    }
    *(u16x8*)&dh[i] = hi;
    *(u16x8*)&dl[i] = lo;
}

// ---------------------------------------------------------------------------
// GEMM NT: Y = A * W^T + bias. K=1024. 128x128 tile.
// WPRE=1: W pre-split bf16 planes (Whp/Wlp), A fp32 staged hi-only; 2 MFMAs.
// OUT_MODE 0: f32 + bias[col]. 4: bf16 V^T head-major (+bias[row]).
// 5: bf16 hi-only head-major [b][h][s][64] (+bias[col]).
// ---------------------------------------------------------------------------
template<int SPLIT, int A_BF16, int WPRE, int OUT_MODE>
__global__ __launch_bounds__(256)
void gemm_mfma(const void* __restrict__ Ap, const float* __restrict__ Wp,
               const u16* __restrict__ Whp, const u16* __restrict__ Wlp,
               const float* __restrict__ bias,
               void* __restrict__ Y0p, void* __restrict__ Y1p,
               int M, int N, int bshift) {
    const int K = 1024;
    __shared__ u16 sA[2][128 * 40];
    __shared__ u16 sB[2][128 * 40];

    const int t = threadIdx.x;
    const int lane = t & 63;
    const int w = t >> 6;
    const int wm = w >> 1, wn = w & 1;
    const int rowBase = blockIdx.y * 128;
    const int colBase = blockIdx.x * 128;
    const int srow = t >> 1;
    const int sc = (t & 1) * 16;

    const float* Af = (const float*)Ap;
    const u16* Au = (const u16*)Ap;

    f32x4 acc[4][4];
#pragma unroll
    for (int i = 0; i < 4; ++i)
#pragma unroll
        for (int j = 0; j < 4; ++j) acc[i][j] = (f32x4){0.f, 0.f, 0.f, 0.f};

    float ax[16], bx[16];
    u16x8 au0, au1, wh0, wh1, wl0, wl1;
    {
        if constexpr (A_BF16) {
            au0 = *(const u16x8*)&Au[(size_t)(rowBase + srow) * K + sc];
            au1 = *(const u16x8*)&Au[(size_t)(rowBase + srow) * K + sc + 8];
        } else {
#pragma unroll
            for (int j = 0; j < 4; ++j)
                *(float4*)&ax[j * 4] = *(const float4*)&Af[(size_t)(rowBase + srow) * K + sc + j * 4];
        }
        if constexpr (WPRE) {
            wh0 = *(const u16x8*)&Whp[(size_t)(colBase + srow) * K + sc];
            wh1 = *(const u16x8*)&Whp[(size_t)(colBase + srow) * K + sc + 8];
            wl0 = *(const u16x8*)&Wlp[(size_t)(colBase + srow) * K + sc];
            wl1 = *(const u16x8*)&Wlp[(size_t)(colBase + srow) * K + sc + 8];
        } else {
#pragma unroll
            for (int j = 0; j < 4; ++j)
                *(float4*)&bx[j * 4] = *(const float4*)&Wp[(size_t)(colBase + srow) * K + sc + j * 4];
        }
    }

    for (int k0 = 0; k0 < K; k0 += 32) {
        __syncthreads();
        {
            u16x8 h0, h1, l0, l1;
            if constexpr (A_BF16) {
                h0 = au0; h1 = au1;
            } else {
#pragma unroll
                for (int j = 0; j < 8; ++j) {
                    h0[j] = f2bf(ax[j]); h1[j] = f2bf(ax[j + 8]);
                    if constexpr (SPLIT) {
                        l0[j] = f2bf(ax[j] - bf2f(h0[j]));
                        l1[j] = f2bf(ax[j + 8] - bf2f(h1[j]));
                    }
                }
            }
            *(u16x8*)&sA[0][srow * 40 + sc] = h0;
            *(u16x8*)&sA[0][srow * 40 + sc + 8] = h1;
            if constexpr (SPLIT) {
                *(u16x8*)&sA[1][srow * 40 + sc] = l0;
                *(u16x8*)&sA[1][srow * 40 + sc + 8] = l1;
            }
            if constexpr (WPRE) {
                *(u16x8*)&sB[0][srow * 40 + sc] = wh0;
                *(u16x8*)&sB[0][srow * 40 + sc + 8] = wh1;
                *(u16x8*)&sB[1][srow * 40 + sc] = wl0;
                *(u16x8*)&sB[1][srow * 40 + sc + 8] = wl1;
            } else {
                u16x8 bh0, bh1, bl0, bl1;
#pragma unroll
                for (int j = 0; j < 8; ++j) {
                    bh0[j] = f2bf(bx[j]); bh1[j] = f2bf(bx[j + 8]);
                    if constexpr (SPLIT) {
                        bl0[j] = f2bf(bx[j] - bf2f(bh0[j]));
                        bl1[j] = f2bf(bx[j + 8] - bf2f(bh1[j]));
                    }
                }
                *(u16x8*)&sB[0][srow * 40 + sc] = bh0;
                *(u16x8*)&sB[0][srow * 40 + sc + 8] = bh1;
                if constexpr (SPLIT) {
                    *(u16x8*)&sB[1][srow * 40 + sc] = bl0;
                    *(u16x8*)&sB[1][srow * 40 + sc + 8] = bl1;
                }
            }
        }
        __syncthreads();
        if (k0 + 32 < K) {
            const int kn = k0 + 32;
            if constexpr (A_BF16) {
                au0 = *(const u16x8*)&Au[(size_t)(rowBase + srow) * K + kn + sc];
                au1 = *(const u16x8*)&Au[(size_t)(rowBase + srow) * K + kn + sc + 8];
            } else {
#pragma unroll
                for (int j = 0; j < 4; ++j)
                    *(float4*)&ax[j * 4] = *(const float4*)&Af[(size_t)(rowBase + srow) * K + kn + sc + j * 4];
            }
            if constexpr (WPRE) {
                wh0 = *(const u16x8*)&Whp[(size_t)(colBase + srow) * K + kn + sc];
                wh1 = *(const u16x8*)&Whp[(size_t)(colBase + srow) * K + kn + sc + 8];
                wl0 = *(const u16x8*)&Wlp[(size_t)(colBase + srow) * K + kn + sc];
                wl1 = *(const u16x8*)&Wlp[(size_t)(colBase + srow) * K + kn + sc + 8];
            } else {
#pragma unroll
                for (int j = 0; j < 4; ++j)
                    *(float4*)&bx[j * 4] = *(const float4*)&Wp[(size_t)(colBase + srow) * K + kn + sc + j * 4];
            }
        }
        {
            s16x8 afh[4], afl[4], bfh[4], bfl[4];
#pragma unroll
            for (int mi = 0; mi < 4; ++mi) {
                int ai = (wm * 64 + mi * 16 + (lane & 15)) * 40 + (lane >> 4) * 8;
                afh[mi] = *(const s16x8*)&sA[0][ai];
                if constexpr (SPLIT) afl[mi] = *(const s16x8*)&sA[1][ai];
            }
#pragma unroll
            for (int ni = 0; ni < 4; ++ni) {
                int bi = (wn * 64 + ni * 16 + (lane & 15)) * 40 + (lane >> 4) * 8;
                bfh[ni] = *(const s16x8*)&sB[0][bi];
                if constexpr (SPLIT || WPRE) bfl[ni] = *(const s16x8*)&sB[1][bi];
            }
#pragma unroll
            for (int mi = 0; mi < 4; ++mi)
#pragma unroll
                for (int ni = 0; ni < 4; ++ni) {
                    acc[mi][ni] = mfma16(afh[mi], bfh[ni], acc[mi][ni]);
                    if constexpr (WPRE) {
                        acc[mi][ni] = mfma16(afh[mi], bfl[ni], acc[mi][ni]);
                    }
                    if constexpr (SPLIT) {
                        acc[mi][ni] = mfma16(afh[mi], bfl[ni], acc[mi][ni]);
                        acc[mi][ni] = mfma16(afl[mi], bfh[ni], acc[mi][ni]);
                    }
                }
        }
    }

#pragma unroll
    for (int mi = 0; mi < 4; ++mi)
#pragma unroll
        for (int ni = 0; ni < 4; ++ni)
#pragma unroll
            for (int rr = 0; rr < 4; ++rr) {
                int mg = rowBase + wm * 64 + mi * 16 + (lane >> 4) * 4 + rr;
                int ng = colBase + wn * 64 + ni * 16 + (lane & 15);
                float y = acc[mi][ni][rr];
                if constexpr (OUT_MODE == 0) {
                    ((float*)Y0p)[(size_t)mg * N + ng] = y + bias[ng];
                } else if constexpr (OUT_MODE == 4) {
                    y += bias[mg];
                    size_t idx = ((size_t)((ng >> 11) * 16 + (mg >> 6)) * 64 + (mg & 63)) * 2048 + (ng & 2047);
                    ((u16*)Y0p)[idx] = f2bf(y);
                } else if constexpr (OUT_MODE == 5) {
                    y += bias[ng];
                    int bb = mg >> bshift, s = mg & ((1 << bshift) - 1);
                    size_t idx = ((((size_t)(bb * 16 + (ng >> 6))) << bshift) + s) * 64 + (ng & 63);
                    ((u16*)Y0p)[idx] = f2bf(y);
                }
            }
}

// ---------------------------------------------------------------------------
// Pass 1: attended output + denominators (unchanged from r11).
// ---------------------------------------------------------------------------
__global__ __launch_bounds__(512, 4)
void attn_O(const u16* __restrict__ Qhi, const u16* __restrict__ Khi,
            const u16* __restrict__ VT, u16* __restrict__ Att,
            float* __restrict__ llog) {
    __shared__ char lds[49152];
    float* sOf = (float*)lds;
    float* sL2 = (float*)(lds + 35840);

    const int t = threadIdx.x;
    const int w = t >> 6, lane = t & 63;
    const int g = lane >> 4, c16 = lane & 15;
    const int qt = blockIdx.x >> 6;
    const int g6 = blockIdx.x & 63;
    const int b = g6 >> 4, h = g6 & 15;
    const int qbase = qt * 128;
    const int wq = w >> 1, wk = w & 1;
    const int kswz = (g ^ (c16 & 7)) << 4;
    const int vsw0 = (((wk * 4 + 0 + (g >> 1)) ^ (c16 & 7)) << 4) | ((g & 1) << 3);
    const int vsw1 = (((wk * 4 + 2 + (g >> 1)) ^ (c16 & 7)) << 4) | ((g & 1) << 3);

    const char* Kh_g = (const char*)(Khi + (size_t)(b * 16 + h) * SKL * 64);
    const char* V_g  = (const char*)(VT + (size_t)(b * 16 + h) * 64 * SKL);

    s16x8 qh[2][2];
    const size_t qrowbase = (size_t)(b * 16 + h) * SQL + qbase;
#pragma unroll
    for (int qf = 0; qf < 2; ++qf) {
        size_t qo = (qrowbase + wq * 32 + qf * 16 + c16) * 64 + g * 8;
        qh[qf][0] = *(const s16x8*)&Qhi[qo];
        qh[qf][1] = *(const s16x8*)&Qhi[qo + 32];
    }

    stage8k(Kh_g, 128, lds, w, lane);
    stage8k(V_g, 4096, lds + 24576, w, lane);
    stage8k(Kh_g + 8192, 128, lds + 8192, w, lane);
    stage8k(V_g + 128, 4096, lds + 24576 + 8192, w, lane);

    f32x4 oacc[2][4];
#pragma unroll
    for (int qf = 0; qf < 2; ++qf)
#pragma unroll
        for (int i = 0; i < 4; ++i) oacc[qf][i] = (f32x4){0.f, 0.f, 0.f, 0.f};
    float lsum[2] = {0.f, 0.f};

    int cur = 0;
    for (int c = 0; c < 32; ++c) {
        if (c < 31) { asm volatile("s_waitcnt vmcnt(2)" ::: "memory"); }
        else        { asm volatile("s_waitcnt vmcnt(0)" ::: "memory"); }
        SBAR();
        if (c + 2 < 32) {
            int nb = cur + 2; if (nb >= 3) nb -= 3;
            stage8k(Kh_g + (size_t)(c + 2) * 8192, 128, lds + nb * 8192, w, lane);
            stage8k(V_g + (size_t)(c + 2) * 128, 4096, lds + 24576 + nb * 8192, w, lane);
        }
        char* curK = lds + cur * 8192;
        char* curV = lds + 24576 + cur * 8192;
#pragma unroll
        for (int kf = 0; kf < 2; ++kf) {
            int kb = (wk * 32 + kf * 16 + c16) * 128 + kswz;
            s16x8 kh0 = *(const s16x8*)(curK + kb);
            s16x8 kh1 = *(const s16x8*)(curK + (kb ^ 64));
            s16x4 pb[2];
#pragma unroll
            for (int qf = 0; qf < 2; ++qf) {
                f32x4 s = {0.f, 0.f, 0.f, 0.f};
                s = mfma16(kh0, qh[qf][0], s);
                s = mfma16(kh1, qh[qf][1], s);
                float e0 = exp2f(s[0] * PSC);
                float e1 = exp2f(s[1] * PSC);
                float e2 = exp2f(s[2] * PSC);
                float e3 = exp2f(s[3] * PSC);
                lsum[qf] += (e0 + e1) + (e2 + e3);
                pb[qf][0] = (short)f2bf(e0); pb[qf][1] = (short)f2bf(e1);
                pb[qf][2] = (short)f2bf(e2); pb[qf][3] = (short)f2bf(e3);
            }
            int vs = kf ? vsw1 : vsw0;
#pragma unroll
            for (int df = 0; df < 4; ++df) {
                s16x4 vf = *(const s16x4*)(curV + (df * 16 + c16) * 128 + vs);
                oacc[0][df] = mfma16k16(vf, pb[0], oacc[0][df]);
                oacc[1][df] = mfma16k16(vf, pb[1], oacc[1][df]);
            }
        }
        ++cur; if (cur == 3) cur = 0;
    }

#pragma unroll
    for (int qf = 0; qf < 2; ++qf) {
        lsum[qf] += __shfl_xor(lsum[qf], 16, 64);
        lsum[qf] += __shfl_xor(lsum[qf], 32, 64);
    }
    __syncthreads();
#pragma unroll
    for (int qf = 0; qf < 2; ++qf)
        if (g == 0) sL2[wk * 128 + wq * 32 + qf * 16 + c16] = lsum[qf];

#pragma unroll
    for (int half = 0; half < 2; ++half) {
        if (half) __syncthreads();
        if ((wq >> 1) == half) {
            int qlocal = (wq & 1) * 32 + c16;
#pragma unroll
            for (int qf = 0; qf < 2; ++qf)
#pragma unroll
                for (int df = 0; df < 4; ++df)
#pragma unroll
                    for (int r = 0; r < 4; ++r)
                        sOf[wk * 4352 + (df * 16 + g * 4 + r) * 68 + qlocal + qf * 16] =
                            oacc[qf][df][r];
        }
        __syncthreads();
        {
            int q = t >> 3, dg = t & 7;
            float l = sL2[half * 64 + q] + sL2[128 + half * 64 + q];
            float linv = 1.f / l;
            u16x8 ov;
#pragma unroll
            for (int i = 0; i < 8; ++i) {
                int d = dg * 8 + i;
                ov[i] = f2bf((sOf[d * 68 + q] + sOf[4352 + d * 68 + q]) * linv);
            }
            *(u16x8*)&Att[(size_t)(b * SQL + qbase + half * 64 + q) * EMBED + h * 64 + dg * 8] = ov;
            if (dg == 0)
                llog[(size_t)(b * 16 + h) * SQL + qbase + half * 64 + q] = log2f(l);
        }
    }
}

// ---------------------------------------------------------------------------
// Pass 2: mean_attn (unchanged from r11).
// ---------------------------------------------------------------------------
__global__ __launch_bounds__(512, 4)
void attn_mean(const u16* __restrict__ Qhi, const u16* __restrict__ Khi,
               const float* __restrict__ llog, float* __restrict__ meanOut) {
    __shared__ char lds[81920];   // Q dbuf 2x16K @0; K tbuf 3x16K @32768

    const int t = threadIdx.x;
    const int w = t >> 6, lane = t & 63;
    const int g = lane >> 4, c16 = lane & 15;
    const int qt = blockIdx.x >> 6;
    const int low = blockIdx.x & 63;
    const int b = low >> 4, ks = low & 15;
    const int qbase = qt * 128;
    const int kbase = ks * 128;
    const int wq = w >> 1, wk = w & 1;
    const int kswz = (g ^ (c16 & 7)) << 4;

    const size_t QH_STRIDE = (size_t)SQL * 128;
    const size_t KH_STRIDE = (size_t)SKL * 128;
    const char* Qh_b = (const char*)(Qhi + ((size_t)(b * 16) * SQL + qbase) * 64);
    const char* Kh_b = (const char*)(Khi + ((size_t)(b * 16) * SKL + kbase) * 64);
    const float* ll_b = llog + (size_t)(b * 16) * SQL + qbase;

    f32x4 ma[2][4];
#pragma unroll
    for (int qf = 0; qf < 2; ++qf)
#pragma unroll
        for (int i = 0; i < 4; ++i) ma[qf][i] = (f32x4){0.f, 0.f, 0.f, 0.f};

    stage8k(Qh_b, 128, lds, w, lane);
    stage8k(Qh_b + 8192, 128, lds + 8192, w, lane);
    float lbA0 = ll_b[wq * 32 + c16];
    float lbA1 = ll_b[wq * 32 + 16 + c16];
    stage8k(Kh_b, 128, lds + 32768, w, lane);
    stage8k(Kh_b + 8192, 128, lds + 32768 + 8192, w, lane);
    stage8k(Qh_b + QH_STRIDE, 128, lds + 16384, w, lane);
    stage8k(Qh_b + QH_STRIDE + 8192, 128, lds + 16384 + 8192, w, lane);
    float lbB0 = ll_b[SQL + wq * 32 + c16];
    float lbB1 = ll_b[SQL + wq * 32 + 16 + c16];
    stage8k(Kh_b + KH_STRIDE, 128, lds + 32768 + 16384, w, lane);
    stage8k(Kh_b + KH_STRIDE + 8192, 128, lds + 32768 + 16384 + 8192, w, lane);

    int curK = 0;
    for (int h = 0; h < 16; ++h) {
        if (h < 15) { asm volatile("s_waitcnt vmcnt(4)" ::: "memory"); }
        else        { asm volatile("s_waitcnt vmcnt(0)" ::: "memory"); }
        SBAR();

        const char* sQ = lds + (h & 1) * 16384;
        s16x8 qa0, qa1, qc0, qc1;
        {
            int qb0 = (wq * 32 + c16) * 128 + kswz;
            qa0 = *(const s16x8*)(sQ + qb0);
            qa1 = *(const s16x8*)(sQ + (qb0 ^ 64));
            int qb1 = (wq * 32 + 16 + c16) * 128 + kswz;
            qc0 = *(const s16x8*)(sQ + qb1);
            qc1 = *(const s16x8*)(sQ + (qb1 ^ 64));
        }
        asm volatile("s_waitcnt lgkmcnt(0)" ::: "memory");
        SBAR();

        float lb0 = lbA0, lb1 = lbA1;
        lbA0 = lbB0; lbA1 = lbB1;

        if (h + 2 < 16) {
            const char* Qg = Qh_b + (size_t)(h + 2) * QH_STRIDE;
            char* qdst = lds + (h & 1) * 16384;
            stage8k(Qg, 128, qdst, w, lane);
            stage8k(Qg + 8192, 128, qdst + 8192, w, lane);
            lbB0 = ll_b[(size_t)(h + 2) * SQL + wq * 32 + c16];
            lbB1 = ll_b[(size_t)(h + 2) * SQL + wq * 32 + 16 + c16];
            const char* Kg = Kh_b + (size_t)(h + 2) * KH_STRIDE;
            int nb = curK + 2; if (nb >= 3) nb -= 3;
            char* kdst = lds + 32768 + nb * 16384;
            stage8k(Kg, 128, kdst, w, lane);
            stage8k(Kg + 8192, 128, kdst + 8192, w, lane);
        }

        const char* sK = lds + 32768 + curK * 16384;
#pragma unroll
        for (int kf = 0; kf < 4; ++kf) {
            int kb = (kf * 32 + wk * 16 + c16) * 128 + kswz;
            s16x8 kh0 = *(const s16x8*)(sK + kb);
            s16x8 kh1 = *(const s16x8*)(sK + (kb ^ 64));
            {
                f32x4 s = {0.f, 0.f, 0.f, 0.f};
                s = mfma16(kh0, qa0, s);
                s = mfma16(kh1, qa1, s);
                ma[0][kf][0] += exp2f(s[0] * PSC - lb0);
                ma[0][kf][1] += exp2f(s[1] * PSC - lb0);
                ma[0][kf][2] += exp2f(s[2] * PSC - lb0);
                ma[0][kf][3] += exp2f(s[3] * PSC - lb0);
            }
            {
                f32x4 s = {0.f, 0.f, 0.f, 0.f};
                s = mfma16(kh0, qc0, s);
                s = mfma16(kh1, qc1, s);
                ma[1][kf][0] += exp2f(s[0] * PSC - lb1);
                ma[1][kf][1] += exp2f(s[1] * PSC - lb1);
                ma[1][kf][2] += exp2f(s[2] * PSC - lb1);
                ma[1][kf][3] += exp2f(s[3] * PSC - lb1);
            }
        }
        ++curK; if (curK == 3) curK = 0;
    }

    const float s16c = 1.f / 16.f;
#pragma unroll
    for (int qf = 0; qf < 2; ++qf)
#pragma unroll
        for (int kf = 0; kf < 4; ++kf) {
            f32x4 m = ma[qf][kf];
            m[0] *= s16c; m[1] *= s16c; m[2] *= s16c; m[3] *= s16c;
            *(f32x4*)&meanOut[(size_t)(b * SQL + qbase + wq * 32 + qf * 16 + c16) * SKL +
                              kbase + kf * 32 + wk * 16 + g * 4] = m;
        }
}

// ---------------------------------------------------------------------------
extern "C" void kernel_launch(void* const* d_in, const int* in_sizes, int n_in,
                              void* d_out, int out_size, void* d_ws, size_t ws_size,
                              hipStream_t stream) {
    const float* query = (const float*)d_in[0];
    const float* key   = (const float*)d_in[1];
    const float* value = (const float*)d_in[2];
    const float* Wq = (const float*)d_in[3];
    const float* bq = (const float*)d_in[4];
    const float* Wk = (const float*)d_in[5];
    const float* bk = (const float*)d_in[6];
    const float* Wv = (const float*)d_in[7];
    const float* bv = (const float*)d_in[8];
    const float* Wo = (const float*)d_in[9];
    const float* bo = (const float*)d_in[10];

    float* out = (float*)d_out;                         // [4,1024,1024] f32
    float* meanOut = out + (size_t)BATCH * SQL * EMBED; // [4,1024,2048] f32

    u16* Qhi = (u16*)d_ws;                              // head-major [b][h][q][64]
    u16* Khi = Qhi + (size_t)4096 * 1024;               // [b][h][k][64]
    u16* VTh = Khi + (size_t)8192 * 1024;               // [b][h][d][2048]
    u16* Att = VTh + (size_t)8192 * 1024;               // [4096][1024] bf16
    float* llog = (float*)(Att + (size_t)4096 * 1024);  // [b*16+h][q]
    u16* Wqh = (u16*)(llog + 64 * 1024);                // [1024][1024] bf16 planes
    u16* Wql = Wqh + (size_t)1024 * 1024;
    u16* Wkh = Wql + (size_t)1024 * 1024;
    u16* Wkl = Wkh + (size_t)1024 * 1024;

    split_w<<<dim3(1024), 256, 0, stream>>>(Wq, Wk, Wqh, Wql, Wkh, Wkl);

    gemm_mfma<0, 0, 1, 5><<<dim3(8, 32), 256, 0, stream>>>(
        query, nullptr, Wqh, Wql, bq, Qhi, nullptr, 4096, 1024, 10);
    gemm_mfma<0, 0, 1, 5><<<dim3(8, 64), 256, 0, stream>>>(
        key, nullptr, Wkh, Wkl, bk, Khi, nullptr, 8192, 1024, 11);
    gemm_mfma<0, 0, 0, 4><<<dim3(64, 8), 256, 0, stream>>>(
        Wv, value, nullptr, nullptr, bv, VTh, nullptr, 1024, 8192, 0);

    attn_O<<<dim3(512), dim3(512), 0, stream>>>(Qhi, Khi, VTh, Att, llog);
    attn_mean<<<dim3(512), dim3(512), 0, stream>>>(Qhi, Khi, llog, meanOut);

    gemm_mfma<0, 1, 0, 0><<<dim3(8, 32), 256, 0, stream>>>(
        Att, Wo, nullptr, nullptr, bo, out, nullptr, 4096, 1024, 0);
}

// Round 13
// 245.406 us; speedup vs baseline: 3.1174x; 1.0479x over previous
//
#include <hip/hip_runtime.h>
#include <hip/hip_bf16.h>
#include <math.h>

#define EMBED 1024
#define NHEADS 16
#define HDIM 64
#define BATCH 4
#define SQL 1024
#define SKL 2048
#define PSC 0.18033688f   // 0.125 * log2(e)

typedef unsigned short u16;
typedef __attribute__((ext_vector_type(4))) float f32x4;
typedef __attribute__((ext_vector_type(8))) __bf16 bf16x8;
typedef __attribute__((ext_vector_type(8))) short s16x8;
typedef __attribute__((ext_vector_type(4))) short s16x4;
typedef __attribute__((ext_vector_type(8))) u16 u16x8;

__device__ __forceinline__ u16 f2bf(float x) {
    __hip_bfloat16 h = __float2bfloat16(x);
    return *reinterpret_cast<u16*>(&h);
}
__device__ __forceinline__ float bf2f(u16 u) {
    __hip_bfloat16 h;
    *reinterpret_cast<u16*>(&h) = u;
    return __bfloat162float(h);
}
__device__ __forceinline__ f32x4 mfma16(s16x8 a, s16x8 b, f32x4 c) {
    return __builtin_amdgcn_mfma_f32_16x16x32_bf16(
        __builtin_bit_cast(bf16x8, a), __builtin_bit_cast(bf16x8, b), c, 0, 0, 0);
}
__device__ __forceinline__ f32x4 mfma16k16(s16x4 a, s16x4 b, f32x4 c) {
    return __builtin_amdgcn_mfma_f32_16x16x16bf16_1k(a, b, c, 0, 0, 0);
}
__device__ __forceinline__ void gload16(const void* g, void* l) {
    __builtin_amdgcn_global_load_lds(
        (const __attribute__((address_space(1))) void*)g,
        (__attribute__((address_space(3))) void*)l, 16, 0, 0);
}
// Stage one 8KB plane (64 rows x 128B) with XOR-preswizzled source.
__device__ __forceinline__ void stage8k(const char* g, size_t rstrideB,
                                        char* ldsPlane, int w, int lane) {
    int r = w * 8 + (lane >> 3);
    int cs = (lane & 7) ^ (r & 7);
    gload16(g + (size_t)r * rstrideB + cs * 16, ldsPlane + (size_t)w * 1024);
}
#define SBAR() { __builtin_amdgcn_sched_barrier(0); \
    __builtin_amdgcn_s_barrier(); __builtin_amdgcn_sched_barrier(0); }

// ---------------------------------------------------------------------------
// split_w4: Wq,Wk -> bf16 hi+lo planes (lo at +1M); Wv,Wo -> bf16 hi only.
// ---------------------------------------------------------------------------
__global__ __launch_bounds__(256)
void split_w4(const float* __restrict__ Wq, const float* __restrict__ Wk,
              const float* __restrict__ Wv, const float* __restrict__ Wo,
              u16* __restrict__ Wqh, u16* __restrict__ Wkh,
              u16* __restrict__ Wvh, u16* __restrict__ Woh) {
    int bid = blockIdx.x;
    const float* src; u16* dh; u16* dl = nullptr;
    if (bid < 512)       { src = Wq; dh = Wqh; dl = Wqh + 1048576; }
    else if (bid < 1024) { bid -= 512;  src = Wk; dh = Wkh; dl = Wkh + 1048576; }
    else if (bid < 1536) { bid -= 1024; src = Wv; dh = Wvh; }
    else                 { bid -= 1536; src = Wo; dh = Woh; }
    size_t i = ((size_t)bid * 256 + threadIdx.x) * 8;
    float4 a = *(const float4*)&src[i];
    float4 b = *(const float4*)&src[i + 4];
    float v[8] = {a.x, a.y, a.z, a.w, b.x, b.y, b.z, b.w};
    u16x8 hi;
#pragma unroll
    for (int j = 0; j < 8; ++j) hi[j] = f2bf(v[j]);
    *(u16x8*)&dh[i] = hi;
    if (dl) {
        u16x8 lo;
#pragma unroll
        for (int j = 0; j < 8; ++j) lo[j] = f2bf(v[j] - bf2f(hi[j]));
        *(u16x8*)&dl[i] = lo;
    }
}

// ---------------------------------------------------------------------------
// GEMM NT: Y = A * W^T + bias. K=1024. 128x128 tile, 2-DEEP register
// prefetch (two named load sets; each set's ds_write waits -- via compiler-
// counted vmcnt -- only for loads issued 1.5 iterations earlier).
// AMODE: 0 = A f32 (cvt hi at write), 1 = A bf16 direct.
// WMODE: 0 = W f32 (cvt hi), 1 = W bf16 hi, 2 = W pre-split hi+lo (2 MFMA).
// OUT_MODE 0: f32 + bias[col]. 4: bf16 V^T head-major (+bias[row]).
// 5: bf16 head-major [b][h][s][64] (+bias[col]).
// ---------------------------------------------------------------------------
#define GEMM_LOAD(S, kk) { \
    if constexpr (AMODE == 0) { \
        _Pragma("unroll") for (int j = 0; j < 4; ++j) \
            *(float4*)&ax##S[j * 4] = *(const float4*)&Af[(size_t)(rowBase + srow) * 1024 + (kk) + sc + j * 4]; \
    } else { \
        au##S##0 = *(const u16x8*)&Au[(size_t)(rowBase + srow) * 1024 + (kk) + sc]; \
        au##S##1 = *(const u16x8*)&Au[(size_t)(rowBase + srow) * 1024 + (kk) + sc + 8]; \
    } \
    if constexpr (WMODE == 0) { \
        _Pragma("unroll") for (int j = 0; j < 4; ++j) \
            *(float4*)&bx##S[j * 4] = *(const float4*)&Wf[(size_t)(colBase + srow) * 1024 + (kk) + sc + j * 4]; \
    } else { \
        wh##S##0 = *(const u16x8*)&Wu[(size_t)(colBase + srow) * 1024 + (kk) + sc]; \
        wh##S##1 = *(const u16x8*)&Wu[(size_t)(colBase + srow) * 1024 + (kk) + sc + 8]; \
        if constexpr (WMODE == 2) { \
            wl##S##0 = *(const u16x8*)&Wu[1048576 + (size_t)(colBase + srow) * 1024 + (kk) + sc]; \
            wl##S##1 = *(const u16x8*)&Wu[1048576 + (size_t)(colBase + srow) * 1024 + (kk) + sc + 8]; \
        } \
    } }

#define GEMM_WRITE(S) { \
    u16x8 h0, h1; \
    if constexpr (AMODE == 0) { \
        _Pragma("unroll") for (int j = 0; j < 8; ++j) { \
            h0[j] = f2bf(ax##S[j]); h1[j] = f2bf(ax##S[j + 8]); } \
    } else { h0 = au##S##0; h1 = au##S##1; } \
    *(u16x8*)&sA[srow * 40 + sc] = h0; \
    *(u16x8*)&sA[srow * 40 + sc + 8] = h1; \
    u16x8 b0, b1; \
    if constexpr (WMODE == 0) { \
        _Pragma("unroll") for (int j = 0; j < 8; ++j) { \
            b0[j] = f2bf(bx##S[j]); b1[j] = f2bf(bx##S[j + 8]); } \
    } else { b0 = wh##S##0; b1 = wh##S##1; } \
    *(u16x8*)&sB[0][srow * 40 + sc] = b0; \
    *(u16x8*)&sB[0][srow * 40 + sc + 8] = b1; \
    if constexpr (WMODE == 2) { \
        *(u16x8*)&sB[1][srow * 40 + sc] = wl##S##0; \
        *(u16x8*)&sB[1][srow * 40 + sc + 8] = wl##S##1; \
    } }

#define GEMM_COMPUTE() { \
    s16x8 afh[4], bfh[4], bfl[4]; \
    _Pragma("unroll") for (int mi = 0; mi < 4; ++mi) { \
        int ai = (wm * 64 + mi * 16 + (lane & 15)) * 40 + (lane >> 4) * 8; \
        afh[mi] = *(const s16x8*)&sA[ai]; \
    } \
    _Pragma("unroll") for (int ni = 0; ni < 4; ++ni) { \
        int bi = (wn * 64 + ni * 16 + (lane & 15)) * 40 + (lane >> 4) * 8; \
        bfh[ni] = *(const s16x8*)&sB[0][bi]; \
        if constexpr (WMODE == 2) bfl[ni] = *(const s16x8*)&sB[1][bi]; \
    } \
    _Pragma("unroll") for (int mi = 0; mi < 4; ++mi) \
        _Pragma("unroll") for (int ni = 0; ni < 4; ++ni) { \
            acc[mi][ni] = mfma16(afh[mi], bfh[ni], acc[mi][ni]); \
            if constexpr (WMODE == 2) \
                acc[mi][ni] = mfma16(afh[mi], bfl[ni], acc[mi][ni]); \
        } }

template<int AMODE, int WMODE, int OUT_MODE>
__global__ __launch_bounds__(256)
void gemm_mfma(const void* __restrict__ Ap, const void* __restrict__ Wop,
               const float* __restrict__ bias, void* __restrict__ Y0p,
               int M, int N, int bshift) {
    __shared__ u16 sA[128 * 40];
    __shared__ u16 sB[2][128 * 40];

    const int t = threadIdx.x;
    const int lane = t & 63;
    const int w = t >> 6;
    const int wm = w >> 1, wn = w & 1;
    const int rowBase = blockIdx.y * 128;
    const int colBase = blockIdx.x * 128;
    const int srow = t >> 1;
    const int sc = (t & 1) * 16;

    const float* Af = (const float*)Ap;
    const u16* Au = (const u16*)Ap;
    const float* Wf = (const float*)Wop;
    const u16* Wu = (const u16*)Wop;

    f32x4 acc[4][4];
#pragma unroll
    for (int i = 0; i < 4; ++i)
#pragma unroll
        for (int j = 0; j < 4; ++j) acc[i][j] = (f32x4){0.f, 0.f, 0.f, 0.f};

    float ax0[16], ax1[16], bx0[16], bx1[16];
    u16x8 au00, au01, au10, au11;
    u16x8 wh00, wh01, wl00, wl01, wh10, wh11, wl10, wl11;

    GEMM_LOAD(0, 0)
    GEMM_LOAD(1, 32)

    for (int k0 = 0; k0 < 1024; k0 += 64) {
        __syncthreads();
        GEMM_WRITE(0)
        __syncthreads();
        if (k0 + 64 < 1024) GEMM_LOAD(0, k0 + 64)
        GEMM_COMPUTE()
        __syncthreads();
        GEMM_WRITE(1)
        __syncthreads();
        if (k0 + 96 < 1024) GEMM_LOAD(1, k0 + 96)
        GEMM_COMPUTE()
    }

#pragma unroll
    for (int mi = 0; mi < 4; ++mi)
#pragma unroll
        for (int ni = 0; ni < 4; ++ni)
#pragma unroll
            for (int rr = 0; rr < 4; ++rr) {
                int mg = rowBase + wm * 64 + mi * 16 + (lane >> 4) * 4 + rr;
                int ng = colBase + wn * 64 + ni * 16 + (lane & 15);
                float y = acc[mi][ni][rr];
                if constexpr (OUT_MODE == 0) {
                    ((float*)Y0p)[(size_t)mg * N + ng] = y + bias[ng];
                } else if constexpr (OUT_MODE == 4) {
                    y += bias[mg];
                    size_t idx = ((size_t)((ng >> 11) * 16 + (mg >> 6)) * 64 + (mg & 63)) * 2048 + (ng & 2047);
                    ((u16*)Y0p)[idx] = f2bf(y);
                } else if constexpr (OUT_MODE == 5) {
                    y += bias[ng];
                    int bb = mg >> bshift, s = mg & ((1 << bshift) - 1);
                    size_t idx = ((((size_t)(bb * 16 + (ng >> 6))) << bshift) + s) * 64 + (ng & 63);
                    ((u16*)Y0p)[idx] = f2bf(y);
                }
            }
}

// ---------------------------------------------------------------------------
// Pass 1: attended output + denominators (unchanged from r12).
// ---------------------------------------------------------------------------
__global__ __launch_bounds__(512, 4)
void attn_O(const u16* __restrict__ Qhi, const u16* __restrict__ Khi,
            const u16* __restrict__ VT, u16* __restrict__ Att,
            float* __restrict__ llog) {
    __shared__ char lds[49152];
    float* sOf = (float*)lds;
    float* sL2 = (float*)(lds + 35840);

    const int t = threadIdx.x;
    const int w = t >> 6, lane = t & 63;
    const int g = lane >> 4, c16 = lane & 15;
    const int qt = blockIdx.x >> 6;
    const int g6 = blockIdx.x & 63;
    const int b = g6 >> 4, h = g6 & 15;
    const int qbase = qt * 128;
    const int wq = w >> 1, wk = w & 1;
    const int kswz = (g ^ (c16 & 7)) << 4;
    const int vsw0 = (((wk * 4 + 0 + (g >> 1)) ^ (c16 & 7)) << 4) | ((g & 1) << 3);
    const int vsw1 = (((wk * 4 + 2 + (g >> 1)) ^ (c16 & 7)) << 4) | ((g & 1) << 3);

    const char* Kh_g = (const char*)(Khi + (size_t)(b * 16 + h) * SKL * 64);
    const char* V_g  = (const char*)(VT + (size_t)(b * 16 + h) * 64 * SKL);

    s16x8 qh[2][2];
    const size_t qrowbase = (size_t)(b * 16 + h) * SQL + qbase;
#pragma unroll
    for (int qf = 0; qf < 2; ++qf) {
        size_t qo = (qrowbase + wq * 32 + qf * 16 + c16) * 64 + g * 8;
        qh[qf][0] = *(const s16x8*)&Qhi[qo];
        qh[qf][1] = *(const s16x8*)&Qhi[qo + 32];
    }

    stage8k(Kh_g, 128, lds, w, lane);
    stage8k(V_g, 4096, lds + 24576, w, lane);
    stage8k(Kh_g + 8192, 128, lds + 8192, w, lane);
    stage8k(V_g + 128, 4096, lds + 24576 + 8192, w, lane);

    f32x4 oacc[2][4];
#pragma unroll
    for (int qf = 0; qf < 2; ++qf)
#pragma unroll
        for (int i = 0; i < 4; ++i) oacc[qf][i] = (f32x4){0.f, 0.f, 0.f, 0.f};
    float lsum[2] = {0.f, 0.f};

    int cur = 0;
    for (int c = 0; c < 32; ++c) {
        if (c < 31) { asm volatile("s_waitcnt vmcnt(2)" ::: "memory"); }
        else        { asm volatile("s_waitcnt vmcnt(0)" ::: "memory"); }
        SBAR();
        if (c + 2 < 32) {
            int nb = cur + 2; if (nb >= 3) nb -= 3;
            stage8k(Kh_g + (size_t)(c + 2) * 8192, 128, lds + nb * 8192, w, lane);
            stage8k(V_g + (size_t)(c + 2) * 128, 4096, lds + 24576 + nb * 8192, w, lane);
        }
        char* curK = lds + cur * 8192;
        char* curV = lds + 24576 + cur * 8192;
#pragma unroll
        for (int kf = 0; kf < 2; ++kf) {
            int kb = (wk * 32 + kf * 16 + c16) * 128 + kswz;
            s16x8 kh0 = *(const s16x8*)(curK + kb);
            s16x8 kh1 = *(const s16x8*)(curK + (kb ^ 64));
            s16x4 pb[2];
#pragma unroll
            for (int qf = 0; qf < 2; ++qf) {
                f32x4 s = {0.f, 0.f, 0.f, 0.f};
                s = mfma16(kh0, qh[qf][0], s);
                s = mfma16(kh1, qh[qf][1], s);
                float e0 = exp2f(s[0] * PSC);
                float e1 = exp2f(s[1] * PSC);
                float e2 = exp2f(s[2] * PSC);
                float e3 = exp2f(s[3] * PSC);
                lsum[qf] += (e0 + e1) + (e2 + e3);
                pb[qf][0] = (short)f2bf(e0); pb[qf][1] = (short)f2bf(e1);
                pb[qf][2] = (short)f2bf(e2); pb[qf][3] = (short)f2bf(e3);
            }
            int vs = kf ? vsw1 : vsw0;
#pragma unroll
            for (int df = 0; df < 4; ++df) {
                s16x4 vf = *(const s16x4*)(curV + (df * 16 + c16) * 128 + vs);
                oacc[0][df] = mfma16k16(vf, pb[0], oacc[0][df]);
                oacc[1][df] = mfma16k16(vf, pb[1], oacc[1][df]);
            }
        }
        ++cur; if (cur == 3) cur = 0;
    }

#pragma unroll
    for (int qf = 0; qf < 2; ++qf) {
        lsum[qf] += __shfl_xor(lsum[qf], 16, 64);
        lsum[qf] += __shfl_xor(lsum[qf], 32, 64);
    }
    __syncthreads();
#pragma unroll
    for (int qf = 0; qf < 2; ++qf)
        if (g == 0) sL2[wk * 128 + wq * 32 + qf * 16 + c16] = lsum[qf];

#pragma unroll
    for (int half = 0; half < 2; ++half) {
        if (half) __syncthreads();
        if ((wq >> 1) == half) {
            int qlocal = (wq & 1) * 32 + c16;
#pragma unroll
            for (int qf = 0; qf < 2; ++qf)
#pragma unroll
                for (int df = 0; df < 4; ++df)
#pragma unroll
                    for (int r = 0; r < 4; ++r)
                        sOf[wk * 4352 + (df * 16 + g * 4 + r) * 68 + qlocal + qf * 16] =
                            oacc[qf][df][r];
        }
        __syncthreads();
        {
            int q = t >> 3, dg = t & 7;
            float l = sL2[half * 64 + q] + sL2[128 + half * 64 + q];
            float linv = 1.f / l;
            u16x8 ov;
#pragma unroll
            for (int i = 0; i < 8; ++i) {
                int d = dg * 8 + i;
                ov[i] = f2bf((sOf[d * 68 + q] + sOf[4352 + d * 68 + q]) * linv);
            }
            *(u16x8*)&Att[(size_t)(b * SQL + qbase + half * 64 + q) * EMBED + h * 64 + dg * 8] = ov;
            if (dg == 0)
                llog[(size_t)(b * 16 + h) * SQL + qbase + half * 64 + q] = log2f(l);
        }
    }
}

// ---------------------------------------------------------------------------
// Pass 2: mean_attn (unchanged from r12).
// ---------------------------------------------------------------------------
__global__ __launch_bounds__(512, 4)
void attn_mean(const u16* __restrict__ Qhi, const u16* __restrict__ Khi,
               const float* __restrict__ llog, float* __restrict__ meanOut) {
    __shared__ char lds[81920];   // Q dbuf 2x16K @0; K tbuf 3x16K @32768

    const int t = threadIdx.x;
    const int w = t >> 6, lane = t & 63;
    const int g = lane >> 4, c16 = lane & 15;
    const int qt = blockIdx.x >> 6;
    const int low = blockIdx.x & 63;
    const int b = low >> 4, ks = low & 15;
    const int qbase = qt * 128;
    const int kbase = ks * 128;
    const int wq = w >> 1, wk = w & 1;
    const int kswz = (g ^ (c16 & 7)) << 4;

    const size_t QH_STRIDE = (size_t)SQL * 128;
    const size_t KH_STRIDE = (size_t)SKL * 128;
    const char* Qh_b = (const char*)(Qhi + ((size_t)(b * 16) * SQL + qbase) * 64);
    const char* Kh_b = (const char*)(Khi + ((size_t)(b * 16) * SKL + kbase) * 64);
    const float* ll_b = llog + (size_t)(b * 16) * SQL + qbase;

    f32x4 ma[2][4];
#pragma unroll
    for (int qf = 0; qf < 2; ++qf)
#pragma unroll
        for (int i = 0; i < 4; ++i) ma[qf][i] = (f32x4){0.f, 0.f, 0.f, 0.f};

    stage8k(Qh_b, 128, lds, w, lane);
    stage8k(Qh_b + 8192, 128, lds + 8192, w, lane);
    float lbA0 = ll_b[wq * 32 + c16];
    float lbA1 = ll_b[wq * 32 + 16 + c16];
    stage8k(Kh_b, 128, lds + 32768, w, lane);
    stage8k(Kh_b + 8192, 128, lds + 32768 + 8192, w, lane);
    stage8k(Qh_b + QH_STRIDE, 128, lds + 16384, w, lane);
    stage8k(Qh_b + QH_STRIDE + 8192, 128, lds + 16384 + 8192, w, lane);
    float lbB0 = ll_b[SQL + wq * 32 + c16];
    float lbB1 = ll_b[SQL + wq * 32 + 16 + c16];
    stage8k(Kh_b + KH_STRIDE, 128, lds + 32768 + 16384, w, lane);
    stage8k(Kh_b + KH_STRIDE + 8192, 128, lds + 32768 + 16384 + 8192, w, lane);

    int curK = 0;
    for (int h = 0; h < 16; ++h) {
        if (h < 15) { asm volatile("s_waitcnt vmcnt(4)" ::: "memory"); }
        else        { asm volatile("s_waitcnt vmcnt(0)" ::: "memory"); }
        SBAR();

        const char* sQ = lds + (h & 1) * 16384;
        s16x8 qa0, qa1, qc0, qc1;
        {
            int qb0 = (wq * 32 + c16) * 128 + kswz;
            qa0 = *(const s16x8*)(sQ + qb0);
            qa1 = *(const s16x8*)(sQ + (qb0 ^ 64));
            int qb1 = (wq * 32 + 16 + c16) * 128 + kswz;
            qc0 = *(const s16x8*)(sQ + qb1);
            qc1 = *(const s16x8*)(sQ + (qb1 ^ 64));
        }
        asm volatile("s_waitcnt lgkmcnt(0)" ::: "memory");
        SBAR();

        float lb0 = lbA0, lb1 = lbA1;
        lbA0 = lbB0; lbA1 = lbB1;

        if (h + 2 < 16) {
            const char* Qg = Qh_b + (size_t)(h + 2) * QH_STRIDE;
            char* qdst = lds + (h & 1) * 16384;
            stage8k(Qg, 128, qdst, w, lane);
            stage8k(Qg + 8192, 128, qdst + 8192, w, lane);
            lbB0 = ll_b[(size_t)(h + 2) * SQL + wq * 32 + c16];
            lbB1 = ll_b[(size_t)(h + 2) * SQL + wq * 32 + 16 + c16];
            const char* Kg = Kh_b + (size_t)(h + 2) * KH_STRIDE;
            int nb = curK + 2; if (nb >= 3) nb -= 3;
            char* kdst = lds + 32768 + nb * 16384;
            stage8k(Kg, 128, kdst, w, lane);
            stage8k(Kg + 8192, 128, kdst + 8192, w, lane);
        }

        const char* sK = lds + 32768 + curK * 16384;
#pragma unroll
        for (int kf = 0; kf < 4; ++kf) {
            int kb = (kf * 32 + wk * 16 + c16) * 128 + kswz;
            s16x8 kh0 = *(const s16x8*)(sK + kb);
            s16x8 kh1 = *(const s16x8*)(sK + (kb ^ 64));
            {
                f32x4 s = {0.f, 0.f, 0.f, 0.f};
                s = mfma16(kh0, qa0, s);
                s = mfma16(kh1, qa1, s);
                ma[0][kf][0] += exp2f(s[0] * PSC - lb0);
                ma[0][kf][1] += exp2f(s[1] * PSC - lb0);
                ma[0][kf][2] += exp2f(s[2] * PSC - lb0);
                ma[0][kf][3] += exp2f(s[3] * PSC - lb0);
            }
            {
                f32x4 s = {0.f, 0.f, 0.f, 0.f};
                s = mfma16(kh0, qc0, s);
                s = mfma16(kh1, qc1, s);
                ma[1][kf][0] += exp2f(s[0] * PSC - lb1);
                ma[1][kf][1] += exp2f(s[1] * PSC - lb1);
                ma[1][kf][2] += exp2f(s[2] * PSC - lb1);
                ma[1][kf][3] += exp2f(s[3] * PSC - lb1);
            }
        }
        ++curK; if (curK == 3) curK = 0;
    }

    const float s16c = 1.f / 16.f;
#pragma unroll
    for (int qf = 0; qf < 2; ++qf)
#pragma unroll
        for (int kf = 0; kf < 4; ++kf) {
            f32x4 m = ma[qf][kf];
            m[0] *= s16c; m[1] *= s16c; m[2] *= s16c; m[3] *= s16c;
            *(f32x4*)&meanOut[(size_t)(b * SQL + qbase + wq * 32 + qf * 16 + c16) * SKL +
                              kbase + kf * 32 + wk * 16 + g * 4] = m;
        }
}

// ---------------------------------------------------------------------------
extern "C" void kernel_launch(void* const* d_in, const int* in_sizes, int n_in,
                              void* d_out, int out_size, void* d_ws, size_t ws_size,
                              hipStream_t stream) {
    const float* query = (const float*)d_in[0];
    const float* key   = (const float*)d_in[1];
    const float* value = (const float*)d_in[2];
    const float* Wq = (const float*)d_in[3];
    const float* bq = (const float*)d_in[4];
    const float* Wk = (const float*)d_in[5];
    const float* bk = (const float*)d_in[6];
    const float* Wv = (const float*)d_in[7];
    const float* bv = (const float*)d_in[8];
    const float* Wo = (const float*)d_in[9];
    const float* bo = (const float*)d_in[10];

    float* out = (float*)d_out;                         // [4,1024,1024] f32
    float* meanOut = out + (size_t)BATCH * SQL * EMBED; // [4,1024,2048] f32

    u16* Qhi = (u16*)d_ws;                              // head-major [b][h][q][64]
    u16* Khi = Qhi + (size_t)4096 * 1024;               // [b][h][k][64]
    u16* VTh = Khi + (size_t)8192 * 1024;               // [b][h][d][2048]
    u16* Att = VTh + (size_t)8192 * 1024;               // [4096][1024] bf16
    float* llog = (float*)(Att + (size_t)4096 * 1024);  // [b*16+h][q]
    u16* Wqh = (u16*)(llog + 64 * 1024);                // hi+lo (lo at +1M)
    u16* Wkh = Wqh + (size_t)2 * 1024 * 1024;           // hi+lo
    u16* Wvh = Wkh + (size_t)2 * 1024 * 1024;           // hi only
    u16* Woh = Wvh + (size_t)1024 * 1024;               // hi only

    split_w4<<<dim3(2048), 256, 0, stream>>>(Wq, Wk, Wv, Wo, Wqh, Wkh, Wvh, Woh);

    gemm_mfma<0, 2, 5><<<dim3(8, 32), 256, 0, stream>>>(query, Wqh, bq, Qhi, 4096, 1024, 10);
    gemm_mfma<0, 2, 5><<<dim3(8, 64), 256, 0, stream>>>(key, Wkh, bk, Khi, 8192, 1024, 11);
    gemm_mfma<1, 0, 4><<<dim3(64, 8), 256, 0, stream>>>(Wvh, value, bv, VTh, 1024, 8192, 0);

    attn_O<<<dim3(512), dim3(512), 0, stream>>>(Qhi, Khi, VTh, Att, llog);
    attn_mean<<<dim3(512), dim3(512), 0, stream>>>(Qhi, Khi, llog, meanOut);

    gemm_mfma<1, 1, 0><<<dim3(8, 32), 256, 0, stream>>>(Att, Woh, bo, out, 4096, 1024, 0);
}

// Round 14
// 228.502 us; speedup vs baseline: 3.3480x; 1.0740x over previous
//
#include <hip/hip_runtime.h>
#include <hip/hip_bf16.h>
#include <math.h>

#define EMBED 1024
#define NHEADS 16
#define HDIM 64
#define BATCH 4
#define SQL 1024
#define SKL 2048
#define PSC 0.18033688f   // 0.125 * log2(e)  (folded into Q projection)

typedef unsigned short u16;
typedef __attribute__((ext_vector_type(4))) float f32x4;
typedef __attribute__((ext_vector_type(8))) __bf16 bf16x8;
typedef __attribute__((ext_vector_type(8))) short s16x8;
typedef __attribute__((ext_vector_type(4))) short s16x4;
typedef __attribute__((ext_vector_type(8))) u16 u16x8;

__device__ __forceinline__ u16 f2bf(float x) {
    __hip_bfloat16 h = __float2bfloat16(x);
    return *reinterpret_cast<u16*>(&h);
}
__device__ __forceinline__ float bf2f(u16 u) {
    __hip_bfloat16 h;
    *reinterpret_cast<u16*>(&h) = u;
    return __bfloat162float(h);
}
__device__ __forceinline__ f32x4 mfma16(s16x8 a, s16x8 b, f32x4 c) {
    return __builtin_amdgcn_mfma_f32_16x16x32_bf16(
        __builtin_bit_cast(bf16x8, a), __builtin_bit_cast(bf16x8, b), c, 0, 0, 0);
}
__device__ __forceinline__ f32x4 mfma16k16(s16x4 a, s16x4 b, f32x4 c) {
    return __builtin_amdgcn_mfma_f32_16x16x16bf16_1k(a, b, c, 0, 0, 0);
}
__device__ __forceinline__ void gload16(const void* g, void* l) {
    __builtin_amdgcn_global_load_lds(
        (const __attribute__((address_space(1))) void*)g,
        (__attribute__((address_space(3))) void*)l, 16, 0, 0);
}
// Stage one 8KB plane (64 rows x 128B) with XOR-preswizzled source.
__device__ __forceinline__ void stage8k(const char* g, size_t rstrideB,
                                        char* ldsPlane, int w, int lane) {
    int r = w * 8 + (lane >> 3);
    int cs = (lane & 7) ^ (r & 7);
    gload16(g + (size_t)r * rstrideB + cs * 16, ldsPlane + (size_t)w * 1024);
}
#define SBAR() { __builtin_amdgcn_sched_barrier(0); \
    __builtin_amdgcn_s_barrier(); __builtin_amdgcn_sched_barrier(0); }

// ---------------------------------------------------------------------------
// cvt_w: all four weight matrices f32 -> bf16 (hi only; no splits anymore).
// ---------------------------------------------------------------------------
__global__ __launch_bounds__(256)
void cvt_w(const float* __restrict__ Wq, const float* __restrict__ Wk,
           const float* __restrict__ Wv, const float* __restrict__ Wo,
           u16* __restrict__ Wqh, u16* __restrict__ Wkh,
           u16* __restrict__ Wvh, u16* __restrict__ Woh) {
    int bid = blockIdx.x;
    const float* src; u16* dh;
    if (bid < 512)       { src = Wq; dh = Wqh; }
    else if (bid < 1024) { bid -= 512;  src = Wk; dh = Wkh; }
    else if (bid < 1536) { bid -= 1024; src = Wv; dh = Wvh; }
    else                 { bid -= 1536; src = Wo; dh = Woh; }
    size_t i = ((size_t)bid * 256 + threadIdx.x) * 8;
    float4 a = *(const float4*)&src[i];
    float4 b = *(const float4*)&src[i + 4];
    float v[8] = {a.x, a.y, a.z, a.w, b.x, b.y, b.z, b.w};
    u16x8 hi;
#pragma unroll
    for (int j = 0; j < 8; ++j) hi[j] = f2bf(v[j]);
    *(u16x8*)&dh[i] = hi;
}

// ---------------------------------------------------------------------------
// GEMM NT: Y = A * W^T + bias. K=1024. 128x128 tile, 2-deep register
// prefetch. AMODE: 0 = A f32 (cvt at write), 1 = A bf16 direct.
// WMODE: 0 = W f32 (cvt), 1 = W bf16 direct.
// OUT_MODE 0: f32 + bias[col]. 4: bf16 V^T head-major (+bias[row]).
// 5: bf16 head-major (+bias[col]). 6: mode 5 scaled by PSC (Q projection).
// ---------------------------------------------------------------------------
#define GEMM_LOAD(S, kk) { \
    if constexpr (AMODE == 0) { \
        _Pragma("unroll") for (int j = 0; j < 4; ++j) \
            *(float4*)&ax##S[j * 4] = *(const float4*)&Af[(size_t)(rowBase + srow) * 1024 + (kk) + sc + j * 4]; \
    } else { \
        au##S##0 = *(const u16x8*)&Au[(size_t)(rowBase + srow) * 1024 + (kk) + sc]; \
        au##S##1 = *(const u16x8*)&Au[(size_t)(rowBase + srow) * 1024 + (kk) + sc + 8]; \
    } \
    if constexpr (WMODE == 0) { \
        _Pragma("unroll") for (int j = 0; j < 4; ++j) \
            *(float4*)&bx##S[j * 4] = *(const float4*)&Wf[(size_t)(colBase + srow) * 1024 + (kk) + sc + j * 4]; \
    } else { \
        wh##S##0 = *(const u16x8*)&Wu[(size_t)(colBase + srow) * 1024 + (kk) + sc]; \
        wh##S##1 = *(const u16x8*)&Wu[(size_t)(colBase + srow) * 1024 + (kk) + sc + 8]; \
    } }

#define GEMM_WRITE(S) { \
    u16x8 h0, h1; \
    if constexpr (AMODE == 0) { \
        _Pragma("unroll") for (int j = 0; j < 8; ++j) { \
            h0[j] = f2bf(ax##S[j]); h1[j] = f2bf(ax##S[j + 8]); } \
    } else { h0 = au##S##0; h1 = au##S##1; } \
    *(u16x8*)&sA[srow * 40 + sc] = h0; \
    *(u16x8*)&sA[srow * 40 + sc + 8] = h1; \
    u16x8 b0, b1; \
    if constexpr (WMODE == 0) { \
        _Pragma("unroll") for (int j = 0; j < 8; ++j) { \
            b0[j] = f2bf(bx##S[j]); b1[j] = f2bf(bx##S[j + 8]); } \
    } else { b0 = wh##S##0; b1 = wh##S##1; } \
    *(u16x8*)&sB[srow * 40 + sc] = b0; \
    *(u16x8*)&sB[srow * 40 + sc + 8] = b1; }

#define GEMM_COMPUTE() { \
    s16x8 afh[4], bfh[4]; \
    _Pragma("unroll") for (int mi = 0; mi < 4; ++mi) { \
        int ai = (wm * 64 + mi * 16 + (lane & 15)) * 40 + (lane >> 4) * 8; \
        afh[mi] = *(const s16x8*)&sA[ai]; \
    } \
    _Pragma("unroll") for (int ni = 0; ni < 4; ++ni) { \
        int bi = (wn * 64 + ni * 16 + (lane & 15)) * 40 + (lane >> 4) * 8; \
        bfh[ni] = *(const s16x8*)&sB[bi]; \
    } \
    _Pragma("unroll") for (int mi = 0; mi < 4; ++mi) \
        _Pragma("unroll") for (int ni = 0; ni < 4; ++ni) \
            acc[mi][ni] = mfma16(afh[mi], bfh[ni], acc[mi][ni]); }

template<int AMODE, int WMODE, int OUT_MODE>
__global__ __launch_bounds__(256)
void gemm_mfma(const void* __restrict__ Ap, const void* __restrict__ Wop,
               const float* __restrict__ bias, void* __restrict__ Y0p,
               int M, int N, int bshift) {
    __shared__ u16 sA[128 * 40];
    __shared__ u16 sB[128 * 40];

    const int t = threadIdx.x;
    const int lane = t & 63;
    const int w = t >> 6;
    const int wm = w >> 1, wn = w & 1;
    const int rowBase = blockIdx.y * 128;
    const int colBase = blockIdx.x * 128;
    const int srow = t >> 1;
    const int sc = (t & 1) * 16;

    const float* Af = (const float*)Ap;
    const u16* Au = (const u16*)Ap;
    const float* Wf = (const float*)Wop;
    const u16* Wu = (const u16*)Wop;

    f32x4 acc[4][4];
#pragma unroll
    for (int i = 0; i < 4; ++i)
#pragma unroll
        for (int j = 0; j < 4; ++j) acc[i][j] = (f32x4){0.f, 0.f, 0.f, 0.f};

    float ax0[16], ax1[16], bx0[16], bx1[16];
    u16x8 au00, au01, au10, au11;
    u16x8 wh00, wh01, wh10, wh11;

    GEMM_LOAD(0, 0)
    GEMM_LOAD(1, 32)

    for (int k0 = 0; k0 < 1024; k0 += 64) {
        __syncthreads();
        GEMM_WRITE(0)
        __syncthreads();
        if (k0 + 64 < 1024) GEMM_LOAD(0, k0 + 64)
        GEMM_COMPUTE()
        __syncthreads();
        GEMM_WRITE(1)
        __syncthreads();
        if (k0 + 96 < 1024) GEMM_LOAD(1, k0 + 96)
        GEMM_COMPUTE()
    }

#pragma unroll
    for (int mi = 0; mi < 4; ++mi)
#pragma unroll
        for (int ni = 0; ni < 4; ++ni)
#pragma unroll
            for (int rr = 0; rr < 4; ++rr) {
                int mg = rowBase + wm * 64 + mi * 16 + (lane >> 4) * 4 + rr;
                int ng = colBase + wn * 64 + ni * 16 + (lane & 15);
                float y = acc[mi][ni][rr];
                if constexpr (OUT_MODE == 0) {
                    ((float*)Y0p)[(size_t)mg * N + ng] = y + bias[ng];
                } else if constexpr (OUT_MODE == 4) {
                    y += bias[mg];
                    size_t idx = ((size_t)((ng >> 11) * 16 + (mg >> 6)) * 64 + (mg & 63)) * 2048 + (ng & 2047);
                    ((u16*)Y0p)[idx] = f2bf(y);
                } else if constexpr (OUT_MODE == 5 || OUT_MODE == 6) {
                    y += bias[ng];
                    if constexpr (OUT_MODE == 6) y *= PSC;
                    int bb = mg >> bshift, s = mg & ((1 << bshift) - 1);
                    size_t idx = ((((size_t)(bb * 16 + (ng >> 6))) << bshift) + s) * 64 + (ng & 63);
                    ((u16*)Y0p)[idx] = f2bf(y);
                }
            }
}

// ---------------------------------------------------------------------------
// Pass 1: attended output + denominators. Q pre-scaled by PSC -> e = exp2(s)
// directly. l computed via ones-A-fragment MFMA (D rows all = sum_k p[q][k]),
// removing the scalar adds and shuffles; numerator and denominator now use
// identical bf16 p. K/V triple-buffered, counted vmcnt(2).
// ---------------------------------------------------------------------------
__global__ __launch_bounds__(512, 4)
void attn_O(const u16* __restrict__ Qhi, const u16* __restrict__ Khi,
            const u16* __restrict__ VT, u16* __restrict__ Att,
            float* __restrict__ llog) {
    __shared__ char lds[49152];
    float* sOf = (float*)lds;
    float* sL2 = (float*)(lds + 35840);

    const int t = threadIdx.x;
    const int w = t >> 6, lane = t & 63;
    const int g = lane >> 4, c16 = lane & 15;
    const int qt = blockIdx.x >> 6;
    const int g6 = blockIdx.x & 63;
    const int b = g6 >> 4, h = g6 & 15;
    const int qbase = qt * 128;
    const int wq = w >> 1, wk = w & 1;
    const int kswz = (g ^ (c16 & 7)) << 4;
    const int vsw0 = (((wk * 4 + 0 + (g >> 1)) ^ (c16 & 7)) << 4) | ((g & 1) << 3);
    const int vsw1 = (((wk * 4 + 2 + (g >> 1)) ^ (c16 & 7)) << 4) | ((g & 1) << 3);

    const char* Kh_g = (const char*)(Khi + (size_t)(b * 16 + h) * SKL * 64);
    const char* V_g  = (const char*)(VT + (size_t)(b * 16 + h) * 64 * SKL);

    s16x8 qh[2][2];
    const size_t qrowbase = (size_t)(b * 16 + h) * SQL + qbase;
#pragma unroll
    for (int qf = 0; qf < 2; ++qf) {
        size_t qo = (qrowbase + wq * 32 + qf * 16 + c16) * 64 + g * 8;
        qh[qf][0] = *(const s16x8*)&Qhi[qo];
        qh[qf][1] = *(const s16x8*)&Qhi[qo + 32];
    }

    stage8k(Kh_g, 128, lds, w, lane);
    stage8k(V_g, 4096, lds + 24576, w, lane);
    stage8k(Kh_g + 8192, 128, lds + 8192, w, lane);
    stage8k(V_g + 128, 4096, lds + 24576 + 8192, w, lane);

    const s16x4 onesf = {(short)0x3F80, (short)0x3F80, (short)0x3F80, (short)0x3F80};
    f32x4 oacc[2][4];
    f32x4 lacc[2];
#pragma unroll
    for (int qf = 0; qf < 2; ++qf) {
        lacc[qf] = (f32x4){0.f, 0.f, 0.f, 0.f};
#pragma unroll
        for (int i = 0; i < 4; ++i) oacc[qf][i] = (f32x4){0.f, 0.f, 0.f, 0.f};
    }

    int cur = 0;
    for (int c = 0; c < 32; ++c) {
        if (c < 31) { asm volatile("s_waitcnt vmcnt(2)" ::: "memory"); }
        else        { asm volatile("s_waitcnt vmcnt(0)" ::: "memory"); }
        SBAR();
        if (c + 2 < 32) {
            int nb = cur + 2; if (nb >= 3) nb -= 3;
            stage8k(Kh_g + (size_t)(c + 2) * 8192, 128, lds + nb * 8192, w, lane);
            stage8k(V_g + (size_t)(c + 2) * 128, 4096, lds + 24576 + nb * 8192, w, lane);
        }
        char* curK = lds + cur * 8192;
        char* curV = lds + 24576 + cur * 8192;
#pragma unroll
        for (int kf = 0; kf < 2; ++kf) {
            int kb = (wk * 32 + kf * 16 + c16) * 128 + kswz;
            s16x8 kh0 = *(const s16x8*)(curK + kb);
            s16x8 kh1 = *(const s16x8*)(curK + (kb ^ 64));
            s16x4 pb[2];
#pragma unroll
            for (int qf = 0; qf < 2; ++qf) {
                f32x4 s = {0.f, 0.f, 0.f, 0.f};
                s = mfma16(kh0, qh[qf][0], s);
                s = mfma16(kh1, qh[qf][1], s);
                pb[qf][0] = (short)f2bf(exp2f(s[0]));
                pb[qf][1] = (short)f2bf(exp2f(s[1]));
                pb[qf][2] = (short)f2bf(exp2f(s[2]));
                pb[qf][3] = (short)f2bf(exp2f(s[3]));
                lacc[qf] = mfma16k16(onesf, pb[qf], lacc[qf]);
            }
            int vs = kf ? vsw1 : vsw0;
#pragma unroll
            for (int df = 0; df < 4; ++df) {
                s16x4 vf = *(const s16x4*)(curV + (df * 16 + c16) * 128 + vs);
                oacc[0][df] = mfma16k16(vf, pb[0], oacc[0][df]);
                oacc[1][df] = mfma16k16(vf, pb[1], oacc[1][df]);
            }
        }
        ++cur; if (cur == 3) cur = 0;
    }

    __syncthreads();   // all compute done; staging region becomes sOf
    // lacc rows are identical; lane (g==0, c16) holds l for q = wq*32+qf*16+c16
#pragma unroll
    for (int qf = 0; qf < 2; ++qf)
        if (g == 0) sL2[wk * 128 + wq * 32 + qf * 16 + c16] = lacc[qf][0];

#pragma unroll
    for (int half = 0; half < 2; ++half) {
        if (half) __syncthreads();
        if ((wq >> 1) == half) {
            int qlocal = (wq & 1) * 32 + c16;
#pragma unroll
            for (int qf = 0; qf < 2; ++qf)
#pragma unroll
                for (int df = 0; df < 4; ++df)
#pragma unroll
                    for (int r = 0; r < 4; ++r)
                        sOf[wk * 4352 + (df * 16 + g * 4 + r) * 68 + qlocal + qf * 16] =
                            oacc[qf][df][r];
        }
        __syncthreads();
        {
            int q = t >> 3, dg = t & 7;
            float l = sL2[half * 64 + q] + sL2[128 + half * 64 + q];
            float linv = 1.f / l;
            u16x8 ov;
#pragma unroll
            for (int i = 0; i < 8; ++i) {
                int d = dg * 8 + i;
                ov[i] = f2bf((sOf[d * 68 + q] + sOf[4352 + d * 68 + q]) * linv);
            }
            *(u16x8*)&Att[(size_t)(b * SQL + qbase + half * 64 + q) * EMBED + h * 64 + dg * 8] = ov;
            if (dg == 0)
                llog[(size_t)(b * 16 + h) * SQL + qbase + half * 64 + q] = log2f(l);
        }
    }
}

// ---------------------------------------------------------------------------
// Pass 2: mean_attn (Q pre-scaled: p = exp2(s - lb)). Structure unchanged.
// ---------------------------------------------------------------------------
__global__ __launch_bounds__(512, 4)
void attn_mean(const u16* __restrict__ Qhi, const u16* __restrict__ Khi,
               const float* __restrict__ llog, float* __restrict__ meanOut) {
    __shared__ char lds[81920];   // Q dbuf 2x16K @0; K tbuf 3x16K @32768

    const int t = threadIdx.x;
    const int w = t >> 6, lane = t & 63;
    const int g = lane >> 4, c16 = lane & 15;
    const int qt = blockIdx.x >> 6;
    const int low = blockIdx.x & 63;
    const int b = low >> 4, ks = low & 15;
    const int qbase = qt * 128;
    const int kbase = ks * 128;
    const int wq = w >> 1, wk = w & 1;
    const int kswz = (g ^ (c16 & 7)) << 4;

    const size_t QH_STRIDE = (size_t)SQL * 128;
    const size_t KH_STRIDE = (size_t)SKL * 128;
    const char* Qh_b = (const char*)(Qhi + ((size_t)(b * 16) * SQL + qbase) * 64);
    const char* Kh_b = (const char*)(Khi + ((size_t)(b * 16) * SKL + kbase) * 64);
    const float* ll_b = llog + (size_t)(b * 16) * SQL + qbase;

    f32x4 ma[2][4];
#pragma unroll
    for (int qf = 0; qf < 2; ++qf)
#pragma unroll
        for (int i = 0; i < 4; ++i) ma[qf][i] = (f32x4){0.f, 0.f, 0.f, 0.f};

    stage8k(Qh_b, 128, lds, w, lane);
    stage8k(Qh_b + 8192, 128, lds + 8192, w, lane);
    float lbA0 = ll_b[wq * 32 + c16];
    float lbA1 = ll_b[wq * 32 + 16 + c16];
    stage8k(Kh_b, 128, lds + 32768, w, lane);
    stage8k(Kh_b + 8192, 128, lds + 32768 + 8192, w, lane);
    stage8k(Qh_b + QH_STRIDE, 128, lds + 16384, w, lane);
    stage8k(Qh_b + QH_STRIDE + 8192, 128, lds + 16384 + 8192, w, lane);
    float lbB0 = ll_b[SQL + wq * 32 + c16];
    float lbB1 = ll_b[SQL + wq * 32 + 16 + c16];
    stage8k(Kh_b + KH_STRIDE, 128, lds + 32768 + 16384, w, lane);
    stage8k(Kh_b + KH_STRIDE + 8192, 128, lds + 32768 + 16384 + 8192, w, lane);

    int curK = 0;
    for (int h = 0; h < 16; ++h) {
        if (h < 15) { asm volatile("s_waitcnt vmcnt(4)" ::: "memory"); }
        else        { asm volatile("s_waitcnt vmcnt(0)" ::: "memory"); }
        SBAR();

        const char* sQ = lds + (h & 1) * 16384;
        s16x8 qa0, qa1, qc0, qc1;
        {
            int qb0 = (wq * 32 + c16) * 128 + kswz;
            qa0 = *(const s16x8*)(sQ + qb0);
            qa1 = *(const s16x8*)(sQ + (qb0 ^ 64));
            int qb1 = (wq * 32 + 16 + c16) * 128 + kswz;
            qc0 = *(const s16x8*)(sQ + qb1);
            qc1 = *(const s16x8*)(sQ + (qb1 ^ 64));
        }
        asm volatile("s_waitcnt lgkmcnt(0)" ::: "memory");
        SBAR();

        float lb0 = lbA0, lb1 = lbA1;
        lbA0 = lbB0; lbA1 = lbB1;

        if (h + 2 < 16) {
            const char* Qg = Qh_b + (size_t)(h + 2) * QH_STRIDE;
            char* qdst = lds + (h & 1) * 16384;
            stage8k(Qg, 128, qdst, w, lane);
            stage8k(Qg + 8192, 128, qdst + 8192, w, lane);
            lbB0 = ll_b[(size_t)(h + 2) * SQL + wq * 32 + c16];
            lbB1 = ll_b[(size_t)(h + 2) * SQL + wq * 32 + 16 + c16];
            const char* Kg = Kh_b + (size_t)(h + 2) * KH_STRIDE;
            int nb = curK + 2; if (nb >= 3) nb -= 3;
            char* kdst = lds + 32768 + nb * 16384;
            stage8k(Kg, 128, kdst, w, lane);
            stage8k(Kg + 8192, 128, kdst + 8192, w, lane);
        }

        const char* sK = lds + 32768 + curK * 16384;
#pragma unroll
        for (int kf = 0; kf < 4; ++kf) {
            int kb = (kf * 32 + wk * 16 + c16) * 128 + kswz;
            s16x8 kh0 = *(const s16x8*)(sK + kb);
            s16x8 kh1 = *(const s16x8*)(sK + (kb ^ 64));
            {
                f32x4 s = {0.f, 0.f, 0.f, 0.f};
                s = mfma16(kh0, qa0, s);
                s = mfma16(kh1, qa1, s);
                ma[0][kf][0] += exp2f(s[0] - lb0);
                ma[0][kf][1] += exp2f(s[1] - lb0);
                ma[0][kf][2] += exp2f(s[2] - lb0);
                ma[0][kf][3] += exp2f(s[3] - lb0);
            }
            {
                f32x4 s = {0.f, 0.f, 0.f, 0.f};
                s = mfma16(kh0, qc0, s);
                s = mfma16(kh1, qc1, s);
                ma[1][kf][0] += exp2f(s[0] - lb1);
                ma[1][kf][1] += exp2f(s[1] - lb1);
                ma[1][kf][2] += exp2f(s[2] - lb1);
                ma[1][kf][3] += exp2f(s[3] - lb1);
            }
        }
        ++curK; if (curK == 3) curK = 0;
    }

    const float s16c = 1.f / 16.f;
#pragma unroll
    for (int qf = 0; qf < 2; ++qf)
#pragma unroll
        for (int kf = 0; kf < 4; ++kf) {
            f32x4 m = ma[qf][kf];
            m[0] *= s16c; m[1] *= s16c; m[2] *= s16c; m[3] *= s16c;
            *(f32x4*)&meanOut[(size_t)(b * SQL + qbase + wq * 32 + qf * 16 + c16) * SKL +
                              kbase + kf * 32 + wk * 16 + g * 4] = m;
        }
}

// ---------------------------------------------------------------------------
extern "C" void kernel_launch(void* const* d_in, const int* in_sizes, int n_in,
                              void* d_out, int out_size, void* d_ws, size_t ws_size,
                              hipStream_t stream) {
    const float* query = (const float*)d_in[0];
    const float* key   = (const float*)d_in[1];
    const float* value = (const float*)d_in[2];
    const float* Wq = (const float*)d_in[3];
    const float* bq = (const float*)d_in[4];
    const float* Wk = (const float*)d_in[5];
    const float* bk = (const float*)d_in[6];
    const float* Wv = (const float*)d_in[7];
    const float* bv = (const float*)d_in[8];
    const float* Wo = (const float*)d_in[9];
    const float* bo = (const float*)d_in[10];

    float* out = (float*)d_out;                         // [4,1024,1024] f32
    float* meanOut = out + (size_t)BATCH * SQL * EMBED; // [4,1024,2048] f32

    u16* Qhi = (u16*)d_ws;                              // head-major [b][h][q][64], pre-scaled by PSC
    u16* Khi = Qhi + (size_t)4096 * 1024;               // [b][h][k][64]
    u16* VTh = Khi + (size_t)8192 * 1024;               // [b][h][d][2048]
    u16* Att = VTh + (size_t)8192 * 1024;               // [4096][1024] bf16
    float* llog = (float*)(Att + (size_t)4096 * 1024);  // [b*16+h][q]
    u16* Wqh = (u16*)(llog + 64 * 1024);                // bf16 weight planes
    u16* Wkh = Wqh + (size_t)1024 * 1024;
    u16* Wvh = Wkh + (size_t)1024 * 1024;
    u16* Woh = Wvh + (size_t)1024 * 1024;

    cvt_w<<<dim3(2048), 256, 0, stream>>>(Wq, Wk, Wv, Wo, Wqh, Wkh, Wvh, Woh);

    gemm_mfma<0, 1, 6><<<dim3(8, 32), 256, 0, stream>>>(query, Wqh, bq, Qhi, 4096, 1024, 10);
    gemm_mfma<0, 1, 5><<<dim3(8, 64), 256, 0, stream>>>(key, Wkh, bk, Khi, 8192, 1024, 11);
    gemm_mfma<1, 0, 4><<<dim3(64, 8), 256, 0, stream>>>(Wvh, value, bv, VTh, 1024, 8192, 0);

    attn_O<<<dim3(512), dim3(512), 0, stream>>>(Qhi, Khi, VTh, Att, llog);
    attn_mean<<<dim3(512), dim3(512), 0, stream>>>(Qhi, Khi, llog, meanOut);

    gemm_mfma<1, 1, 0><<<dim3(8, 32), 256, 0, stream>>>(Att, Woh, bo, out, 4096, 1024, 0);
}